// Round 10
// baseline (292.009 us; speedup 1.0000x reference)
//
#include <hip/hip_runtime.h>
#include <math.h>

typedef unsigned short u16;
typedef __bf16 bf16x8 __attribute__((ext_vector_type(8)));
typedef __bf16 bf16x4 __attribute__((ext_vector_type(4)));
typedef u16 u16x4 __attribute__((ext_vector_type(4)));
typedef float f32x4 __attribute__((ext_vector_type(4)));

// ---- constants ----
// B=4, N=1024, D=768, H=12, Dh=64, HID=2048, 3D=2304
#define NTOK 1024
#define DMODEL 768
#define NHEAD 12
#define LD3 2304
#define HIDDIM 2048

__device__ __forceinline__ float b2f(u16 u) {
  unsigned int t = ((unsigned int)u) << 16;
  float f;
  __builtin_memcpy(&f, &t, 4);
  return f;
}
__device__ __forceinline__ u16 f2b(float f) {
  unsigned int t;
  __builtin_memcpy(&t, &f, 4);
  t += 0x7fffu + ((t >> 16) & 1u);
  return (u16)(t >> 16);
}

// async global->LDS, 16B per lane; LDS dest is wave-uniform base + lane*16
__device__ __forceinline__ void gl_lds16(const u16* g, u16* l) {
  __builtin_amdgcn_global_load_lds(
      (__attribute__((address_space(1))) const unsigned int*)g,
      (__attribute__((address_space(3))) unsigned int*)l, 16, 0, 0);
}

// ---------------- host-assert signal (f32 output now) ------------------------
__global__ __launch_bounds__(256) void signal_kernel(float* __restrict__ out,
                                                     int n, float c) {
  int i = blockIdx.x * 256 + threadIdx.x;
  if (i < n) out[i] = c;
}

// ---------------- input dtype detection (verified f32: flag=1, R6) -----------
__global__ __launch_bounds__(256) void detect_kernel(const u16* __restrict__ x,
                                                     int* __restrict__ flag) {
  __shared__ int cnt;
  if (threadIdx.x == 0) cnt = 0;
  __syncthreads();
  int bad = 0;
  for (int i = threadIdx.x; i < 4096; i += 256) {
    u16 v = x[2 * i];
    int e = (v >> 7) & 0xFF;
    if (e >= 0xC0) bad++;
  }
  atomicAdd(&cnt, bad);
  __syncthreads();
  if (threadIdx.x == 0) *flag = (cnt >= 64) ? 1 : 0;
}

// ---------------- canonicalize all inputs to bf16 (vectorized x4) ------------
struct CanonJobs {
  const void* s[13];
  u16* d[13];
  int n[13];
};

__global__ __launch_bounds__(256) void canon_kernel(CanonJobs jobs,
                                                    const int* __restrict__ flag) {
  int j = blockIdx.y;
  int n4 = jobs.n[j] >> 2;            // all sizes divisible by 4
  const void* s = jobs.s[j];
  u16* d = jobs.d[j];
  bool isf32 = (*flag != 0);
  for (int i = blockIdx.x * 256 + threadIdx.x; i < n4; i += gridDim.x * 256) {
    if (isf32) {
      f32x4 v = *((const f32x4*)s + i);
      u16x4 o = {f2b(v[0]), f2b(v[1]), f2b(v[2]), f2b(v[3])};
      *((u16x4*)d + i) = o;
    } else {
      *((u16x4*)d + i) = *((const u16x4*)s + i);
    }
  }
}

// ---------------- LayerNorm (bf16 input) ----------------
__global__ __launch_bounds__(256) void ln_bf16_kernel(
    const u16* __restrict__ x, const u16* __restrict__ g,
    const u16* __restrict__ b, u16* __restrict__ out) {
  int row = blockIdx.x;
  int tid = threadIdx.x;
  const u16* xr = x + (size_t)row * DMODEL;
  float v0 = b2f(xr[tid]), v1 = b2f(xr[tid + 256]), v2 = b2f(xr[tid + 512]);
  float s = v0 + v1 + v2;
  float q = v0 * v0 + v1 * v1 + v2 * v2;
#pragma unroll
  for (int off = 32; off; off >>= 1) {
    s += __shfl_xor(s, off, 64);
    q += __shfl_xor(q, off, 64);
  }
  __shared__ float rs[4], rq[4];
  int wv = tid >> 6;
  if ((tid & 63) == 0) { rs[wv] = s; rq[wv] = q; }
  __syncthreads();
  s = rs[0] + rs[1] + rs[2] + rs[3];
  q = rq[0] + rq[1] + rq[2] + rq[3];
  float mean = s * (1.0f / 768.0f);
  float var = q * (1.0f / 768.0f) - mean * mean;
  float inv = rsqrtf(var + 1e-5f);
  u16* outr = out + (size_t)row * DMODEL;
  outr[tid]       = f2b((v0 - mean) * inv * b2f(g[tid])       + b2f(b[tid]));
  outr[tid + 256] = f2b((v1 - mean) * inv * b2f(g[tid + 256]) + b2f(b[tid + 256]));
  outr[tid + 512] = f2b((v2 - mean) * inv * b2f(g[tid + 512]) + b2f(b[tid + 512]));
}

// ---------------- LayerNorm (f32 input) ----------------
__global__ __launch_bounds__(256) void ln_f32_kernel(
    const float* __restrict__ x, const u16* __restrict__ g,
    const u16* __restrict__ b, u16* __restrict__ out) {
  int row = blockIdx.x;
  int tid = threadIdx.x;
  const float* xr = x + (size_t)row * DMODEL;
  float v0 = xr[tid], v1 = xr[tid + 256], v2 = xr[tid + 512];
  float s = v0 + v1 + v2;
  float q = v0 * v0 + v1 * v1 + v2 * v2;
#pragma unroll
  for (int off = 32; off; off >>= 1) {
    s += __shfl_xor(s, off, 64);
    q += __shfl_xor(q, off, 64);
  }
  __shared__ float rs[4], rq[4];
  int wv = tid >> 6;
  if ((tid & 63) == 0) { rs[wv] = s; rq[wv] = q; }
  __syncthreads();
  s = rs[0] + rs[1] + rs[2] + rs[3];
  q = rq[0] + rq[1] + rq[2] + rq[3];
  float mean = s * (1.0f / 768.0f);
  float var = q * (1.0f / 768.0f) - mean * mean;
  float inv = rsqrtf(var + 1e-5f);
  u16* outr = out + (size_t)row * DMODEL;
  outr[tid]       = f2b((v0 - mean) * inv * b2f(g[tid])       + b2f(b[tid]));
  outr[tid + 256] = f2b((v1 - mean) * inv * b2f(g[tid + 256]) + b2f(b[tid + 256]));
  outr[tid + 512] = f2b((v2 - mean) * inv * b2f(g[tid + 512]) + b2f(b[tid + 512]));
}

// ---------------- MFMA GEMM 128x64 tile, 3-ring pipelined, swizzled ----------
// grid (Nn/64, 32) = 1152 blocks for Nn=2304. Waves 2m x 2n: wave 64x32.
// Per wave/stage: 2 A-chunks + 1 B-chunk -> vmcnt(3) steady.
__global__ __launch_bounds__(256) void gemm_bt(
    const u16* __restrict__ Ap, const u16* __restrict__ Wp,
    const u16* __restrict__ bias, u16* __restrict__ Cp, int Nn, int K) {
  __shared__ __align__(16) u16 Al[3 * 128 * 32], Bl[3 * 64 * 32];
  int lane = threadIdx.x & 63;
  int wv = threadIdx.x >> 6;
  int q16 = lane & 15, quad = lane >> 4;
  int mB0 = blockIdx.y * 128;
  int nB0 = blockIdx.x * 64;
  int mW = (wv >> 1) * 64, nW = (wv & 1) * 32;
  int srow = lane >> 2;
  int scol = ((lane & 3) ^ ((lane >> 3) & 3)) * 8;   // inverse-swizzled source
  int sx8 = (quad ^ ((q16 >> 1) & 3)) * 8;           // swizzled read slot
  int r0 = wv * 32 + srow, r1 = r0 + 16;             // A rows this lane stages
  int rb = wv * 16 + srow;                           // B row 0..63
  const u16* Ag0 = Ap + (size_t)(mB0 + r0) * K + scol;
  const u16* Ag1 = Ap + (size_t)(mB0 + r1) * K + scol;
  const u16* Wg  = Wp + (size_t)(nB0 + rb) * K + scol;
  int ch0 = wv * 1024, ch1 = ch0 + 512, chb = wv * 512;
  int nsteps = K >> 5;                               // 24 (div by 3)
  f32x4 acc[4][2] = {};
#pragma unroll
  for (int tt = 0; tt < 2; ++tt) {
    int k0 = tt * 32;
    gl_lds16(Ag0 + k0, Al + tt * 4096 + ch0);
    gl_lds16(Ag1 + k0, Al + tt * 4096 + ch1);
    gl_lds16(Wg + k0, Bl + tt * 2048 + chb);
  }
  int n3 = nsteps / 3;
  for (int kb = 0; kb < n3; ++kb) {
#pragma unroll
    for (int c = 0; c < 3; ++c) {
      int t = kb * 3 + c;
      if (t < nsteps - 1) asm volatile("s_waitcnt vmcnt(3)" ::: "memory");
      else                asm volatile("s_waitcnt vmcnt(0)" ::: "memory");
      __builtin_amdgcn_sched_barrier(0);
      __builtin_amdgcn_s_barrier();
      __builtin_amdgcn_sched_barrier(0);
      if (t < nsteps - 2) {
        int k0 = (t + 2) * 32;
        int bs = (c + 2) % 3;
        gl_lds16(Ag0 + k0, Al + bs * 4096 + ch0);
        gl_lds16(Ag1 + k0, Al + bs * 4096 + ch1);
        gl_lds16(Wg + k0, Bl + bs * 2048 + chb);
      }
      const __bf16* Ab = (const __bf16*)(Al + c * 4096);
      const __bf16* Bb = (const __bf16*)(Bl + c * 2048);
      bf16x8 af[4], bfr[2];
#pragma unroll
      for (int si = 0; si < 4; ++si)
        af[si] = *(const bf16x8*)(Ab + (mW + si * 16 + q16) * 32 + sx8);
#pragma unroll
      for (int sj = 0; sj < 2; ++sj)
        bfr[sj] = *(const bf16x8*)(Bb + (nW + sj * 16 + q16) * 32 + sx8);
#pragma unroll
      for (int si = 0; si < 4; ++si)
#pragma unroll
        for (int sj = 0; sj < 2; ++sj)
          acc[si][sj] = __builtin_amdgcn_mfma_f32_16x16x32_bf16(af[si], bfr[sj], acc[si][sj], 0, 0, 0);
    }
  }
#pragma unroll
  for (int si = 0; si < 4; ++si)
#pragma unroll
    for (int sj = 0; sj < 2; ++sj) {
      int col = nB0 + nW + sj * 16 + q16;
      float bcol = b2f(bias[col]);
#pragma unroll
      for (int r = 0; r < 4; ++r) {
        int rowi = mB0 + mW + si * 16 + quad * 4 + r;
        Cp[(size_t)rowi * Nn + col] = f2b(acc[si][sj][r] + bcol);
      }
    }
}

// ---------------- final GEMM, split-K x 2, N-tile 64, ring-4 pipelined -------
// grid (12, 32, 2). Block = 128M x 64N, K-half = 1024 (32 K-steps, 4-unroll).
__global__ __launch_bounds__(256) void gemm_out_split(
    const u16* __restrict__ Ap, const u16* __restrict__ Wp,
    const u16* __restrict__ bias, const float* __restrict__ res,
    float* __restrict__ part, float* __restrict__ out) {
  __shared__ __align__(16) u16 Al[4 * 128 * 32], Bl[4 * 64 * 32];
  int lane = threadIdx.x & 63;
  int wv = threadIdx.x >> 6;
  int q16 = lane & 15, quad = lane >> 4;
  int mB0 = blockIdx.y * 128;
  int nB0 = blockIdx.x * 64;
  int kz = blockIdx.z;
  int kbase = kz * 1024;
  int mW = (wv >> 1) * 64, nW = (wv & 1) * 32;
  int srow = lane >> 2;
  int scol = ((lane & 3) ^ ((lane >> 3) & 3)) * 8;
  int sx8 = (quad ^ ((q16 >> 1) & 3)) * 8;
  int r0 = wv * 32 + srow, r1 = r0 + 16;
  int rb = wv * 16 + srow;
  const u16* Ag0 = Ap + (size_t)(mB0 + r0) * 2048 + kbase + scol;
  const u16* Ag1 = Ap + (size_t)(mB0 + r1) * 2048 + kbase + scol;
  const u16* Wg  = Wp + (size_t)(nB0 + rb) * 2048 + kbase + scol;
  int ch0 = wv * 1024, ch1 = ch0 + 512, chb = wv * 512;
  f32x4 acc[4][2] = {};
#pragma unroll
  for (int tt = 0; tt < 2; ++tt) {
    int k0 = tt * 32;
    gl_lds16(Ag0 + k0, Al + tt * 4096 + ch0);
    gl_lds16(Ag1 + k0, Al + tt * 4096 + ch1);
    gl_lds16(Wg + k0, Bl + tt * 2048 + chb);
  }
  for (int kb = 0; kb < 8; ++kb) {
#pragma unroll
    for (int c = 0; c < 4; ++c) {
      int t = kb * 4 + c;
      if (t < 31) asm volatile("s_waitcnt vmcnt(3)" ::: "memory");
      else        asm volatile("s_waitcnt vmcnt(0)" ::: "memory");
      __builtin_amdgcn_sched_barrier(0);
      __builtin_amdgcn_s_barrier();
      __builtin_amdgcn_sched_barrier(0);
      if (t < 30) {
        int k0 = (t + 2) * 32;
        int bs = (c + 2) & 3;                    // static per unrolled copy
        gl_lds16(Ag0 + k0, Al + bs * 4096 + ch0);
        gl_lds16(Ag1 + k0, Al + bs * 4096 + ch1);
        gl_lds16(Wg + k0, Bl + bs * 2048 + chb);
      }
      const __bf16* Ab = (const __bf16*)(Al + c * 4096);
      const __bf16* Bb = (const __bf16*)(Bl + c * 2048);
      bf16x8 af[4], bfr[2];
#pragma unroll
      for (int si = 0; si < 4; ++si)
        af[si] = *(const bf16x8*)(Ab + (mW + si * 16 + q16) * 32 + sx8);
#pragma unroll
      for (int sj = 0; sj < 2; ++sj)
        bfr[sj] = *(const bf16x8*)(Bb + (nW + sj * 16 + q16) * 32 + sx8);
#pragma unroll
      for (int si = 0; si < 4; ++si)
#pragma unroll
        for (int sj = 0; sj < 2; ++sj)
          acc[si][sj] = __builtin_amdgcn_mfma_f32_16x16x32_bf16(af[si], bfr[sj], acc[si][sj], 0, 0, 0);
    }
  }
#pragma unroll
  for (int si = 0; si < 4; ++si)
#pragma unroll
    for (int sj = 0; sj < 2; ++sj) {
      int col = nB0 + nW + sj * 16 + q16;
#pragma unroll
      for (int r = 0; r < 4; ++r) {
        int rowi = mB0 + mW + si * 16 + quad * 4 + r;
        size_t idx = (size_t)rowi * 768 + col;
        if (kz == 0) {
          part[idx] = acc[si][sj][r];
        } else {
          out[idx] = acc[si][sj][r] + b2f(bias[col]) + res[idx];
        }
      }
    }
}

// ---------------- out += part (vectorized, 3.1M floats) ----------------------
__global__ __launch_bounds__(256) void add_kernel(float* __restrict__ out,
                                                  const float* __restrict__ part) {
  int i = blockIdx.x * 256 + threadIdx.x;   // 786432 f32x4 elems -> 3072 blocks
  f32x4 o = ((f32x4*)out)[i];
  f32x4 p = ((const f32x4*)part)[i];
#pragma unroll
  for (int r = 0; r < 4; ++r) o[r] += p[r];
  ((f32x4*)out)[i] = o;
}

// ---------------- fused FFN-in, 128x32 tile (64-row stacked B), pipelined ----
// grid (64, 32) = 2048 blocks. Waves 2m x 2c: wave 64M x 16cols.
// B-tile rows 0..31 = Wu[cB0..+32], rows 32..63 = Wg[cB0..+32].
// Per wave/stage: 2 A + 1 B -> vmcnt(3). LDS 36KB -> 4 blocks/CU.
__global__ __launch_bounds__(256) void ffn_in_kernel(
    const u16* __restrict__ hp, const u16* __restrict__ Wp,
    const u16* __restrict__ bias, u16* __restrict__ actp) {
  __shared__ __align__(16) u16 Al[3 * 128 * 32], Bl[3 * 64 * 32];
  int lane = threadIdx.x & 63;
  int wv = threadIdx.x >> 6;
  int q16 = lane & 15, quad = lane >> 4;
  int mB0 = blockIdx.y * 128;
  int cB0 = blockIdx.x * 32;
  int mW = (wv >> 1) * 64;
  int cW = (wv & 1) * 16;
  int srow = lane >> 2;
  int scol = ((lane & 3) ^ ((lane >> 3) & 3)) * 8;
  int sx8 = (quad ^ ((q16 >> 1) & 3)) * 8;
  int r0 = wv * 32 + srow, r1 = r0 + 16;   // A rows
  int rb = wv * 16 + srow;                 // B row 0..63
  int gb = (rb < 32) ? (cB0 + rb) : (HIDDIM + cB0 + rb - 32);
  const u16* Ag0 = hp + (size_t)(mB0 + r0) * DMODEL + scol;
  const u16* Ag1 = hp + (size_t)(mB0 + r1) * DMODEL + scol;
  const u16* Wg  = Wp + (size_t)gb * DMODEL + scol;
  int ch0 = wv * 1024, ch1 = ch0 + 512, chb = wv * 512;
  f32x4 au[4] = {}, ag[4] = {};
#pragma unroll
  for (int tt = 0; tt < 2; ++tt) {
    int k0 = tt * 32;
    gl_lds16(Ag0 + k0, Al + tt * 4096 + ch0);
    gl_lds16(Ag1 + k0, Al + tt * 4096 + ch1);
    gl_lds16(Wg + k0, Bl + tt * 2048 + chb);
  }
  for (int kb = 0; kb < 8; ++kb) {
#pragma unroll
    for (int c = 0; c < 3; ++c) {
      int t = kb * 3 + c;
      if (t < 23) asm volatile("s_waitcnt vmcnt(3)" ::: "memory");
      else        asm volatile("s_waitcnt vmcnt(0)" ::: "memory");
      __builtin_amdgcn_sched_barrier(0);
      __builtin_amdgcn_s_barrier();
      __builtin_amdgcn_sched_barrier(0);
      if (t < 22) {
        int k0 = (t + 2) * 32;
        int bs = (c + 2) % 3;
        gl_lds16(Ag0 + k0, Al + bs * 4096 + ch0);
        gl_lds16(Ag1 + k0, Al + bs * 4096 + ch1);
        gl_lds16(Wg + k0, Bl + bs * 2048 + chb);
      }
      const __bf16* Ab = (const __bf16*)(Al + c * 4096);
      const __bf16* Bb = (const __bf16*)(Bl + c * 2048);
      bf16x8 af[4], wu, wg;
#pragma unroll
      for (int si = 0; si < 4; ++si)
        af[si] = *(const bf16x8*)(Ab + (mW + si * 16 + q16) * 32 + sx8);
      wu = *(const bf16x8*)(Bb + (cW + q16) * 32 + sx8);
      wg = *(const bf16x8*)(Bb + (32 + cW + q16) * 32 + sx8);
#pragma unroll
      for (int si = 0; si < 4; ++si) {
        au[si] = __builtin_amdgcn_mfma_f32_16x16x32_bf16(af[si], wu, au[si], 0, 0, 0);
        ag[si] = __builtin_amdgcn_mfma_f32_16x16x32_bf16(af[si], wg, ag[si], 0, 0, 0);
      }
    }
  }
  int col = cB0 + cW + q16;
  float bu = b2f(bias[col]);
  float bg = b2f(bias[HIDDIM + col]);
#pragma unroll
  for (int si = 0; si < 4; ++si) {
#pragma unroll
    for (int r = 0; r < 4; ++r) {
      int rowi = mB0 + mW + si * 16 + quad * 4 + r;
      float u = au[si][r] + bu;
      float g = ag[si][r] + bg;
      float s = u / (1.0f + __expf(-u));
      actp[(size_t)rowi * HIDDIM + col] = f2b(s * g);
    }
  }
}

// ---------------- coord bias p2[b,h,n] = (coords.relw) * LOG2E ---------------
__global__ __launch_bounds__(256) void p_kernel(
    const u16* __restrict__ coords, const u16* __restrict__ relw,
    float* __restrict__ p) {
  const float LOG2E = 1.4426950408889634f;
  int idx = blockIdx.x * 256 + threadIdx.x;  // B*N = 4096
  float c0 = b2f(coords[idx * 3 + 0]);
  float c1 = b2f(coords[idx * 3 + 1]);
  float c2 = b2f(coords[idx * 3 + 2]);
  int b = idx >> 10, n = idx & 1023;
#pragma unroll
  for (int h = 0; h < NHEAD; ++h) {
    float w0 = b2f(relw[h * 3 + 0]), w1 = b2f(relw[h * 3 + 1]), w2 = b2f(relw[h * 3 + 2]);
    p[(size_t)(b * NHEAD + h) * NTOK + n] = (c0 * w0 + c1 * w1 + c2 * w2) * LOG2E;
  }
}

// ---------------- V transpose: Vt[b][h][d][n] = V[b][n][h][d] ----------------
__global__ __launch_bounds__(256) void vt_kernel(const u16* __restrict__ qkvp,
                                                 u16* __restrict__ vtp) {
  int blk = blockIdx.x;            // b*192 + h*16 + nt
  int b = blk / 192;
  int rem = blk % 192;
  int h = rem >> 4;
  int nt = rem & 15;
  int wv = threadIdx.x >> 6;
  int d = threadIdx.x & 63;
  int n0 = nt * 64 + wv * 16;
  const u16* src = qkvp + ((size_t)(b * NTOK) + n0) * LD3 + 2 * DMODEL + h * 64 + d;
  u16* dst = vtp + ((size_t)((b * NHEAD + h) * 64 + d)) * NTOK + n0;
#pragma unroll
  for (int c = 0; c < 2; ++c) {
    u16 buf[8] __attribute__((aligned(16)));
#pragma unroll
    for (int i = 0; i < 8; ++i) buf[i] = src[(size_t)(c * 8 + i) * LD3];
    *(uint4*)(dst + c * 8) = *(const uint4*)buf;
  }
}

// ---------------- flash attention: XCD-local heads, 4-deep counted pipeline --
__global__ __launch_bounds__(256) void attn_kernel(
    const u16* __restrict__ qkvp, const u16* __restrict__ vtp,
    const float* __restrict__ p2, const u16* __restrict__ xp,
    float* __restrict__ x1) {
  const __bf16* qb = (const __bf16*)qkvp;
  __shared__ __align__(16) u16 Kl[4][32 * 64];   // [j][d], slot swz by j&7
  __shared__ __align__(16) u16 Vl[4][64 * 32];   // [d][j], slot swz by (d>>1)&3
  __shared__ __align__(16) u16 Pl[4][16][40];    // 80B row stride
  __shared__ __align__(16) float Pb[1024];       // p-row (pre-scaled by LOG2E)
  int lane = threadIdx.x & 63;
  int wv = threadIdx.x >> 6;
  int hw = blockIdx.x;                     // 0..767
  int g = hw % 48;                         // (b,h): all its 16 tiles same XCD
  int nt = hw / 48;                        // query-tile group 0..15
  int b = g / 12, h = g % 12;
  int i0 = (nt * 4 + wv) * 16;             // wave's query tile
  int q16 = lane & 15, quad = lane >> 4;

  const float scl2 = 0.125f * 1.4426950408889634f;

  const __bf16* qrow = qb + ((size_t)(b * NTOK) + i0 + q16) * LD3 + h * 64;
  bf16x8 bq0 = *(const bf16x8*)(qrow + quad * 8);
  bf16x8 bq1 = *(const bf16x8*)(qrow + 32 + quad * 8);

  const float* prow = p2 + (size_t)(b * NHEAD + h) * NTOK;

  int krw = wv * 8 + (lane >> 3);          // K row 0..31 this lane stages
  int ks  = (lane & 7) ^ (krw & 7);        // swizzled 16B slot (8 per 128B row)
  const u16* kg0 = qkvp + (size_t)(b * NTOK) * LD3 + DMODEL + h * 64 + ks * 8;
  int vrw = wv * 16 + (lane >> 2);         // Vt row (d) 0..63
  int vs  = (lane & 3) ^ ((vrw >> 1) & 3); // swizzled 16B slot (4 per 64B row)
  const u16* vg0 = vtp + ((size_t)((b * NHEAD + h) * 64 + vrw)) * NTOK + vs * 8;

  // hoisted read-slot constants
  int kx0 = (quad ^ (q16 & 7)) << 3;
  int kx1 = ((4 | quad) ^ (q16 & 7)) << 3;
  int vx  = (quad ^ ((q16 >> 1) & 3)) << 3;

  float mrun = -1e30f, lsum = 0.f;
  f32x4 accO[4] = {};

  // prologue: p-row + tiles 0..2 (7 outstanding loads/wave)
  gl_lds16((const u16*)(prow + wv * 256 + lane * 4), (u16*)&Pb[wv * 256]);
#pragma unroll
  for (int tt = 0; tt < 3; ++tt) {
    gl_lds16(kg0 + (size_t)(tt * 32 + krw) * LD3, &Kl[tt][wv * 512]);
    gl_lds16(vg0 + tt * 32, &Vl[tt][wv * 512]);
  }

  for (int kb = 0; kb < 8; ++kb) {
#pragma unroll
    for (int c = 0; c < 4; ++c) {
      int t = kb * 4 + c;
      if (t < 30)       asm volatile("s_waitcnt vmcnt(4)" ::: "memory");
      else if (t == 30) asm volatile("s_waitcnt vmcnt(2)" ::: "memory");
      else              asm volatile("s_waitcnt vmcnt(0)" ::: "memory");
      __builtin_amdgcn_sched_barrier(0);
      __builtin_amdgcn_s_barrier();            // all waves' stage(t) landed
      __builtin_amdgcn_sched_barrier(0);
      if (t < 29) {                            // stage(t+3) into buf (c+3)&3
        int j = (t + 3) * 32;
        gl_lds16(kg0 + (size_t)(j + krw) * LD3, &Kl[(c + 3) & 3][wv * 512]);
        gl_lds16(vg0 + j, &Vl[(c + 3) & 3][wv * 512]);
      }

      int j0 = t * 32;
      const __bf16* Kb = (const __bf16*)Kl[c];
      bf16x8 ka00 = *(const bf16x8*)(Kb + q16 * 64 + kx0);
      bf16x8 ka01 = *(const bf16x8*)(Kb + q16 * 64 + kx1);
      bf16x8 ka10 = *(const bf16x8*)(Kb + (16 + q16) * 64 + kx0);
      bf16x8 ka11 = *(const bf16x8*)(Kb + (16 + q16) * 64 + kx1);
      f32x4 st0 = {}, st1 = {};
      st0 = __builtin_amdgcn_mfma_f32_16x16x32_bf16(ka00, bq0, st0, 0, 0, 0);
      st0 = __builtin_amdgcn_mfma_f32_16x16x32_bf16(ka01, bq1, st0, 0, 0, 0);
      st1 = __builtin_amdgcn_mfma_f32_16x16x32_bf16(ka10, bq0, st1, 0, 0, 0);
      st1 = __builtin_amdgcn_mfma_f32_16x16x32_bf16(ka11, bq1, st1, 0, 0, 0);

      f32x4 pjl = *(const f32x4*)(&Pb[j0 + 4 * quad]);
      f32x4 pjh = *(const f32x4*)(&Pb[j0 + 16 + 4 * quad]);
      float sl[4], sh[4];
#pragma unroll
      for (int r = 0; r < 4; ++r) {
        sl[r] = st0[r] * scl2 - pjl[r];
        sh[r] = st1[r] * scl2 - pjh[r];
      }
      float lm = fmaxf(fmaxf(fmaxf(sl[0], sl[1]), fmaxf(sl[2], sl[3])),
                       fmaxf(fmaxf(sh[0], sh[1]), fmaxf(sh[2], sh[3])));
      lm = fmaxf(lm, __shfl_xor(lm, 16, 64));
      lm = fmaxf(lm, __shfl_xor(lm, 32, 64));
      float mn = fmaxf(mrun, lm);
      float alpha = exp2f(mrun - mn);
      mrun = mn;
      float pl[4], ph[4];
#pragma unroll
      for (int r = 0; r < 4; ++r) {
        pl[r] = exp2f(sl[r] - mn);
        ph[r] = exp2f(sh[r] - mn);
      }
      float ts = (pl[0] + pl[1]) + (pl[2] + pl[3]) +
                 (ph[0] + ph[1]) + (ph[2] + ph[3]);
      ts += __shfl_xor(ts, 16, 64);
      ts += __shfl_xor(ts, 32, 64);
      lsum = lsum * alpha + ts;

      bf16x4 w0 = {(__bf16)pl[0], (__bf16)pl[1], (__bf16)pl[2], (__bf16)pl[3]};
      bf16x4 w1 = {(__bf16)ph[0], (__bf16)ph[1], (__bf16)ph[2], (__bf16)ph[3]};
      *(bf16x4*)(&Pl[wv][q16][4 * quad]) = w0;
      *(bf16x4*)(&Pl[wv][q16][16 + 4 * quad]) = w1;
      bf16x8 ap = *(const bf16x8*)(&Pl[wv][q16][quad * 8]);  // wave-private

      const __bf16* Vb = (const __bf16*)Vl[c];
#pragma unroll
      for (int ds = 0; ds < 4; ++ds) {
        bf16x8 av = *(const bf16x8*)(Vb + (ds * 16 + q16) * 32 + vx);
        f32x4 cc = accO[ds];
#pragma unroll
        for (int r = 0; r < 4; ++r) cc[r] *= alpha;
        accO[ds] = __builtin_amdgcn_mfma_f32_16x16x32_bf16(av, ap, cc, 0, 0, 0);
      }
    }
  }

  float rl = 1.0f / lsum;
  size_t rowbase = ((size_t)(b * NTOK) + i0 + q16) * DMODEL + h * 64;
#pragma unroll
  for (int ds = 0; ds < 4; ++ds) {
    int d0 = ds * 16 + quad * 4;
    u16x4 xv = *(const u16x4*)(xp + rowbase + d0);
    f32x4 ov;
#pragma unroll
    for (int r = 0; r < 4; ++r) ov[r] = b2f(xv[r]) + accO[ds][r] * rl;
    *(f32x4*)(x1 + rowbase + d0) = ov;
  }
}

extern "C" void kernel_launch(void* const* d_in, const int* in_sizes, int n_in,
                              void* d_out, int out_size, void* d_ws, size_t ws_size,
                              hipStream_t stream) {
  // ---- host-side boundary tripwires (verified passing in R6) ----
  static const int esz[13] = {3145728, 12288, 768, 768, 1769472, 2304, 36,
                              768, 768, 3145728, 4096, 1572864, 768};
  float sig = -1.f;
  if (n_in != 13) {
    sig = 6000.f + 100.f * (float)n_in;
  } else {
    for (int i = 0; i < 13; ++i)
      if (in_sizes[i] != esz[i]) { sig = 1000.f + 100.f * (float)i; break; }
  }
  if (sig < 0.f && ws_size < 57258496ULL) sig = 3000.f;
  if (sig < 0.f && out_size != 3145728) sig = 3100.f;
  if (sig >= 0.f) {
    signal_kernel<<<(out_size + 255) / 256, 256, 0, stream>>>((float*)d_out, out_size, sig);
    return;
  }

  char* ws = (char*)d_ws;
  int*  flag    = (int*)ws;                       // 256 B
  u16*  cx      = (u16*)(ws + 256);               // 6291456
  u16*  cqkvw   = (u16*)(ws + 6291712);           // 3538944
  u16*  cwinw   = (u16*)(ws + 9830656);           // 6291456
  u16*  cwoutw  = (u16*)(ws + 16122112);          // 3145728
  u16*  ccoords = (u16*)(ws + 19267840);          // 24576
  u16*  cln1g   = (u16*)(ws + 19292416);          // 1536
  u16*  cln1b   = (u16*)(ws + 19293952);          // 1536
  u16*  cqkvb   = (u16*)(ws + 19295488);          // 4608
  u16*  crelw   = (u16*)(ws + 19300096);          // 72 (padded)
  u16*  cln2g   = (u16*)(ws + 19300352);          // 1536
  u16*  cln2b   = (u16*)(ws + 19301888);          // 1536
  u16*  cwinb   = (u16*)(ws + 19303424);          // 8192
  u16*  cwoutb  = (u16*)(ws + 19311616);          // 1536
  u16*  h       = (u16*)(ws + 19313152);          // 6291456 (LN out; dead between
                                                  //  gemm_bt and ln2 -> reused as Vt)
  u16*  qkv     = (u16*)(ws + 25604608);          // 18874368 (reused as act)
  float* pbuf   = (float*)(ws + 44478976);        // 196608
  float* x1     = (float*)(ws + 44675584);        // 12582912 -> end 57258496
  u16*  act     = qkv;
  u16*  vt      = h;       // Vt needs 6291456 B == sizeof(h)
  // split-K partial: cx/cqkvw/cwinw region is dead after ffn_in (needs 12.6MB of 16.1MB)
  float* part   = (float*)(ws + 256);

  // 0a. dtype flag (f32 confirmed; adaptive kept as insurance)
  detect_kernel<<<1, 256, 0, stream>>>((const u16*)d_in[0], flag);

  // 0b. canonicalize all 13 inputs to bf16 (vectorized x4)
  CanonJobs jobs;
  u16* dsts[13] = {cx, ccoords, cln1g, cln1b, cqkvw, cqkvb, crelw,
                   cln2g, cln2b, cwinw, cwinb, cwoutw, cwoutb};
  for (int i = 0; i < 13; ++i) {
    jobs.s[i] = d_in[i];
    jobs.d[i] = dsts[i];
    jobs.n[i] = in_sizes[i];
  }
  canon_kernel<<<dim3(768, 13), 256, 0, stream>>>(jobs, flag);

  // 1. h = LN1(x)
  ln_bf16_kernel<<<4096, 256, 0, stream>>>(cx, cln1g, cln1b, h);
  // 2. qkv = h @ qkv_w^T + qkv_b   (M=4096, N=2304, K=768; 128x64 tiles)
  gemm_bt<<<dim3(36, 32), 256, 0, stream>>>(h, cqkvw, cqkvb, qkv, 2304, 768);
  // 3. p2[b,h,n] (pre-scaled by LOG2E)
  p_kernel<<<16, 256, 0, stream>>>(ccoords, crelw, pbuf);
  // 3b. Vt[b][h][d][n] = V  (h buffer is dead here; gemm_bt already consumed it)
  vt_kernel<<<768, 256, 0, stream>>>(qkv, vt);
  // 4. x1 = x + attention(qkv, Vt, p2)   (768 blocks; XCD-local + deep pipeline)
  attn_kernel<<<768, 256, 0, stream>>>(qkv, vt, pbuf, cx, x1);
  // 5. h2 = LN2(x1)  (reuse h)
  ln_f32_kernel<<<4096, 256, 0, stream>>>(x1, cln2g, cln2b, h);
  // 6+7. act = silu(h2 @ Wu^T + bu) * (h2 @ Wg^T + bg)   (128x32 tiles, 2048 blocks)
  ffn_in_kernel<<<dim3(64, 32), 256, 0, stream>>>(h, cwinw, cwinb, act);
  // 8. out(F32) = x1 + act @ wout_w^T + wout_b   split-K x2, ring-4 pipelined
  gemm_out_split<<<dim3(12, 32, 2), 256, 0, stream>>>(act, cwoutw, cwoutb, x1,
                                                      part, (float*)d_out);
  // 8b. out += partial(kz=0)
  add_kernel<<<3072, 256, 0, stream>>>((float*)d_out, part);
}

// Round 11
// 287.187 us; speedup vs baseline: 1.0168x; 1.0168x over previous
//
#include <hip/hip_runtime.h>
#include <math.h>

typedef unsigned short u16;
typedef __bf16 bf16x8 __attribute__((ext_vector_type(8)));
typedef __bf16 bf16x4 __attribute__((ext_vector_type(4)));
typedef u16 u16x4 __attribute__((ext_vector_type(4)));
typedef float f32x4 __attribute__((ext_vector_type(4)));

// ---- constants ----
// B=4, N=1024, D=768, H=12, Dh=64, HID=2048, 3D=2304
#define NTOK 1024
#define DMODEL 768
#define NHEAD 12
#define LD3 2304
#define HIDDIM 2048

__device__ __forceinline__ float b2f(u16 u) {
  unsigned int t = ((unsigned int)u) << 16;
  float f;
  __builtin_memcpy(&f, &t, 4);
  return f;
}
__device__ __forceinline__ u16 f2b(float f) {
  unsigned int t;
  __builtin_memcpy(&t, &f, 4);
  t += 0x7fffu + ((t >> 16) & 1u);
  return (u16)(t >> 16);
}

// async global->LDS, 16B per lane; LDS dest is wave-uniform base + lane*16
__device__ __forceinline__ void gl_lds16(const u16* g, u16* l) {
  __builtin_amdgcn_global_load_lds(
      (__attribute__((address_space(1))) const unsigned int*)g,
      (__attribute__((address_space(3))) unsigned int*)l, 16, 0, 0);
}

// ---------------- host-assert signal (f32 output now) ------------------------
__global__ __launch_bounds__(256) void signal_kernel(float* __restrict__ out,
                                                     int n, float c) {
  int i = blockIdx.x * 256 + threadIdx.x;
  if (i < n) out[i] = c;
}

// ---------------- canonicalize all inputs to bf16 (inline dtype-detect) ------
// Each block samples 256 u16s of x (job 0) and ballots on "exponent" bits:
// f32 data -> x[2i] is mantissa-low (uniform) -> ~25% hits; bf16 -> ~0.
struct CanonJobs {
  const void* s[13];
  u16* d[13];
  int n[13];
};

__global__ __launch_bounds__(256) void canon_kernel(CanonJobs jobs) {
  __shared__ int csh;
  u16 v = ((const u16*)jobs.s[0])[2 * threadIdx.x];
  int e = (v >> 7) & 0xFF;
  unsigned long long m = __ballot(e >= 0xC0);
  if (threadIdx.x == 0) csh = 0;
  __syncthreads();
  if ((threadIdx.x & 63) == 0) atomicAdd(&csh, __popcll(m));
  __syncthreads();
  bool isf32 = csh >= 8;       // 256 samples: f32 ~64 hits, bf16 ~0

  int j = blockIdx.y;
  int n4 = jobs.n[j] >> 2;     // all sizes divisible by 4
  const void* s = jobs.s[j];
  u16* d = jobs.d[j];
  for (int i = blockIdx.x * 256 + threadIdx.x; i < n4; i += gridDim.x * 256) {
    if (isf32) {
      f32x4 vv = *((const f32x4*)s + i);
      u16x4 o = {f2b(vv[0]), f2b(vv[1]), f2b(vv[2]), f2b(vv[3])};
      *((u16x4*)d + i) = o;
    } else {
      *((u16x4*)d + i) = *((const u16x4*)s + i);
    }
  }
}

// ---------------- LayerNorm (bf16 input) ----------------
__global__ __launch_bounds__(256) void ln_bf16_kernel(
    const u16* __restrict__ x, const u16* __restrict__ g,
    const u16* __restrict__ b, u16* __restrict__ out) {
  int row = blockIdx.x;
  int tid = threadIdx.x;
  const u16* xr = x + (size_t)row * DMODEL;
  float v0 = b2f(xr[tid]), v1 = b2f(xr[tid + 256]), v2 = b2f(xr[tid + 512]);
  float s = v0 + v1 + v2;
  float q = v0 * v0 + v1 * v1 + v2 * v2;
#pragma unroll
  for (int off = 32; off; off >>= 1) {
    s += __shfl_xor(s, off, 64);
    q += __shfl_xor(q, off, 64);
  }
  __shared__ float rs[4], rq[4];
  int wv = tid >> 6;
  if ((tid & 63) == 0) { rs[wv] = s; rq[wv] = q; }
  __syncthreads();
  s = rs[0] + rs[1] + rs[2] + rs[3];
  q = rq[0] + rq[1] + rq[2] + rq[3];
  float mean = s * (1.0f / 768.0f);
  float var = q * (1.0f / 768.0f) - mean * mean;
  float inv = rsqrtf(var + 1e-5f);
  u16* outr = out + (size_t)row * DMODEL;
  outr[tid]       = f2b((v0 - mean) * inv * b2f(g[tid])       + b2f(b[tid]));
  outr[tid + 256] = f2b((v1 - mean) * inv * b2f(g[tid + 256]) + b2f(b[tid + 256]));
  outr[tid + 512] = f2b((v2 - mean) * inv * b2f(g[tid + 512]) + b2f(b[tid + 512]));
}

// ---------------- LayerNorm (f32 input) ----------------
__global__ __launch_bounds__(256) void ln_f32_kernel(
    const float* __restrict__ x, const u16* __restrict__ g,
    const u16* __restrict__ b, u16* __restrict__ out) {
  int row = blockIdx.x;
  int tid = threadIdx.x;
  const float* xr = x + (size_t)row * DMODEL;
  float v0 = xr[tid], v1 = xr[tid + 256], v2 = xr[tid + 512];
  float s = v0 + v1 + v2;
  float q = v0 * v0 + v1 * v1 + v2 * v2;
#pragma unroll
  for (int off = 32; off; off >>= 1) {
    s += __shfl_xor(s, off, 64);
    q += __shfl_xor(q, off, 64);
  }
  __shared__ float rs[4], rq[4];
  int wv = tid >> 6;
  if ((tid & 63) == 0) { rs[wv] = s; rq[wv] = q; }
  __syncthreads();
  s = rs[0] + rs[1] + rs[2] + rs[3];
  q = rq[0] + rq[1] + rq[2] + rq[3];
  float mean = s * (1.0f / 768.0f);
  float var = q * (1.0f / 768.0f) - mean * mean;
  float inv = rsqrtf(var + 1e-5f);
  u16* outr = out + (size_t)row * DMODEL;
  outr[tid]       = f2b((v0 - mean) * inv * b2f(g[tid])       + b2f(b[tid]));
  outr[tid + 256] = f2b((v1 - mean) * inv * b2f(g[tid + 256]) + b2f(b[tid + 256]));
  outr[tid + 512] = f2b((v2 - mean) * inv * b2f(g[tid + 512]) + b2f(b[tid + 512]));
}

// ---------------- MFMA GEMM 128x64 tile, 3-ring pipelined, swizzled ----------
__global__ __launch_bounds__(256) void gemm_bt(
    const u16* __restrict__ Ap, const u16* __restrict__ Wp,
    const u16* __restrict__ bias, u16* __restrict__ Cp, int Nn, int K) {
  __shared__ __align__(16) u16 Al[3 * 128 * 32], Bl[3 * 64 * 32];
  int lane = threadIdx.x & 63;
  int wv = threadIdx.x >> 6;
  int q16 = lane & 15, quad = lane >> 4;
  int mB0 = blockIdx.y * 128;
  int nB0 = blockIdx.x * 64;
  int mW = (wv >> 1) * 64, nW = (wv & 1) * 32;
  int srow = lane >> 2;
  int scol = ((lane & 3) ^ ((lane >> 3) & 3)) * 8;   // inverse-swizzled source
  int sx8 = (quad ^ ((q16 >> 1) & 3)) * 8;           // swizzled read slot
  int r0 = wv * 32 + srow, r1 = r0 + 16;             // A rows this lane stages
  int rb = wv * 16 + srow;                           // B row 0..63
  const u16* Ag0 = Ap + (size_t)(mB0 + r0) * K + scol;
  const u16* Ag1 = Ap + (size_t)(mB0 + r1) * K + scol;
  const u16* Wg  = Wp + (size_t)(nB0 + rb) * K + scol;
  int ch0 = wv * 1024, ch1 = ch0 + 512, chb = wv * 512;
  int nsteps = K >> 5;                               // 24 (div by 3)
  f32x4 acc[4][2] = {};
#pragma unroll
  for (int tt = 0; tt < 2; ++tt) {
    int k0 = tt * 32;
    gl_lds16(Ag0 + k0, Al + tt * 4096 + ch0);
    gl_lds16(Ag1 + k0, Al + tt * 4096 + ch1);
    gl_lds16(Wg + k0, Bl + tt * 2048 + chb);
  }
  int n3 = nsteps / 3;
  for (int kb = 0; kb < n3; ++kb) {
#pragma unroll
    for (int c = 0; c < 3; ++c) {
      int t = kb * 3 + c;
      if (t < nsteps - 1) asm volatile("s_waitcnt vmcnt(3)" ::: "memory");
      else                asm volatile("s_waitcnt vmcnt(0)" ::: "memory");
      __builtin_amdgcn_sched_barrier(0);
      __builtin_amdgcn_s_barrier();
      __builtin_amdgcn_sched_barrier(0);
      if (t < nsteps - 2) {
        int k0 = (t + 2) * 32;
        int bs = (c + 2) % 3;
        gl_lds16(Ag0 + k0, Al + bs * 4096 + ch0);
        gl_lds16(Ag1 + k0, Al + bs * 4096 + ch1);
        gl_lds16(Wg + k0, Bl + bs * 2048 + chb);
      }
      const __bf16* Ab = (const __bf16*)(Al + c * 4096);
      const __bf16* Bb = (const __bf16*)(Bl + c * 2048);
      bf16x8 af[4], bfr[2];
#pragma unroll
      for (int si = 0; si < 4; ++si)
        af[si] = *(const bf16x8*)(Ab + (mW + si * 16 + q16) * 32 + sx8);
#pragma unroll
      for (int sj = 0; sj < 2; ++sj)
        bfr[sj] = *(const bf16x8*)(Bb + (nW + sj * 16 + q16) * 32 + sx8);
#pragma unroll
      for (int si = 0; si < 4; ++si)
#pragma unroll
        for (int sj = 0; sj < 2; ++sj)
          acc[si][sj] = __builtin_amdgcn_mfma_f32_16x16x32_bf16(af[si], bfr[sj], acc[si][sj], 0, 0, 0);
    }
  }
#pragma unroll
  for (int si = 0; si < 4; ++si)
#pragma unroll
    for (int sj = 0; sj < 2; ++sj) {
      int col = nB0 + nW + sj * 16 + q16;
      float bcol = b2f(bias[col]);
#pragma unroll
      for (int r = 0; r < 4; ++r) {
        int rowi = mB0 + mW + si * 16 + quad * 4 + r;
        Cp[(size_t)rowi * Nn + col] = f2b(acc[si][sj][r] + bcol);
      }
    }
}

// ---------------- final GEMM, 64x64 tiles, full K, ring-4/3-ahead ------------
// grid (12, 64) = 768 blocks. No split-K, no partial buffer, no add pass.
// Per wave/stage: 1 A chunk + 1 B chunk -> steady vmcnt(4) (2 youngest stages).
__global__ __launch_bounds__(256) void gemm_out_f32(
    const u16* __restrict__ Ap, const u16* __restrict__ Wp,
    const u16* __restrict__ bias, const float* __restrict__ res,
    float* __restrict__ out) {
  __shared__ __align__(16) u16 Al[4 * 64 * 32], Bl[4 * 64 * 32];   // 16+16 KB
  int lane = threadIdx.x & 63;
  int wv = threadIdx.x >> 6;
  int q16 = lane & 15, quad = lane >> 4;
  int mB0 = blockIdx.y * 64;
  int nB0 = blockIdx.x * 64;
  int mW = (wv >> 1) * 32, nW = (wv & 1) * 32;
  int srow = lane >> 2;
  int scol = ((lane & 3) ^ ((lane >> 3) & 3)) * 8;
  int sx8 = (quad ^ ((q16 >> 1) & 3)) * 8;
  int ra = wv * 16 + srow;                 // row this lane stages (0..63)
  const u16* Ag = Ap + (size_t)(mB0 + ra) * 2048 + scol;
  const u16* Wg = Wp + (size_t)(nB0 + ra) * 2048 + scol;
  int ch = wv * 512;
  f32x4 acc[2][2] = {};
#pragma unroll
  for (int tt = 0; tt < 3; ++tt) {
    gl_lds16(Ag + tt * 32, Al + tt * 2048 + ch);
    gl_lds16(Wg + tt * 32, Bl + tt * 2048 + ch);
  }
  for (int kb = 0; kb < 16; ++kb) {
#pragma unroll
    for (int c = 0; c < 4; ++c) {
      int t = kb * 4 + c;
      if (t < 62)       asm volatile("s_waitcnt vmcnt(4)" ::: "memory");
      else if (t == 62) asm volatile("s_waitcnt vmcnt(2)" ::: "memory");
      else              asm volatile("s_waitcnt vmcnt(0)" ::: "memory");
      __builtin_amdgcn_sched_barrier(0);
      __builtin_amdgcn_s_barrier();
      __builtin_amdgcn_sched_barrier(0);
      if (t < 61) {
        int k0 = (t + 3) * 32;
        int bs = (c + 3) & 3;
        gl_lds16(Ag + k0, Al + bs * 2048 + ch);
        gl_lds16(Wg + k0, Bl + bs * 2048 + ch);
      }
      const __bf16* Ab = (const __bf16*)(Al + c * 2048);
      const __bf16* Bb = (const __bf16*)(Bl + c * 2048);
      bf16x8 af[2], bfr[2];
#pragma unroll
      for (int si = 0; si < 2; ++si)
        af[si] = *(const bf16x8*)(Ab + (mW + si * 16 + q16) * 32 + sx8);
#pragma unroll
      for (int sj = 0; sj < 2; ++sj)
        bfr[sj] = *(const bf16x8*)(Bb + (nW + sj * 16 + q16) * 32 + sx8);
#pragma unroll
      for (int si = 0; si < 2; ++si)
#pragma unroll
        for (int sj = 0; sj < 2; ++sj)
          acc[si][sj] = __builtin_amdgcn_mfma_f32_16x16x32_bf16(af[si], bfr[sj], acc[si][sj], 0, 0, 0);
    }
  }
#pragma unroll
  for (int si = 0; si < 2; ++si)
#pragma unroll
    for (int sj = 0; sj < 2; ++sj) {
      int col = nB0 + nW + sj * 16 + q16;
      float bcol = b2f(bias[col]);
#pragma unroll
      for (int r = 0; r < 4; ++r) {
        int rowi = mB0 + mW + si * 16 + quad * 4 + r;
        size_t idx = (size_t)rowi * 768 + col;
        out[idx] = acc[si][sj][r] + bcol + res[idx];
      }
    }
}

// ---------------- fused FFN-in, 128x32 tile, ring-6 / 5-ahead ----------------
// grid (64, 32) = 2048 blocks. LDS 72KB -> 2 blocks/CU. 5-ahead prefetch
// (~750+ cyc cover) targets the L3/HBM-latency stall R7-R9 could not remove.
__global__ __launch_bounds__(256) void ffn_in_kernel(
    const u16* __restrict__ hp, const u16* __restrict__ Wp,
    const u16* __restrict__ bias, u16* __restrict__ actp) {
  __shared__ __align__(16) u16 Al[6 * 128 * 32], Bl[6 * 64 * 32];
  int lane = threadIdx.x & 63;
  int wv = threadIdx.x >> 6;
  int q16 = lane & 15, quad = lane >> 4;
  int mB0 = blockIdx.y * 128;
  int cB0 = blockIdx.x * 32;
  int mW = (wv >> 1) * 64;
  int cW = (wv & 1) * 16;
  int srow = lane >> 2;
  int scol = ((lane & 3) ^ ((lane >> 3) & 3)) * 8;
  int sx8 = (quad ^ ((q16 >> 1) & 3)) * 8;
  int r0 = wv * 32 + srow, r1 = r0 + 16;   // A rows
  int rb = wv * 16 + srow;                 // B row 0..63
  int gb = (rb < 32) ? (cB0 + rb) : (HIDDIM + cB0 + rb - 32);
  const u16* Ag0 = hp + (size_t)(mB0 + r0) * DMODEL + scol;
  const u16* Ag1 = hp + (size_t)(mB0 + r1) * DMODEL + scol;
  const u16* Wg  = Wp + (size_t)gb * DMODEL + scol;
  int ch0 = wv * 1024, ch1 = ch0 + 512, chb = wv * 512;
  f32x4 au[4] = {}, ag[4] = {};
#pragma unroll
  for (int tt = 0; tt < 5; ++tt) {
    int k0 = tt * 32;
    gl_lds16(Ag0 + k0, Al + tt * 4096 + ch0);
    gl_lds16(Ag1 + k0, Al + tt * 4096 + ch1);
    gl_lds16(Wg + k0, Bl + tt * 2048 + chb);
  }
  for (int kb = 0; kb < 4; ++kb) {
#pragma unroll
    for (int c = 0; c < 6; ++c) {
      int t = kb * 6 + c;
      if (t < 20)       asm volatile("s_waitcnt vmcnt(12)" ::: "memory");
      else if (t == 20) asm volatile("s_waitcnt vmcnt(9)" ::: "memory");
      else if (t == 21) asm volatile("s_waitcnt vmcnt(6)" ::: "memory");
      else if (t == 22) asm volatile("s_waitcnt vmcnt(3)" ::: "memory");
      else              asm volatile("s_waitcnt vmcnt(0)" ::: "memory");
      __builtin_amdgcn_sched_barrier(0);
      __builtin_amdgcn_s_barrier();
      __builtin_amdgcn_sched_barrier(0);
      if (t < 19) {
        int k0 = (t + 5) * 32;
        int bs = (c + 5) % 6;
        gl_lds16(Ag0 + k0, Al + bs * 4096 + ch0);
        gl_lds16(Ag1 + k0, Al + bs * 4096 + ch1);
        gl_lds16(Wg + k0, Bl + bs * 2048 + chb);
      }
      const __bf16* Ab = (const __bf16*)(Al + c * 4096);
      const __bf16* Bb = (const __bf16*)(Bl + c * 2048);
      bf16x8 af[4], wu, wg;
#pragma unroll
      for (int si = 0; si < 4; ++si)
        af[si] = *(const bf16x8*)(Ab + (mW + si * 16 + q16) * 32 + sx8);
      wu = *(const bf16x8*)(Bb + (cW + q16) * 32 + sx8);
      wg = *(const bf16x8*)(Bb + (32 + cW + q16) * 32 + sx8);
#pragma unroll
      for (int si = 0; si < 4; ++si) {
        au[si] = __builtin_amdgcn_mfma_f32_16x16x32_bf16(af[si], wu, au[si], 0, 0, 0);
        ag[si] = __builtin_amdgcn_mfma_f32_16x16x32_bf16(af[si], wg, ag[si], 0, 0, 0);
      }
    }
  }
  int col = cB0 + cW + q16;
  float bu = b2f(bias[col]);
  float bg = b2f(bias[HIDDIM + col]);
#pragma unroll
  for (int si = 0; si < 4; ++si) {
#pragma unroll
    for (int r = 0; r < 4; ++r) {
      int rowi = mB0 + mW + si * 16 + quad * 4 + r;
      float u = au[si][r] + bu;
      float g = ag[si][r] + bg;
      float s = u / (1.0f + __expf(-u));
      actp[(size_t)rowi * HIDDIM + col] = f2b(s * g);
    }
  }
}

// ---------------- V transpose + fused coord-bias p ---------------------------
// Vt[b][h][d][n] = V[b][n][h][d]; blocks with (rem&15)==0 also compute the
// p2-row for their (b,h): p2 = (coords . relw) * LOG2E.
__global__ __launch_bounds__(256) void vt_kernel(const u16* __restrict__ qkvp,
                                                 u16* __restrict__ vtp,
                                                 const u16* __restrict__ coords,
                                                 const u16* __restrict__ relw,
                                                 float* __restrict__ p) {
  int blk = blockIdx.x;            // b*192 + h*16 + nt
  int b = blk / 192;
  int rem = blk % 192;
  int h = rem >> 4;
  int nt = rem & 15;
  int wv = threadIdx.x >> 6;
  int d = threadIdx.x & 63;
  int n0 = nt * 64 + wv * 16;
  const u16* src = qkvp + ((size_t)(b * NTOK) + n0) * LD3 + 2 * DMODEL + h * 64 + d;
  u16* dst = vtp + ((size_t)((b * NHEAD + h) * 64 + d)) * NTOK + n0;
#pragma unroll
  for (int c = 0; c < 2; ++c) {
    u16 buf[8] __attribute__((aligned(16)));
#pragma unroll
    for (int i = 0; i < 8; ++i) buf[i] = src[(size_t)(c * 8 + i) * LD3];
    *(uint4*)(dst + c * 8) = *(const uint4*)buf;
  }
  if (nt == 0) {   // one block per (b,h): fused p-row
    const float LOG2E = 1.4426950408889634f;
    float w0 = b2f(relw[h * 3 + 0]), w1 = b2f(relw[h * 3 + 1]), w2 = b2f(relw[h * 3 + 2]);
    float* prow = p + (size_t)(b * NHEAD + h) * NTOK;
    for (int n = threadIdx.x; n < NTOK; n += 256) {
      int idx = b * NTOK + n;
      float c0 = b2f(coords[idx * 3 + 0]);
      float c1 = b2f(coords[idx * 3 + 1]);
      float c2 = b2f(coords[idx * 3 + 2]);
      prow[n] = (c0 * w0 + c1 * w1 + c2 * w2) * LOG2E;
    }
  }
}

// ---------------- flash attention: XCD-local heads, 4-deep counted pipeline --
__global__ __launch_bounds__(256) void attn_kernel(
    const u16* __restrict__ qkvp, const u16* __restrict__ vtp,
    const float* __restrict__ p2, const u16* __restrict__ xp,
    float* __restrict__ x1) {
  const __bf16* qb = (const __bf16*)qkvp;
  __shared__ __align__(16) u16 Kl[4][32 * 64];   // [j][d], slot swz by j&7
  __shared__ __align__(16) u16 Vl[4][64 * 32];   // [d][j], slot swz by (d>>1)&3
  __shared__ __align__(16) u16 Pl[4][16][40];    // 80B row stride
  __shared__ __align__(16) float Pb[1024];       // p-row (pre-scaled by LOG2E)
  int lane = threadIdx.x & 63;
  int wv = threadIdx.x >> 6;
  int hw = blockIdx.x;                     // 0..767
  int g = hw % 48;                         // (b,h): all its 16 tiles same XCD
  int nt = hw / 48;                        // query-tile group 0..15
  int b = g / 12, h = g % 12;
  int i0 = (nt * 4 + wv) * 16;             // wave's query tile
  int q16 = lane & 15, quad = lane >> 4;

  const float scl2 = 0.125f * 1.4426950408889634f;

  const __bf16* qrow = qb + ((size_t)(b * NTOK) + i0 + q16) * LD3 + h * 64;
  bf16x8 bq0 = *(const bf16x8*)(qrow + quad * 8);
  bf16x8 bq1 = *(const bf16x8*)(qrow + 32 + quad * 8);

  const float* prow = p2 + (size_t)(b * NHEAD + h) * NTOK;

  int krw = wv * 8 + (lane >> 3);          // K row 0..31 this lane stages
  int ks  = (lane & 7) ^ (krw & 7);        // swizzled 16B slot (8 per 128B row)
  const u16* kg0 = qkvp + (size_t)(b * NTOK) * LD3 + DMODEL + h * 64 + ks * 8;
  int vrw = wv * 16 + (lane >> 2);         // Vt row (d) 0..63
  int vs  = (lane & 3) ^ ((vrw >> 1) & 3); // swizzled 16B slot (4 per 64B row)
  const u16* vg0 = vtp + ((size_t)((b * NHEAD + h) * 64 + vrw)) * NTOK + vs * 8;

  // hoisted read-slot constants
  int kx0 = (quad ^ (q16 & 7)) << 3;
  int kx1 = ((4 | quad) ^ (q16 & 7)) << 3;
  int vx  = (quad ^ ((q16 >> 1) & 3)) << 3;

  float mrun = -1e30f, lsum = 0.f;
  f32x4 accO[4] = {};

  // prologue: p-row + tiles 0..2 (7 outstanding loads/wave)
  gl_lds16((const u16*)(prow + wv * 256 + lane * 4), (u16*)&Pb[wv * 256]);
#pragma unroll
  for (int tt = 0; tt < 3; ++tt) {
    gl_lds16(kg0 + (size_t)(tt * 32 + krw) * LD3, &Kl[tt][wv * 512]);
    gl_lds16(vg0 + tt * 32, &Vl[tt][wv * 512]);
  }

  for (int kb = 0; kb < 8; ++kb) {
#pragma unroll
    for (int c = 0; c < 4; ++c) {
      int t = kb * 4 + c;
      if (t < 30)       asm volatile("s_waitcnt vmcnt(4)" ::: "memory");
      else if (t == 30) asm volatile("s_waitcnt vmcnt(2)" ::: "memory");
      else              asm volatile("s_waitcnt vmcnt(0)" ::: "memory");
      __builtin_amdgcn_sched_barrier(0);
      __builtin_amdgcn_s_barrier();            // all waves' stage(t) landed
      __builtin_amdgcn_sched_barrier(0);
      if (t < 29) {                            // stage(t+3) into buf (c+3)&3
        int j = (t + 3) * 32;
        gl_lds16(kg0 + (size_t)(j + krw) * LD3, &Kl[(c + 3) & 3][wv * 512]);
        gl_lds16(vg0 + j, &Vl[(c + 3) & 3][wv * 512]);
      }

      int j0 = t * 32;
      const __bf16* Kb = (const __bf16*)Kl[c];
      bf16x8 ka00 = *(const bf16x8*)(Kb + q16 * 64 + kx0);
      bf16x8 ka01 = *(const bf16x8*)(Kb + q16 * 64 + kx1);
      bf16x8 ka10 = *(const bf16x8*)(Kb + (16 + q16) * 64 + kx0);
      bf16x8 ka11 = *(const bf16x8*)(Kb + (16 + q16) * 64 + kx1);
      f32x4 st0 = {}, st1 = {};
      st0 = __builtin_amdgcn_mfma_f32_16x16x32_bf16(ka00, bq0, st0, 0, 0, 0);
      st0 = __builtin_amdgcn_mfma_f32_16x16x32_bf16(ka01, bq1, st0, 0, 0, 0);
      st1 = __builtin_amdgcn_mfma_f32_16x16x32_bf16(ka10, bq0, st1, 0, 0, 0);
      st1 = __builtin_amdgcn_mfma_f32_16x16x32_bf16(ka11, bq1, st1, 0, 0, 0);

      f32x4 pjl = *(const f32x4*)(&Pb[j0 + 4 * quad]);
      f32x4 pjh = *(const f32x4*)(&Pb[j0 + 16 + 4 * quad]);
      float sl[4], sh[4];
#pragma unroll
      for (int r = 0; r < 4; ++r) {
        sl[r] = st0[r] * scl2 - pjl[r];
        sh[r] = st1[r] * scl2 - pjh[r];
      }
      float lm = fmaxf(fmaxf(fmaxf(sl[0], sl[1]), fmaxf(sl[2], sl[3])),
                       fmaxf(fmaxf(sh[0], sh[1]), fmaxf(sh[2], sh[3])));
      lm = fmaxf(lm, __shfl_xor(lm, 16, 64));
      lm = fmaxf(lm, __shfl_xor(lm, 32, 64));
      float mn = fmaxf(mrun, lm);
      float alpha = exp2f(mrun - mn);
      mrun = mn;
      float pl[4], ph[4];
#pragma unroll
      for (int r = 0; r < 4; ++r) {
        pl[r] = exp2f(sl[r] - mn);
        ph[r] = exp2f(sh[r] - mn);
      }
      float ts = (pl[0] + pl[1]) + (pl[2] + pl[3]) +
                 (ph[0] + ph[1]) + (ph[2] + ph[3]);
      ts += __shfl_xor(ts, 16, 64);
      ts += __shfl_xor(ts, 32, 64);
      lsum = lsum * alpha + ts;

      bf16x4 w0 = {(__bf16)pl[0], (__bf16)pl[1], (__bf16)pl[2], (__bf16)pl[3]};
      bf16x4 w1 = {(__bf16)ph[0], (__bf16)ph[1], (__bf16)ph[2], (__bf16)ph[3]};
      *(bf16x4*)(&Pl[wv][q16][4 * quad]) = w0;
      *(bf16x4*)(&Pl[wv][q16][16 + 4 * quad]) = w1;
      bf16x8 ap = *(const bf16x8*)(&Pl[wv][q16][quad * 8]);  // wave-private

      const __bf16* Vb = (const __bf16*)Vl[c];
#pragma unroll
      for (int ds = 0; ds < 4; ++ds) {
        bf16x8 av = *(const bf16x8*)(Vb + (ds * 16 + q16) * 32 + vx);
        f32x4 cc = accO[ds];
#pragma unroll
        for (int r = 0; r < 4; ++r) cc[r] *= alpha;
        accO[ds] = __builtin_amdgcn_mfma_f32_16x16x32_bf16(av, ap, cc, 0, 0, 0);
      }
    }
  }

  float rl = 1.0f / lsum;
  size_t rowbase = ((size_t)(b * NTOK) + i0 + q16) * DMODEL + h * 64;
#pragma unroll
  for (int ds = 0; ds < 4; ++ds) {
    int d0 = ds * 16 + quad * 4;
    u16x4 xv = *(const u16x4*)(xp + rowbase + d0);
    f32x4 ov;
#pragma unroll
    for (int r = 0; r < 4; ++r) ov[r] = b2f(xv[r]) + accO[ds][r] * rl;
    *(f32x4*)(x1 + rowbase + d0) = ov;
  }
}

extern "C" void kernel_launch(void* const* d_in, const int* in_sizes, int n_in,
                              void* d_out, int out_size, void* d_ws, size_t ws_size,
                              hipStream_t stream) {
  // ---- host-side boundary tripwires (verified passing in R6) ----
  static const int esz[13] = {3145728, 12288, 768, 768, 1769472, 2304, 36,
                              768, 768, 3145728, 4096, 1572864, 768};
  float sig = -1.f;
  if (n_in != 13) {
    sig = 6000.f + 100.f * (float)n_in;
  } else {
    for (int i = 0; i < 13; ++i)
      if (in_sizes[i] != esz[i]) { sig = 1000.f + 100.f * (float)i; break; }
  }
  if (sig < 0.f && ws_size < 57258496ULL) sig = 3000.f;
  if (sig < 0.f && out_size != 3145728) sig = 3100.f;
  if (sig >= 0.f) {
    signal_kernel<<<(out_size + 255) / 256, 256, 0, stream>>>((float*)d_out, out_size, sig);
    return;
  }

  char* ws = (char*)d_ws;
  u16*  cx      = (u16*)(ws + 256);               // 6291456
  u16*  cqkvw   = (u16*)(ws + 6291712);           // 3538944
  u16*  cwinw   = (u16*)(ws + 9830656);           // 6291456
  u16*  cwoutw  = (u16*)(ws + 16122112);          // 3145728
  u16*  ccoords = (u16*)(ws + 19267840);          // 24576
  u16*  cln1g   = (u16*)(ws + 19292416);          // 1536
  u16*  cln1b   = (u16*)(ws + 19293952);          // 1536
  u16*  cqkvb   = (u16*)(ws + 19295488);          // 4608
  u16*  crelw   = (u16*)(ws + 19300096);          // 72 (padded)
  u16*  cln2g   = (u16*)(ws + 19300352);          // 1536
  u16*  cln2b   = (u16*)(ws + 19301888);          // 1536
  u16*  cwinb   = (u16*)(ws + 19303424);          // 8192
  u16*  cwoutb  = (u16*)(ws + 19311616);          // 1536
  u16*  h       = (u16*)(ws + 19313152);          // 6291456 (LN out; reused as Vt)
  u16*  qkv     = (u16*)(ws + 25604608);          // 18874368 (reused as act)
  float* pbuf   = (float*)(ws + 44478976);        // 196608
  float* x1     = (float*)(ws + 44675584);        // 12582912 -> end 57258496
  u16*  act     = qkv;
  u16*  vt      = h;       // Vt needs 6291456 B == sizeof(h)

  // 0. canonicalize all 13 inputs to bf16 (inline dtype-detect, vectorized x4)
  CanonJobs jobs;
  u16* dsts[13] = {cx, ccoords, cln1g, cln1b, cqkvw, cqkvb, crelw,
                   cln2g, cln2b, cwinw, cwinb, cwoutw, cwoutb};
  for (int i = 0; i < 13; ++i) {
    jobs.s[i] = d_in[i];
    jobs.d[i] = dsts[i];
    jobs.n[i] = in_sizes[i];
  }
  canon_kernel<<<dim3(768, 13), 256, 0, stream>>>(jobs);

  // 1. h = LN1(x)
  ln_bf16_kernel<<<4096, 256, 0, stream>>>(cx, cln1g, cln1b, h);
  // 2. qkv = h @ qkv_w^T + qkv_b   (M=4096, N=2304, K=768; 128x64 tiles)
  gemm_bt<<<dim3(36, 32), 256, 0, stream>>>(h, cqkvw, cqkvb, qkv, 2304, 768);
  // 3. Vt[b][h][d][n] = V  + fused p2 computation (h buffer dead here)
  vt_kernel<<<768, 256, 0, stream>>>(qkv, vt, ccoords, crelw, pbuf);
  // 4. x1 = x + attention(qkv, Vt, p2)   (768 blocks; XCD-local + deep pipeline)
  attn_kernel<<<768, 256, 0, stream>>>(qkv, vt, pbuf, cx, x1);
  // 5. h2 = LN2(x1)  (reuse h)
  ln_f32_kernel<<<4096, 256, 0, stream>>>(x1, cln2g, cln2b, h);
  // 6+7. act = silu(h2 @ Wu^T + bu) * (h2 @ Wg^T + bg)   (ring-6 / 5-ahead)
  ffn_in_kernel<<<dim3(64, 32), 256, 0, stream>>>(h, cwinw, cwinb, act);
  // 8. out(F32) = x1 + act @ wout_w^T + wout_b   (64x64 tiles, 768 blocks)
  gemm_out_f32<<<dim3(12, 64), 256, 0, stream>>>(act, cwoutw, cwoutb, x1,
                                                 (float*)d_out);
}

// Round 12
// 275.319 us; speedup vs baseline: 1.0606x; 1.0431x over previous
//
#include <hip/hip_runtime.h>
#include <math.h>

typedef unsigned short u16;
typedef __bf16 bf16x8 __attribute__((ext_vector_type(8)));
typedef __bf16 bf16x4 __attribute__((ext_vector_type(4)));
typedef u16 u16x4 __attribute__((ext_vector_type(4)));
typedef float f32x4 __attribute__((ext_vector_type(4)));

// ---- constants ----
// B=4, N=1024, D=768, H=12, Dh=64, HID=2048, 3D=2304
#define NTOK 1024
#define DMODEL 768
#define NHEAD 12
#define LD3 2304
#define HIDDIM 2048

__device__ __forceinline__ float b2f(u16 u) {
  unsigned int t = ((unsigned int)u) << 16;
  float f;
  __builtin_memcpy(&f, &t, 4);
  return f;
}
__device__ __forceinline__ u16 f2b(float f) {
  unsigned int t;
  __builtin_memcpy(&t, &f, 4);
  t += 0x7fffu + ((t >> 16) & 1u);
  return (u16)(t >> 16);
}

// async global->LDS, 16B per lane; LDS dest is wave-uniform base + lane*16
__device__ __forceinline__ void gl_lds16(const u16* g, u16* l) {
  __builtin_amdgcn_global_load_lds(
      (__attribute__((address_space(1))) const unsigned int*)g,
      (__attribute__((address_space(3))) unsigned int*)l, 16, 0, 0);
}

// ---------------- host-assert signal (f32 output now) ------------------------
__global__ __launch_bounds__(256) void signal_kernel(float* __restrict__ out,
                                                     int n, float c) {
  int i = blockIdx.x * 256 + threadIdx.x;
  if (i < n) out[i] = c;
}

// ---------------- canonicalize all inputs to bf16 (inline dtype-detect) ------
struct CanonJobs {
  const void* s[13];
  u16* d[13];
  int n[13];
};

__global__ __launch_bounds__(256) void canon_kernel(CanonJobs jobs) {
  __shared__ int csh;
  u16 v = ((const u16*)jobs.s[0])[2 * threadIdx.x];
  int e = (v >> 7) & 0xFF;
  unsigned long long m = __ballot(e >= 0xC0);
  if (threadIdx.x == 0) csh = 0;
  __syncthreads();
  if ((threadIdx.x & 63) == 0) atomicAdd(&csh, __popcll(m));
  __syncthreads();
  bool isf32 = csh >= 8;       // 256 samples: f32 ~64 hits, bf16 ~0

  int j = blockIdx.y;
  int n4 = jobs.n[j] >> 2;     // all sizes divisible by 4
  const void* s = jobs.s[j];
  u16* d = jobs.d[j];
  for (int i = blockIdx.x * 256 + threadIdx.x; i < n4; i += gridDim.x * 256) {
    if (isf32) {
      f32x4 vv = *((const f32x4*)s + i);
      u16x4 o = {f2b(vv[0]), f2b(vv[1]), f2b(vv[2]), f2b(vv[3])};
      *((u16x4*)d + i) = o;
    } else {
      *((u16x4*)d + i) = *((const u16x4*)s + i);
    }
  }
}

// ---------------- LayerNorm (bf16 input) ----------------
__global__ __launch_bounds__(256) void ln_bf16_kernel(
    const u16* __restrict__ x, const u16* __restrict__ g,
    const u16* __restrict__ b, u16* __restrict__ out) {
  int row = blockIdx.x;
  int tid = threadIdx.x;
  const u16* xr = x + (size_t)row * DMODEL;
  float v0 = b2f(xr[tid]), v1 = b2f(xr[tid + 256]), v2 = b2f(xr[tid + 512]);
  float s = v0 + v1 + v2;
  float q = v0 * v0 + v1 * v1 + v2 * v2;
#pragma unroll
  for (int off = 32; off; off >>= 1) {
    s += __shfl_xor(s, off, 64);
    q += __shfl_xor(q, off, 64);
  }
  __shared__ float rs[4], rq[4];
  int wv = tid >> 6;
  if ((tid & 63) == 0) { rs[wv] = s; rq[wv] = q; }
  __syncthreads();
  s = rs[0] + rs[1] + rs[2] + rs[3];
  q = rq[0] + rq[1] + rq[2] + rq[3];
  float mean = s * (1.0f / 768.0f);
  float var = q * (1.0f / 768.0f) - mean * mean;
  float inv = rsqrtf(var + 1e-5f);
  u16* outr = out + (size_t)row * DMODEL;
  outr[tid]       = f2b((v0 - mean) * inv * b2f(g[tid])       + b2f(b[tid]));
  outr[tid + 256] = f2b((v1 - mean) * inv * b2f(g[tid + 256]) + b2f(b[tid + 256]));
  outr[tid + 512] = f2b((v2 - mean) * inv * b2f(g[tid + 512]) + b2f(b[tid + 512]));
}

// ---------------- LayerNorm (f32 input) ----------------
__global__ __launch_bounds__(256) void ln_f32_kernel(
    const float* __restrict__ x, const u16* __restrict__ g,
    const u16* __restrict__ b, u16* __restrict__ out) {
  int row = blockIdx.x;
  int tid = threadIdx.x;
  const float* xr = x + (size_t)row * DMODEL;
  float v0 = xr[tid], v1 = xr[tid + 256], v2 = xr[tid + 512];
  float s = v0 + v1 + v2;
  float q = v0 * v0 + v1 * v1 + v2 * v2;
#pragma unroll
  for (int off = 32; off; off >>= 1) {
    s += __shfl_xor(s, off, 64);
    q += __shfl_xor(q, off, 64);
  }
  __shared__ float rs[4], rq[4];
  int wv = tid >> 6;
  if ((tid & 63) == 0) { rs[wv] = s; rq[wv] = q; }
  __syncthreads();
  s = rs[0] + rs[1] + rs[2] + rs[3];
  q = rq[0] + rq[1] + rq[2] + rq[3];
  float mean = s * (1.0f / 768.0f);
  float var = q * (1.0f / 768.0f) - mean * mean;
  float inv = rsqrtf(var + 1e-5f);
  u16* outr = out + (size_t)row * DMODEL;
  outr[tid]       = f2b((v0 - mean) * inv * b2f(g[tid])       + b2f(b[tid]));
  outr[tid + 256] = f2b((v1 - mean) * inv * b2f(g[tid + 256]) + b2f(b[tid + 256]));
  outr[tid + 512] = f2b((v2 - mean) * inv * b2f(g[tid + 512]) + b2f(b[tid + 512]));
}

// ---------------- MFMA GEMM 128x64 tile, 3-ring pipelined, swizzled ----------
__global__ __launch_bounds__(256) void gemm_bt(
    const u16* __restrict__ Ap, const u16* __restrict__ Wp,
    const u16* __restrict__ bias, u16* __restrict__ Cp, int Nn, int K) {
  __shared__ __align__(16) u16 Al[3 * 128 * 32], Bl[3 * 64 * 32];
  int lane = threadIdx.x & 63;
  int wv = threadIdx.x >> 6;
  int q16 = lane & 15, quad = lane >> 4;
  int mB0 = blockIdx.y * 128;
  int nB0 = blockIdx.x * 64;
  int mW = (wv >> 1) * 64, nW = (wv & 1) * 32;
  int srow = lane >> 2;
  int scol = ((lane & 3) ^ ((lane >> 3) & 3)) * 8;   // inverse-swizzled source
  int sx8 = (quad ^ ((q16 >> 1) & 3)) * 8;           // swizzled read slot
  int r0 = wv * 32 + srow, r1 = r0 + 16;             // A rows this lane stages
  int rb = wv * 16 + srow;                           // B row 0..63
  const u16* Ag0 = Ap + (size_t)(mB0 + r0) * K + scol;
  const u16* Ag1 = Ap + (size_t)(mB0 + r1) * K + scol;
  const u16* Wg  = Wp + (size_t)(nB0 + rb) * K + scol;
  int ch0 = wv * 1024, ch1 = ch0 + 512, chb = wv * 512;
  int nsteps = K >> 5;                               // 24 (div by 3)
  f32x4 acc[4][2] = {};
#pragma unroll
  for (int tt = 0; tt < 2; ++tt) {
    int k0 = tt * 32;
    gl_lds16(Ag0 + k0, Al + tt * 4096 + ch0);
    gl_lds16(Ag1 + k0, Al + tt * 4096 + ch1);
    gl_lds16(Wg + k0, Bl + tt * 2048 + chb);
  }
  int n3 = nsteps / 3;
  for (int kb = 0; kb < n3; ++kb) {
#pragma unroll
    for (int c = 0; c < 3; ++c) {
      int t = kb * 3 + c;
      if (t < nsteps - 1) asm volatile("s_waitcnt vmcnt(3)" ::: "memory");
      else                asm volatile("s_waitcnt vmcnt(0)" ::: "memory");
      __builtin_amdgcn_sched_barrier(0);
      __builtin_amdgcn_s_barrier();
      __builtin_amdgcn_sched_barrier(0);
      if (t < nsteps - 2) {
        int k0 = (t + 2) * 32;
        int bs = (c + 2) % 3;
        gl_lds16(Ag0 + k0, Al + bs * 4096 + ch0);
        gl_lds16(Ag1 + k0, Al + bs * 4096 + ch1);
        gl_lds16(Wg + k0, Bl + bs * 2048 + chb);
      }
      const __bf16* Ab = (const __bf16*)(Al + c * 4096);
      const __bf16* Bb = (const __bf16*)(Bl + c * 2048);
      bf16x8 af[4], bfr[2];
#pragma unroll
      for (int si = 0; si < 4; ++si)
        af[si] = *(const bf16x8*)(Ab + (mW + si * 16 + q16) * 32 + sx8);
#pragma unroll
      for (int sj = 0; sj < 2; ++sj)
        bfr[sj] = *(const bf16x8*)(Bb + (nW + sj * 16 + q16) * 32 + sx8);
#pragma unroll
      for (int si = 0; si < 4; ++si)
#pragma unroll
        for (int sj = 0; sj < 2; ++sj)
          acc[si][sj] = __builtin_amdgcn_mfma_f32_16x16x32_bf16(af[si], bfr[sj], acc[si][sj], 0, 0, 0);
    }
  }
#pragma unroll
  for (int si = 0; si < 4; ++si)
#pragma unroll
    for (int sj = 0; sj < 2; ++sj) {
      int col = nB0 + nW + sj * 16 + q16;
      float bcol = b2f(bias[col]);
#pragma unroll
      for (int r = 0; r < 4; ++r) {
        int rowi = mB0 + mW + si * 16 + quad * 4 + r;
        Cp[(size_t)rowi * Nn + col] = f2b(acc[si][sj][r] + bcol);
      }
    }
}

// ---------------- final GEMM, 64x64 tiles, BK=64 double-buffer ---------------
// grid (12, 64) = 768 blocks. 32 K-steps of 64 -> 32 barriers (was 64).
// Per stage/wave: 2 A + 2 B chunks (1KB each). LDS 32KB.
// Row-swizzle: slot = s ^ (row&7); stage source slot = (lane&7)^(lane>>3).
__global__ __launch_bounds__(256) void gemm_out_f32(
    const u16* __restrict__ Ap, const u16* __restrict__ Wp,
    const u16* __restrict__ bias, const float* __restrict__ res,
    float* __restrict__ out) {
  __shared__ __align__(16) u16 Al[2 * 4096], Bl[2 * 4096];   // 16+16 KB
  int lane = threadIdx.x & 63;
  int wv = threadIdx.x >> 6;
  int q16 = lane & 15, quad = lane >> 4;
  int mB0 = blockIdx.y * 64;
  int nB0 = blockIdx.x * 64;
  int mW = (wv >> 1) * 32, nW = (wv & 1) * 32;
  int lr = lane >> 3, ls = lane & 7;
  int sg = (ls ^ lr) * 8;                       // inverse-swizzled source slot
  int sx0 = (quad ^ (q16 & 7)) * 8;             // read slot, k-half 0
  int sx1 = ((4 | quad) ^ (q16 & 7)) * 8;       // read slot, k-half 1
  // chunks: A rows wv*16 + i*8 + lr (i<2); B same
  const u16* Ag = Ap + (size_t)(mB0 + wv * 16 + lr) * 2048 + sg;
  const u16* Wg = Wp + (size_t)(nB0 + wv * 16 + lr) * 2048 + sg;
  int ch = wv * 1024;
  f32x4 acc[2][2] = {};
#pragma unroll
  for (int i = 0; i < 2; ++i) {
    gl_lds16(Ag + (size_t)i * 8 * 2048, Al + ch + i * 512);
    gl_lds16(Wg + (size_t)i * 8 * 2048, Bl + ch + i * 512);
  }
  for (int kb = 0; kb < 16; ++kb) {
#pragma unroll
    for (int c = 0; c < 2; ++c) {
      int t = kb * 2 + c;
      asm volatile("s_waitcnt vmcnt(0)" ::: "memory");
      __builtin_amdgcn_sched_barrier(0);
      __builtin_amdgcn_s_barrier();
      __builtin_amdgcn_sched_barrier(0);
      if (t < 31) {
        int k0 = (t + 1) * 64;
        int bs = c ^ 1;
#pragma unroll
        for (int i = 0; i < 2; ++i) {
          gl_lds16(Ag + (size_t)i * 8 * 2048 + k0, Al + bs * 4096 + ch + i * 512);
          gl_lds16(Wg + (size_t)i * 8 * 2048 + k0, Bl + bs * 4096 + ch + i * 512);
        }
      }
      const __bf16* Ab = (const __bf16*)(Al + c * 4096);
      const __bf16* Bb = (const __bf16*)(Bl + c * 4096);
      bf16x8 a0[2], a1[2], b0[2], b1[2];
#pragma unroll
      for (int si = 0; si < 2; ++si) {
        a0[si] = *(const bf16x8*)(Ab + (mW + si * 16 + q16) * 64 + sx0);
        a1[si] = *(const bf16x8*)(Ab + (mW + si * 16 + q16) * 64 + sx1);
      }
#pragma unroll
      for (int sj = 0; sj < 2; ++sj) {
        b0[sj] = *(const bf16x8*)(Bb + (nW + sj * 16 + q16) * 64 + sx0);
        b1[sj] = *(const bf16x8*)(Bb + (nW + sj * 16 + q16) * 64 + sx1);
      }
#pragma unroll
      for (int si = 0; si < 2; ++si)
#pragma unroll
        for (int sj = 0; sj < 2; ++sj) {
          acc[si][sj] = __builtin_amdgcn_mfma_f32_16x16x32_bf16(a0[si], b0[sj], acc[si][sj], 0, 0, 0);
          acc[si][sj] = __builtin_amdgcn_mfma_f32_16x16x32_bf16(a1[si], b1[sj], acc[si][sj], 0, 0, 0);
        }
    }
  }
#pragma unroll
  for (int si = 0; si < 2; ++si)
#pragma unroll
    for (int sj = 0; sj < 2; ++sj) {
      int col = nB0 + nW + sj * 16 + q16;
      float bcol = b2f(bias[col]);
#pragma unroll
      for (int r = 0; r < 4; ++r) {
        int rowi = mB0 + mW + si * 16 + quad * 4 + r;
        size_t idx = (size_t)rowi * 768 + col;
        out[idx] = acc[si][sj][r] + bcol + res[idx];
      }
    }
}

// ---------------- fused FFN-in, 128x32 tile, BK=64 double-buffer -------------
// grid (64, 32) = 2048 blocks. 12 K-steps of 64 -> 12 barriers (was 24).
// Per stage/wave: 4 A + 2 B chunks. LDS 48KB -> 3 blocks/CU (R7-best occ).
__global__ __launch_bounds__(256) void ffn_in_kernel(
    const u16* __restrict__ hp, const u16* __restrict__ Wp,
    const u16* __restrict__ bias, u16* __restrict__ actp) {
  __shared__ __align__(16) u16 Al[2 * 8192], Bl[2 * 4096];   // 32+16 KB
  int lane = threadIdx.x & 63;
  int wv = threadIdx.x >> 6;
  int q16 = lane & 15, quad = lane >> 4;
  int mB0 = blockIdx.y * 128;
  int cB0 = blockIdx.x * 32;
  int mW = (wv >> 1) * 64;
  int cW = (wv & 1) * 16;
  int lr = lane >> 3, ls = lane & 7;
  int sg = (ls ^ lr) * 8;
  int sx0 = (quad ^ (q16 & 7)) * 8;
  int sx1 = ((4 | quad) ^ (q16 & 7)) * 8;
  // A chunks i<4: rows wv*32 + i*8 + lr
  const u16* Ag = hp + (size_t)(mB0 + wv * 32 + lr) * DMODEL + sg;
  // B chunks i<2: rows wv*16 + i*8 + lr; <32 -> Wu, >=32 -> Wg
  int rB0 = wv * 16 + lr, rB1 = rB0 + 8;
  int gb0 = (rB0 < 32) ? (cB0 + rB0) : (HIDDIM + cB0 + rB0 - 32);
  int gb1 = (rB1 < 32) ? (cB0 + rB1) : (HIDDIM + cB0 + rB1 - 32);
  const u16* Wg0 = Wp + (size_t)gb0 * DMODEL + sg;
  const u16* Wg1 = Wp + (size_t)gb1 * DMODEL + sg;
  int chA = wv * 2048, chB = wv * 1024;
  f32x4 au[4] = {}, ag[4] = {};
#pragma unroll
  for (int i = 0; i < 4; ++i)
    gl_lds16(Ag + (size_t)i * 8 * DMODEL, Al + chA + i * 512);
  gl_lds16(Wg0, Bl + chB);
  gl_lds16(Wg1, Bl + chB + 512);
  for (int kb = 0; kb < 6; ++kb) {
#pragma unroll
    for (int c = 0; c < 2; ++c) {
      int t = kb * 2 + c;
      asm volatile("s_waitcnt vmcnt(0)" ::: "memory");
      __builtin_amdgcn_sched_barrier(0);
      __builtin_amdgcn_s_barrier();
      __builtin_amdgcn_sched_barrier(0);
      if (t < 11) {
        int k0 = (t + 1) * 64;
        int bs = c ^ 1;
#pragma unroll
        for (int i = 0; i < 4; ++i)
          gl_lds16(Ag + (size_t)i * 8 * DMODEL + k0, Al + bs * 8192 + chA + i * 512);
        gl_lds16(Wg0 + k0, Bl + bs * 4096 + chB);
        gl_lds16(Wg1 + k0, Bl + bs * 4096 + chB + 512);
      }
      const __bf16* Ab = (const __bf16*)(Al + c * 8192);
      const __bf16* Bb = (const __bf16*)(Bl + c * 4096);
      bf16x8 a0[4], a1[4];
#pragma unroll
      for (int si = 0; si < 4; ++si) {
        a0[si] = *(const bf16x8*)(Ab + (mW + si * 16 + q16) * 64 + sx0);
        a1[si] = *(const bf16x8*)(Ab + (mW + si * 16 + q16) * 64 + sx1);
      }
      bf16x8 wu0 = *(const bf16x8*)(Bb + (cW + q16) * 64 + sx0);
      bf16x8 wu1 = *(const bf16x8*)(Bb + (cW + q16) * 64 + sx1);
      bf16x8 wg0 = *(const bf16x8*)(Bb + (32 + cW + q16) * 64 + sx0);
      bf16x8 wg1 = *(const bf16x8*)(Bb + (32 + cW + q16) * 64 + sx1);
#pragma unroll
      for (int si = 0; si < 4; ++si) {
        au[si] = __builtin_amdgcn_mfma_f32_16x16x32_bf16(a0[si], wu0, au[si], 0, 0, 0);
        ag[si] = __builtin_amdgcn_mfma_f32_16x16x32_bf16(a0[si], wg0, ag[si], 0, 0, 0);
      }
#pragma unroll
      for (int si = 0; si < 4; ++si) {
        au[si] = __builtin_amdgcn_mfma_f32_16x16x32_bf16(a1[si], wu1, au[si], 0, 0, 0);
        ag[si] = __builtin_amdgcn_mfma_f32_16x16x32_bf16(a1[si], wg1, ag[si], 0, 0, 0);
      }
    }
  }
  int col = cB0 + cW + q16;
  float bu = b2f(bias[col]);
  float bg = b2f(bias[HIDDIM + col]);
#pragma unroll
  for (int si = 0; si < 4; ++si) {
#pragma unroll
    for (int r = 0; r < 4; ++r) {
      int rowi = mB0 + mW + si * 16 + quad * 4 + r;
      float u = au[si][r] + bu;
      float g = ag[si][r] + bg;
      float s = u / (1.0f + __expf(-u));
      actp[(size_t)rowi * HIDDIM + col] = f2b(s * g);
    }
  }
}

// ---------------- V transpose + fused coord-bias p ---------------------------
__global__ __launch_bounds__(256) void vt_kernel(const u16* __restrict__ qkvp,
                                                 u16* __restrict__ vtp,
                                                 const u16* __restrict__ coords,
                                                 const u16* __restrict__ relw,
                                                 float* __restrict__ p) {
  int blk = blockIdx.x;            // b*192 + h*16 + nt
  int b = blk / 192;
  int rem = blk % 192;
  int h = rem >> 4;
  int nt = rem & 15;
  int wv = threadIdx.x >> 6;
  int d = threadIdx.x & 63;
  int n0 = nt * 64 + wv * 16;
  const u16* src = qkvp + ((size_t)(b * NTOK) + n0) * LD3 + 2 * DMODEL + h * 64 + d;
  u16* dst = vtp + ((size_t)((b * NHEAD + h) * 64 + d)) * NTOK + n0;
#pragma unroll
  for (int c = 0; c < 2; ++c) {
    u16 buf[8] __attribute__((aligned(16)));
#pragma unroll
    for (int i = 0; i < 8; ++i) buf[i] = src[(size_t)(c * 8 + i) * LD3];
    *(uint4*)(dst + c * 8) = *(const uint4*)buf;
  }
  if (nt == 0) {   // one block per (b,h): fused p-row
    const float LOG2E = 1.4426950408889634f;
    float w0 = b2f(relw[h * 3 + 0]), w1 = b2f(relw[h * 3 + 1]), w2 = b2f(relw[h * 3 + 2]);
    float* prow = p + (size_t)(b * NHEAD + h) * NTOK;
    for (int n = threadIdx.x; n < NTOK; n += 256) {
      int idx = b * NTOK + n;
      float c0 = b2f(coords[idx * 3 + 0]);
      float c1 = b2f(coords[idx * 3 + 1]);
      float c2 = b2f(coords[idx * 3 + 2]);
      prow[n] = (c0 * w0 + c1 * w1 + c2 * w2) * LOG2E;
    }
  }
}

// ---------------- flash attention: XCD-local heads, 4-deep counted pipeline --
// Exact-math alpha-skip: when __all(lm <= mrun), mn==mrun and alpha==1 ->
// skip exp2 + accO rescale + lsum mul (bit-identical results).
__global__ __launch_bounds__(256) void attn_kernel(
    const u16* __restrict__ qkvp, const u16* __restrict__ vtp,
    const float* __restrict__ p2, const u16* __restrict__ xp,
    float* __restrict__ x1) {
  const __bf16* qb = (const __bf16*)qkvp;
  __shared__ __align__(16) u16 Kl[4][32 * 64];   // [j][d], slot swz by j&7
  __shared__ __align__(16) u16 Vl[4][64 * 32];   // [d][j], slot swz by (d>>1)&3
  __shared__ __align__(16) u16 Pl[4][16][40];    // 80B row stride
  __shared__ __align__(16) float Pb[1024];       // p-row (pre-scaled by LOG2E)
  int lane = threadIdx.x & 63;
  int wv = threadIdx.x >> 6;
  int hw = blockIdx.x;                     // 0..767
  int g = hw % 48;                         // (b,h): all its 16 tiles same XCD
  int nt = hw / 48;                        // query-tile group 0..15
  int b = g / 12, h = g % 12;
  int i0 = (nt * 4 + wv) * 16;             // wave's query tile
  int q16 = lane & 15, quad = lane >> 4;

  const float scl2 = 0.125f * 1.4426950408889634f;

  const __bf16* qrow = qb + ((size_t)(b * NTOK) + i0 + q16) * LD3 + h * 64;
  bf16x8 bq0 = *(const bf16x8*)(qrow + quad * 8);
  bf16x8 bq1 = *(const bf16x8*)(qrow + 32 + quad * 8);

  const float* prow = p2 + (size_t)(b * NHEAD + h) * NTOK;

  int krw = wv * 8 + (lane >> 3);          // K row 0..31 this lane stages
  int ks  = (lane & 7) ^ (krw & 7);        // swizzled 16B slot (8 per 128B row)
  const u16* kg0 = qkvp + (size_t)(b * NTOK) * LD3 + DMODEL + h * 64 + ks * 8;
  int vrw = wv * 16 + (lane >> 2);         // Vt row (d) 0..63
  int vs  = (lane & 3) ^ ((vrw >> 1) & 3); // swizzled 16B slot (4 per 64B row)
  const u16* vg0 = vtp + ((size_t)((b * NHEAD + h) * 64 + vrw)) * NTOK + vs * 8;

  // hoisted read-slot constants
  int kx0 = (quad ^ (q16 & 7)) << 3;
  int kx1 = ((4 | quad) ^ (q16 & 7)) << 3;
  int vx  = (quad ^ ((q16 >> 1) & 3)) << 3;

  float mrun = -1e30f, lsum = 0.f;
  f32x4 accO[4] = {};

  // prologue: p-row + tiles 0..2 (7 outstanding loads/wave)
  gl_lds16((const u16*)(prow + wv * 256 + lane * 4), (u16*)&Pb[wv * 256]);
#pragma unroll
  for (int tt = 0; tt < 3; ++tt) {
    gl_lds16(kg0 + (size_t)(tt * 32 + krw) * LD3, &Kl[tt][wv * 512]);
    gl_lds16(vg0 + tt * 32, &Vl[tt][wv * 512]);
  }

  for (int kb = 0; kb < 8; ++kb) {
#pragma unroll
    for (int c = 0; c < 4; ++c) {
      int t = kb * 4 + c;
      if (t < 30)       asm volatile("s_waitcnt vmcnt(4)" ::: "memory");
      else if (t == 30) asm volatile("s_waitcnt vmcnt(2)" ::: "memory");
      else              asm volatile("s_waitcnt vmcnt(0)" ::: "memory");
      __builtin_amdgcn_sched_barrier(0);
      __builtin_amdgcn_s_barrier();            // all waves' stage(t) landed
      __builtin_amdgcn_sched_barrier(0);
      if (t < 29) {                            // stage(t+3) into buf (c+3)&3
        int j = (t + 3) * 32;
        gl_lds16(kg0 + (size_t)(j + krw) * LD3, &Kl[(c + 3) & 3][wv * 512]);
        gl_lds16(vg0 + j, &Vl[(c + 3) & 3][wv * 512]);
      }

      int j0 = t * 32;
      const __bf16* Kb = (const __bf16*)Kl[c];
      bf16x8 ka00 = *(const bf16x8*)(Kb + q16 * 64 + kx0);
      bf16x8 ka01 = *(const bf16x8*)(Kb + q16 * 64 + kx1);
      bf16x8 ka10 = *(const bf16x8*)(Kb + (16 + q16) * 64 + kx0);
      bf16x8 ka11 = *(const bf16x8*)(Kb + (16 + q16) * 64 + kx1);
      f32x4 st0 = {}, st1 = {};
      st0 = __builtin_amdgcn_mfma_f32_16x16x32_bf16(ka00, bq0, st0, 0, 0, 0);
      st0 = __builtin_amdgcn_mfma_f32_16x16x32_bf16(ka01, bq1, st0, 0, 0, 0);
      st1 = __builtin_amdgcn_mfma_f32_16x16x32_bf16(ka10, bq0, st1, 0, 0, 0);
      st1 = __builtin_amdgcn_mfma_f32_16x16x32_bf16(ka11, bq1, st1, 0, 0, 0);

      f32x4 pjl = *(const f32x4*)(&Pb[j0 + 4 * quad]);
      f32x4 pjh = *(const f32x4*)(&Pb[j0 + 16 + 4 * quad]);
      float sl[4], sh[4];
#pragma unroll
      for (int r = 0; r < 4; ++r) {
        sl[r] = st0[r] * scl2 - pjl[r];
        sh[r] = st1[r] * scl2 - pjh[r];
      }
      float lm = fmaxf(fmaxf(fmaxf(sl[0], sl[1]), fmaxf(sl[2], sl[3])),
                       fmaxf(fmaxf(sh[0], sh[1]), fmaxf(sh[2], sh[3])));
      lm = fmaxf(lm, __shfl_xor(lm, 16, 64));
      lm = fmaxf(lm, __shfl_xor(lm, 32, 64));
      int up = !__all(lm <= mrun);             // wave-uniform
      float alpha = 1.f;
      if (up) {
        float mn = fmaxf(mrun, lm);
        alpha = exp2f(mrun - mn);
        mrun = mn;
      }
      float pl[4], ph[4];
#pragma unroll
      for (int r = 0; r < 4; ++r) {
        pl[r] = exp2f(sl[r] - mrun);
        ph[r] = exp2f(sh[r] - mrun);
      }
      float ts = (pl[0] + pl[1]) + (pl[2] + pl[3]) +
                 (ph[0] + ph[1]) + (ph[2] + ph[3]);
      ts += __shfl_xor(ts, 16, 64);
      ts += __shfl_xor(ts, 32, 64);
      lsum = up ? (lsum * alpha + ts) : (lsum + ts);

      bf16x4 w0 = {(__bf16)pl[0], (__bf16)pl[1], (__bf16)pl[2], (__bf16)pl[3]};
      bf16x4 w1 = {(__bf16)ph[0], (__bf16)ph[1], (__bf16)ph[2], (__bf16)ph[3]};
      *(bf16x4*)(&Pl[wv][q16][4 * quad]) = w0;
      *(bf16x4*)(&Pl[wv][q16][16 + 4 * quad]) = w1;
      bf16x8 ap = *(const bf16x8*)(&Pl[wv][q16][quad * 8]);  // wave-private

      const __bf16* Vb = (const __bf16*)Vl[c];
#pragma unroll
      for (int ds = 0; ds < 4; ++ds) {
        bf16x8 av = *(const bf16x8*)(Vb + (ds * 16 + q16) * 32 + vx);
        f32x4 cc = accO[ds];
        if (up) {
#pragma unroll
          for (int r = 0; r < 4; ++r) cc[r] *= alpha;
        }
        accO[ds] = __builtin_amdgcn_mfma_f32_16x16x32_bf16(av, ap, cc, 0, 0, 0);
      }
    }
  }

  float rl = 1.0f / lsum;
  size_t rowbase = ((size_t)(b * NTOK) + i0 + q16) * DMODEL + h * 64;
#pragma unroll
  for (int ds = 0; ds < 4; ++ds) {
    int d0 = ds * 16 + quad * 4;
    u16x4 xv = *(const u16x4*)(xp + rowbase + d0);
    f32x4 ov;
#pragma unroll
    for (int r = 0; r < 4; ++r) ov[r] = b2f(xv[r]) + accO[ds][r] * rl;
    *(f32x4*)(x1 + rowbase + d0) = ov;
  }
}

extern "C" void kernel_launch(void* const* d_in, const int* in_sizes, int n_in,
                              void* d_out, int out_size, void* d_ws, size_t ws_size,
                              hipStream_t stream) {
  // ---- host-side boundary tripwires (verified passing in R6) ----
  static const int esz[13] = {3145728, 12288, 768, 768, 1769472, 2304, 36,
                              768, 768, 3145728, 4096, 1572864, 768};
  float sig = -1.f;
  if (n_in != 13) {
    sig = 6000.f + 100.f * (float)n_in;
  } else {
    for (int i = 0; i < 13; ++i)
      if (in_sizes[i] != esz[i]) { sig = 1000.f + 100.f * (float)i; break; }
  }
  if (sig < 0.f && ws_size < 57258496ULL) sig = 3000.f;
  if (sig < 0.f && out_size != 3145728) sig = 3100.f;
  if (sig >= 0.f) {
    signal_kernel<<<(out_size + 255) / 256, 256, 0, stream>>>((float*)d_out, out_size, sig);
    return;
  }

  char* ws = (char*)d_ws;
  u16*  cx      = (u16*)(ws + 256);               // 6291456
  u16*  cqkvw   = (u16*)(ws + 6291712);           // 3538944
  u16*  cwinw   = (u16*)(ws + 9830656);           // 6291456
  u16*  cwoutw  = (u16*)(ws + 16122112);          // 3145728
  u16*  ccoords = (u16*)(ws + 19267840);          // 24576
  u16*  cln1g   = (u16*)(ws + 19292416);          // 1536
  u16*  cln1b   = (u16*)(ws + 19293952);          // 1536
  u16*  cqkvb   = (u16*)(ws + 19295488);          // 4608
  u16*  crelw   = (u16*)(ws + 19300096);          // 72 (padded)
  u16*  cln2g   = (u16*)(ws + 19300352);          // 1536
  u16*  cln2b   = (u16*)(ws + 19301888);          // 1536
  u16*  cwinb   = (u16*)(ws + 19303424);          // 8192
  u16*  cwoutb  = (u16*)(ws + 19311616);          // 1536
  u16*  h       = (u16*)(ws + 19313152);          // 6291456 (LN out; reused as Vt)
  u16*  qkv     = (u16*)(ws + 25604608);          // 18874368 (reused as act)
  float* pbuf   = (float*)(ws + 44478976);        // 196608
  float* x1     = (float*)(ws + 44675584);        // 12582912 -> end 57258496
  u16*  act     = qkv;
  u16*  vt      = h;       // Vt needs 6291456 B == sizeof(h)

  // 0. canonicalize all 13 inputs to bf16 (inline dtype-detect, vectorized x4)
  CanonJobs jobs;
  u16* dsts[13] = {cx, ccoords, cln1g, cln1b, cqkvw, cqkvb, crelw,
                   cln2g, cln2b, cwinw, cwinb, cwoutw, cwoutb};
  for (int i = 0; i < 13; ++i) {
    jobs.s[i] = d_in[i];
    jobs.d[i] = dsts[i];
    jobs.n[i] = in_sizes[i];
  }
  canon_kernel<<<dim3(768, 13), 256, 0, stream>>>(jobs);

  // 1. h = LN1(x)
  ln_bf16_kernel<<<4096, 256, 0, stream>>>(cx, cln1g, cln1b, h);
  // 2. qkv = h @ qkv_w^T + qkv_b   (M=4096, N=2304, K=768; 128x64 tiles)
  gemm_bt<<<dim3(36, 32), 256, 0, stream>>>(h, cqkvw, cqkvb, qkv, 2304, 768);
  // 3. Vt[b][h][d][n] = V  + fused p2 computation (h buffer dead here)
  vt_kernel<<<768, 256, 0, stream>>>(qkv, vt, ccoords, crelw, pbuf);
  // 4. x1 = x + attention(qkv, Vt, p2)   (768 blocks; XCD-local + deep pipeline)
  attn_kernel<<<768, 256, 0, stream>>>(qkv, vt, pbuf, cx, x1);
  // 5. h2 = LN2(x1)  (reuse h)
  ln_f32_kernel<<<4096, 256, 0, stream>>>(x1, cln2g, cln2b, h);
  // 6+7. act = silu(h2 @ Wu^T + bu) * (h2 @ Wg^T + bg)   (BK=64 double-buffer)
  ffn_in_kernel<<<dim3(64, 32), 256, 0, stream>>>(h, cwinw, cwinb, act);
  // 8. out(F32) = x1 + act @ wout_w^T + wout_b   (64x64 tiles, BK=64 dbuf)
  gemm_out_f32<<<dim3(12, 64), 256, 0, stream>>>(act, cwoutw, cwoutb, x1,
                                                 (float*)d_out);
}

// Round 13
// 268.828 us; speedup vs baseline: 1.0862x; 1.0241x over previous
//
#include <hip/hip_runtime.h>
#include <math.h>

typedef unsigned short u16;
typedef __bf16 bf16x8 __attribute__((ext_vector_type(8)));
typedef __bf16 bf16x4 __attribute__((ext_vector_type(4)));
typedef u16 u16x4 __attribute__((ext_vector_type(4)));
typedef float f32x4 __attribute__((ext_vector_type(4)));

// ---- constants ----
// B=4, N=1024, D=768, H=12, Dh=64, HID=2048, 3D=2304
#define NTOK 1024
#define DMODEL 768
#define NHEAD 12
#define LD3 2304
#define HIDDIM 2048

__device__ __forceinline__ float b2f(u16 u) {
  unsigned int t = ((unsigned int)u) << 16;
  float f;
  __builtin_memcpy(&f, &t, 4);
  return f;
}
__device__ __forceinline__ u16 f2b(float f) {
  unsigned int t;
  __builtin_memcpy(&t, &f, 4);
  t += 0x7fffu + ((t >> 16) & 1u);
  return (u16)(t >> 16);
}

// async global->LDS, 16B per lane; LDS dest is wave-uniform base + lane*16
__device__ __forceinline__ void gl_lds16(const u16* g, u16* l) {
  __builtin_amdgcn_global_load_lds(
      (__attribute__((address_space(1))) const unsigned int*)g,
      (__attribute__((address_space(3))) unsigned int*)l, 16, 0, 0);
}

// ---------------- host-assert signal (f32 output now) ------------------------
__global__ __launch_bounds__(256) void signal_kernel(float* __restrict__ out,
                                                     int n, float c) {
  int i = blockIdx.x * 256 + threadIdx.x;
  if (i < n) out[i] = c;
}

// ---------------- canonicalize all inputs to bf16 (inline dtype-detect) ------
struct CanonJobs {
  const void* s[13];
  u16* d[13];
  int n[13];
};

__global__ __launch_bounds__(256) void canon_kernel(CanonJobs jobs) {
  __shared__ int csh;
  u16 v = ((const u16*)jobs.s[0])[2 * threadIdx.x];
  int e = (v >> 7) & 0xFF;
  unsigned long long m = __ballot(e >= 0xC0);
  if (threadIdx.x == 0) csh = 0;
  __syncthreads();
  if ((threadIdx.x & 63) == 0) atomicAdd(&csh, __popcll(m));
  __syncthreads();
  bool isf32 = csh >= 8;       // 256 samples: f32 ~64 hits, bf16 ~0

  int j = blockIdx.y;
  int n4 = jobs.n[j] >> 2;     // all sizes divisible by 4
  const void* s = jobs.s[j];
  u16* d = jobs.d[j];
  for (int i = blockIdx.x * 256 + threadIdx.x; i < n4; i += gridDim.x * 256) {
    if (isf32) {
      f32x4 vv = *((const f32x4*)s + i);
      u16x4 o = {f2b(vv[0]), f2b(vv[1]), f2b(vv[2]), f2b(vv[3])};
      *((u16x4*)d + i) = o;
    } else {
      *((u16x4*)d + i) = *((const u16x4*)s + i);
    }
  }
}

// ---------------- LayerNorm (bf16 input) ----------------
__global__ __launch_bounds__(256) void ln_bf16_kernel(
    const u16* __restrict__ x, const u16* __restrict__ g,
    const u16* __restrict__ b, u16* __restrict__ out) {
  int row = blockIdx.x;
  int tid = threadIdx.x;
  const u16* xr = x + (size_t)row * DMODEL;
  float v0 = b2f(xr[tid]), v1 = b2f(xr[tid + 256]), v2 = b2f(xr[tid + 512]);
  float s = v0 + v1 + v2;
  float q = v0 * v0 + v1 * v1 + v2 * v2;
#pragma unroll
  for (int off = 32; off; off >>= 1) {
    s += __shfl_xor(s, off, 64);
    q += __shfl_xor(q, off, 64);
  }
  __shared__ float rs[4], rq[4];
  int wv = tid >> 6;
  if ((tid & 63) == 0) { rs[wv] = s; rq[wv] = q; }
  __syncthreads();
  s = rs[0] + rs[1] + rs[2] + rs[3];
  q = rq[0] + rq[1] + rq[2] + rq[3];
  float mean = s * (1.0f / 768.0f);
  float var = q * (1.0f / 768.0f) - mean * mean;
  float inv = rsqrtf(var + 1e-5f);
  u16* outr = out + (size_t)row * DMODEL;
  outr[tid]       = f2b((v0 - mean) * inv * b2f(g[tid])       + b2f(b[tid]));
  outr[tid + 256] = f2b((v1 - mean) * inv * b2f(g[tid + 256]) + b2f(b[tid + 256]));
  outr[tid + 512] = f2b((v2 - mean) * inv * b2f(g[tid + 512]) + b2f(b[tid + 512]));
}

// ---------------- LayerNorm (f32 input) ----------------
__global__ __launch_bounds__(256) void ln_f32_kernel(
    const float* __restrict__ x, const u16* __restrict__ g,
    const u16* __restrict__ b, u16* __restrict__ out) {
  int row = blockIdx.x;
  int tid = threadIdx.x;
  const float* xr = x + (size_t)row * DMODEL;
  float v0 = xr[tid], v1 = xr[tid + 256], v2 = xr[tid + 512];
  float s = v0 + v1 + v2;
  float q = v0 * v0 + v1 * v1 + v2 * v2;
#pragma unroll
  for (int off = 32; off; off >>= 1) {
    s += __shfl_xor(s, off, 64);
    q += __shfl_xor(q, off, 64);
  }
  __shared__ float rs[4], rq[4];
  int wv = tid >> 6;
  if ((tid & 63) == 0) { rs[wv] = s; rq[wv] = q; }
  __syncthreads();
  s = rs[0] + rs[1] + rs[2] + rs[3];
  q = rq[0] + rq[1] + rq[2] + rq[3];
  float mean = s * (1.0f / 768.0f);
  float var = q * (1.0f / 768.0f) - mean * mean;
  float inv = rsqrtf(var + 1e-5f);
  u16* outr = out + (size_t)row * DMODEL;
  outr[tid]       = f2b((v0 - mean) * inv * b2f(g[tid])       + b2f(b[tid]));
  outr[tid + 256] = f2b((v1 - mean) * inv * b2f(g[tid + 256]) + b2f(b[tid + 256]));
  outr[tid + 512] = f2b((v2 - mean) * inv * b2f(g[tid + 512]) + b2f(b[tid + 512]));
}

// ---------------- MFMA GEMM 128x64 tile, 3-ring pipelined, swizzled ----------
__global__ __launch_bounds__(256) void gemm_bt(
    const u16* __restrict__ Ap, const u16* __restrict__ Wp,
    const u16* __restrict__ bias, u16* __restrict__ Cp, int Nn, int K) {
  __shared__ __align__(16) u16 Al[3 * 128 * 32], Bl[3 * 64 * 32];
  int lane = threadIdx.x & 63;
  int wv = threadIdx.x >> 6;
  int q16 = lane & 15, quad = lane >> 4;
  int mB0 = blockIdx.y * 128;
  int nB0 = blockIdx.x * 64;
  int mW = (wv >> 1) * 64, nW = (wv & 1) * 32;
  int srow = lane >> 2;
  int scol = ((lane & 3) ^ ((lane >> 3) & 3)) * 8;   // inverse-swizzled source
  int sx8 = (quad ^ ((q16 >> 1) & 3)) * 8;           // swizzled read slot
  int r0 = wv * 32 + srow, r1 = r0 + 16;             // A rows this lane stages
  int rb = wv * 16 + srow;                           // B row 0..63
  const u16* Ag0 = Ap + (size_t)(mB0 + r0) * K + scol;
  const u16* Ag1 = Ap + (size_t)(mB0 + r1) * K + scol;
  const u16* Wg  = Wp + (size_t)(nB0 + rb) * K + scol;
  int ch0 = wv * 1024, ch1 = ch0 + 512, chb = wv * 512;
  int nsteps = K >> 5;                               // 24 (div by 3)
  f32x4 acc[4][2] = {};
#pragma unroll
  for (int tt = 0; tt < 2; ++tt) {
    int k0 = tt * 32;
    gl_lds16(Ag0 + k0, Al + tt * 4096 + ch0);
    gl_lds16(Ag1 + k0, Al + tt * 4096 + ch1);
    gl_lds16(Wg + k0, Bl + tt * 2048 + chb);
  }
  int n3 = nsteps / 3;
  for (int kb = 0; kb < n3; ++kb) {
#pragma unroll
    for (int c = 0; c < 3; ++c) {
      int t = kb * 3 + c;
      if (t < nsteps - 1) asm volatile("s_waitcnt vmcnt(3)" ::: "memory");
      else                asm volatile("s_waitcnt vmcnt(0)" ::: "memory");
      __builtin_amdgcn_sched_barrier(0);
      __builtin_amdgcn_s_barrier();
      __builtin_amdgcn_sched_barrier(0);
      if (t < nsteps - 2) {
        int k0 = (t + 2) * 32;
        int bs = (c + 2) % 3;
        gl_lds16(Ag0 + k0, Al + bs * 4096 + ch0);
        gl_lds16(Ag1 + k0, Al + bs * 4096 + ch1);
        gl_lds16(Wg + k0, Bl + bs * 2048 + chb);
      }
      const __bf16* Ab = (const __bf16*)(Al + c * 4096);
      const __bf16* Bb = (const __bf16*)(Bl + c * 2048);
      bf16x8 af[4], bfr[2];
#pragma unroll
      for (int si = 0; si < 4; ++si)
        af[si] = *(const bf16x8*)(Ab + (mW + si * 16 + q16) * 32 + sx8);
#pragma unroll
      for (int sj = 0; sj < 2; ++sj)
        bfr[sj] = *(const bf16x8*)(Bb + (nW + sj * 16 + q16) * 32 + sx8);
#pragma unroll
      for (int si = 0; si < 4; ++si)
#pragma unroll
        for (int sj = 0; sj < 2; ++sj)
          acc[si][sj] = __builtin_amdgcn_mfma_f32_16x16x32_bf16(af[si], bfr[sj], acc[si][sj], 0, 0, 0);
    }
  }
#pragma unroll
  for (int si = 0; si < 4; ++si)
#pragma unroll
    for (int sj = 0; sj < 2; ++sj) {
      int col = nB0 + nW + sj * 16 + q16;
      float bcol = b2f(bias[col]);
#pragma unroll
      for (int r = 0; r < 4; ++r) {
        int rowi = mB0 + mW + si * 16 + quad * 4 + r;
        Cp[(size_t)rowi * Nn + col] = f2b(acc[si][sj][r] + bcol);
      }
    }
}

// ---------------- final GEMM, 64x64 tiles, BK=64 double-buffer ---------------
__global__ __launch_bounds__(256) void gemm_out_f32(
    const u16* __restrict__ Ap, const u16* __restrict__ Wp,
    const u16* __restrict__ bias, const float* __restrict__ res,
    float* __restrict__ out) {
  __shared__ __align__(16) u16 Al[2 * 4096], Bl[2 * 4096];   // 16+16 KB
  int lane = threadIdx.x & 63;
  int wv = threadIdx.x >> 6;
  int q16 = lane & 15, quad = lane >> 4;
  int mB0 = blockIdx.y * 64;
  int nB0 = blockIdx.x * 64;
  int mW = (wv >> 1) * 32, nW = (wv & 1) * 32;
  int lr = lane >> 3, ls = lane & 7;
  int sg = (ls ^ lr) * 8;                       // inverse-swizzled source slot
  int sx0 = (quad ^ (q16 & 7)) * 8;             // read slot, k-half 0
  int sx1 = ((4 | quad) ^ (q16 & 7)) * 8;       // read slot, k-half 1
  const u16* Ag = Ap + (size_t)(mB0 + wv * 16 + lr) * 2048 + sg;
  const u16* Wg = Wp + (size_t)(nB0 + wv * 16 + lr) * 2048 + sg;
  int ch = wv * 1024;
  f32x4 acc[2][2] = {};
#pragma unroll
  for (int i = 0; i < 2; ++i) {
    gl_lds16(Ag + (size_t)i * 8 * 2048, Al + ch + i * 512);
    gl_lds16(Wg + (size_t)i * 8 * 2048, Bl + ch + i * 512);
  }
  for (int kb = 0; kb < 16; ++kb) {
#pragma unroll
    for (int c = 0; c < 2; ++c) {
      int t = kb * 2 + c;
      asm volatile("s_waitcnt vmcnt(0)" ::: "memory");
      __builtin_amdgcn_sched_barrier(0);
      __builtin_amdgcn_s_barrier();
      __builtin_amdgcn_sched_barrier(0);
      if (t < 31) {
        int k0 = (t + 1) * 64;
        int bs = c ^ 1;
#pragma unroll
        for (int i = 0; i < 2; ++i) {
          gl_lds16(Ag + (size_t)i * 8 * 2048 + k0, Al + bs * 4096 + ch + i * 512);
          gl_lds16(Wg + (size_t)i * 8 * 2048 + k0, Bl + bs * 4096 + ch + i * 512);
        }
      }
      const __bf16* Ab = (const __bf16*)(Al + c * 4096);
      const __bf16* Bb = (const __bf16*)(Bl + c * 4096);
      bf16x8 a0[2], a1[2], b0[2], b1[2];
#pragma unroll
      for (int si = 0; si < 2; ++si) {
        a0[si] = *(const bf16x8*)(Ab + (mW + si * 16 + q16) * 64 + sx0);
        a1[si] = *(const bf16x8*)(Ab + (mW + si * 16 + q16) * 64 + sx1);
      }
#pragma unroll
      for (int sj = 0; sj < 2; ++sj) {
        b0[sj] = *(const bf16x8*)(Bb + (nW + sj * 16 + q16) * 64 + sx0);
        b1[sj] = *(const bf16x8*)(Bb + (nW + sj * 16 + q16) * 64 + sx1);
      }
#pragma unroll
      for (int si = 0; si < 2; ++si)
#pragma unroll
        for (int sj = 0; sj < 2; ++sj) {
          acc[si][sj] = __builtin_amdgcn_mfma_f32_16x16x32_bf16(a0[si], b0[sj], acc[si][sj], 0, 0, 0);
          acc[si][sj] = __builtin_amdgcn_mfma_f32_16x16x32_bf16(a1[si], b1[sj], acc[si][sj], 0, 0, 0);
        }
    }
  }
#pragma unroll
  for (int si = 0; si < 2; ++si)
#pragma unroll
    for (int sj = 0; sj < 2; ++sj) {
      int col = nB0 + nW + sj * 16 + q16;
      float bcol = b2f(bias[col]);
#pragma unroll
      for (int r = 0; r < 4; ++r) {
        int rowi = mB0 + mW + si * 16 + quad * 4 + r;
        size_t idx = (size_t)rowi * 768 + col;
        out[idx] = acc[si][sj][r] + bcol + res[idx];
      }
    }
}

// ---------------- fused FFN-in, 128x32 tile, BK=64 double-buffer -------------
__global__ __launch_bounds__(256) void ffn_in_kernel(
    const u16* __restrict__ hp, const u16* __restrict__ Wp,
    const u16* __restrict__ bias, u16* __restrict__ actp) {
  __shared__ __align__(16) u16 Al[2 * 8192], Bl[2 * 4096];   // 32+16 KB
  int lane = threadIdx.x & 63;
  int wv = threadIdx.x >> 6;
  int q16 = lane & 15, quad = lane >> 4;
  int mB0 = blockIdx.y * 128;
  int cB0 = blockIdx.x * 32;
  int mW = (wv >> 1) * 64;
  int cW = (wv & 1) * 16;
  int lr = lane >> 3, ls = lane & 7;
  int sg = (ls ^ lr) * 8;
  int sx0 = (quad ^ (q16 & 7)) * 8;
  int sx1 = ((4 | quad) ^ (q16 & 7)) * 8;
  const u16* Ag = hp + (size_t)(mB0 + wv * 32 + lr) * DMODEL + sg;
  int rB0 = wv * 16 + lr, rB1 = rB0 + 8;
  int gb0 = (rB0 < 32) ? (cB0 + rB0) : (HIDDIM + cB0 + rB0 - 32);
  int gb1 = (rB1 < 32) ? (cB0 + rB1) : (HIDDIM + cB0 + rB1 - 32);
  const u16* Wg0 = Wp + (size_t)gb0 * DMODEL + sg;
  const u16* Wg1 = Wp + (size_t)gb1 * DMODEL + sg;
  int chA = wv * 2048, chB = wv * 1024;
  f32x4 au[4] = {}, ag[4] = {};
#pragma unroll
  for (int i = 0; i < 4; ++i)
    gl_lds16(Ag + (size_t)i * 8 * DMODEL, Al + chA + i * 512);
  gl_lds16(Wg0, Bl + chB);
  gl_lds16(Wg1, Bl + chB + 512);
  for (int kb = 0; kb < 6; ++kb) {
#pragma unroll
    for (int c = 0; c < 2; ++c) {
      int t = kb * 2 + c;
      asm volatile("s_waitcnt vmcnt(0)" ::: "memory");
      __builtin_amdgcn_sched_barrier(0);
      __builtin_amdgcn_s_barrier();
      __builtin_amdgcn_sched_barrier(0);
      if (t < 11) {
        int k0 = (t + 1) * 64;
        int bs = c ^ 1;
#pragma unroll
        for (int i = 0; i < 4; ++i)
          gl_lds16(Ag + (size_t)i * 8 * DMODEL + k0, Al + bs * 8192 + chA + i * 512);
        gl_lds16(Wg0 + k0, Bl + bs * 4096 + chB);
        gl_lds16(Wg1 + k0, Bl + bs * 4096 + chB + 512);
      }
      const __bf16* Ab = (const __bf16*)(Al + c * 8192);
      const __bf16* Bb = (const __bf16*)(Bl + c * 4096);
      bf16x8 a0[4], a1[4];
#pragma unroll
      for (int si = 0; si < 4; ++si) {
        a0[si] = *(const bf16x8*)(Ab + (mW + si * 16 + q16) * 64 + sx0);
        a1[si] = *(const bf16x8*)(Ab + (mW + si * 16 + q16) * 64 + sx1);
      }
      bf16x8 wu0 = *(const bf16x8*)(Bb + (cW + q16) * 64 + sx0);
      bf16x8 wu1 = *(const bf16x8*)(Bb + (cW + q16) * 64 + sx1);
      bf16x8 wg0 = *(const bf16x8*)(Bb + (32 + cW + q16) * 64 + sx0);
      bf16x8 wg1 = *(const bf16x8*)(Bb + (32 + cW + q16) * 64 + sx1);
#pragma unroll
      for (int si = 0; si < 4; ++si) {
        au[si] = __builtin_amdgcn_mfma_f32_16x16x32_bf16(a0[si], wu0, au[si], 0, 0, 0);
        ag[si] = __builtin_amdgcn_mfma_f32_16x16x32_bf16(a0[si], wg0, ag[si], 0, 0, 0);
      }
#pragma unroll
      for (int si = 0; si < 4; ++si) {
        au[si] = __builtin_amdgcn_mfma_f32_16x16x32_bf16(a1[si], wu1, au[si], 0, 0, 0);
        ag[si] = __builtin_amdgcn_mfma_f32_16x16x32_bf16(a1[si], wg1, ag[si], 0, 0, 0);
      }
    }
  }
  int col = cB0 + cW + q16;
  float bu = b2f(bias[col]);
  float bg = b2f(bias[HIDDIM + col]);
#pragma unroll
  for (int si = 0; si < 4; ++si) {
#pragma unroll
    for (int r = 0; r < 4; ++r) {
      int rowi = mB0 + mW + si * 16 + quad * 4 + r;
      float u = au[si][r] + bu;
      float g = ag[si][r] + bg;
      float s = u / (1.0f + __expf(-u));
      actp[(size_t)rowi * HIDDIM + col] = f2b(s * g);
    }
  }
}

// ---------------- V transpose + fused coord-bias p ---------------------------
__global__ __launch_bounds__(256) void vt_kernel(const u16* __restrict__ qkvp,
                                                 u16* __restrict__ vtp,
                                                 const u16* __restrict__ coords,
                                                 const u16* __restrict__ relw,
                                                 float* __restrict__ p) {
  int blk = blockIdx.x;            // b*192 + h*16 + nt
  int b = blk / 192;
  int rem = blk % 192;
  int h = rem >> 4;
  int nt = rem & 15;
  int wv = threadIdx.x >> 6;
  int d = threadIdx.x & 63;
  int n0 = nt * 64 + wv * 16;
  const u16* src = qkvp + ((size_t)(b * NTOK) + n0) * LD3 + 2 * DMODEL + h * 64 + d;
  u16* dst = vtp + ((size_t)((b * NHEAD + h) * 64 + d)) * NTOK + n0;
#pragma unroll
  for (int c = 0; c < 2; ++c) {
    u16 buf[8] __attribute__((aligned(16)));
#pragma unroll
    for (int i = 0; i < 8; ++i) buf[i] = src[(size_t)(c * 8 + i) * LD3];
    *(uint4*)(dst + c * 8) = *(const uint4*)buf;
  }
  if (nt == 0) {   // one block per (b,h): fused p-row
    const float LOG2E = 1.4426950408889634f;
    float w0 = b2f(relw[h * 3 + 0]), w1 = b2f(relw[h * 3 + 1]), w2 = b2f(relw[h * 3 + 2]);
    float* prow = p + (size_t)(b * NHEAD + h) * NTOK;
    for (int n = threadIdx.x; n < NTOK; n += 256) {
      int idx = b * NTOK + n;
      float c0 = b2f(coords[idx * 3 + 0]);
      float c1 = b2f(coords[idx * 3 + 1]);
      float c2 = b2f(coords[idx * 3 + 2]);
      prow[n] = (c0 * w0 + c1 * w1 + c2 * w2) * LOG2E;
    }
  }
}

// ---------------- flash attention: XCD-local heads, 4-deep counted pipeline --
// R12: alpha-skip REVERTED (R11's wave-uniform branch cost more than the
// saved rescale work: 53 -> 61 us). Straight-line softmax as in R6.
__global__ __launch_bounds__(256) void attn_kernel(
    const u16* __restrict__ qkvp, const u16* __restrict__ vtp,
    const float* __restrict__ p2, const u16* __restrict__ xp,
    float* __restrict__ x1) {
  const __bf16* qb = (const __bf16*)qkvp;
  __shared__ __align__(16) u16 Kl[4][32 * 64];   // [j][d], slot swz by j&7
  __shared__ __align__(16) u16 Vl[4][64 * 32];   // [d][j], slot swz by (d>>1)&3
  __shared__ __align__(16) u16 Pl[4][16][40];    // 80B row stride
  __shared__ __align__(16) float Pb[1024];       // p-row (pre-scaled by LOG2E)
  int lane = threadIdx.x & 63;
  int wv = threadIdx.x >> 6;
  int hw = blockIdx.x;                     // 0..767
  int g = hw % 48;                         // (b,h): all its 16 tiles same XCD
  int nt = hw / 48;                        // query-tile group 0..15
  int b = g / 12, h = g % 12;
  int i0 = (nt * 4 + wv) * 16;             // wave's query tile
  int q16 = lane & 15, quad = lane >> 4;

  const float scl2 = 0.125f * 1.4426950408889634f;

  const __bf16* qrow = qb + ((size_t)(b * NTOK) + i0 + q16) * LD3 + h * 64;
  bf16x8 bq0 = *(const bf16x8*)(qrow + quad * 8);
  bf16x8 bq1 = *(const bf16x8*)(qrow + 32 + quad * 8);

  const float* prow = p2 + (size_t)(b * NHEAD + h) * NTOK;

  int krw = wv * 8 + (lane >> 3);          // K row 0..31 this lane stages
  int ks  = (lane & 7) ^ (krw & 7);        // swizzled 16B slot (8 per 128B row)
  const u16* kg0 = qkvp + (size_t)(b * NTOK) * LD3 + DMODEL + h * 64 + ks * 8;
  int vrw = wv * 16 + (lane >> 2);         // Vt row (d) 0..63
  int vs  = (lane & 3) ^ ((vrw >> 1) & 3); // swizzled 16B slot (4 per 64B row)
  const u16* vg0 = vtp + ((size_t)((b * NHEAD + h) * 64 + vrw)) * NTOK + vs * 8;

  // hoisted read-slot constants
  int kx0 = (quad ^ (q16 & 7)) << 3;
  int kx1 = ((4 | quad) ^ (q16 & 7)) << 3;
  int vx  = (quad ^ ((q16 >> 1) & 3)) << 3;

  float mrun = -1e30f, lsum = 0.f;
  f32x4 accO[4] = {};

  // prologue: p-row + tiles 0..2 (7 outstanding loads/wave)
  gl_lds16((const u16*)(prow + wv * 256 + lane * 4), (u16*)&Pb[wv * 256]);
#pragma unroll
  for (int tt = 0; tt < 3; ++tt) {
    gl_lds16(kg0 + (size_t)(tt * 32 + krw) * LD3, &Kl[tt][wv * 512]);
    gl_lds16(vg0 + tt * 32, &Vl[tt][wv * 512]);
  }

  for (int kb = 0; kb < 8; ++kb) {
#pragma unroll
    for (int c = 0; c < 4; ++c) {
      int t = kb * 4 + c;
      if (t < 30)       asm volatile("s_waitcnt vmcnt(4)" ::: "memory");
      else if (t == 30) asm volatile("s_waitcnt vmcnt(2)" ::: "memory");
      else              asm volatile("s_waitcnt vmcnt(0)" ::: "memory");
      __builtin_amdgcn_sched_barrier(0);
      __builtin_amdgcn_s_barrier();            // all waves' stage(t) landed
      __builtin_amdgcn_sched_barrier(0);
      if (t < 29) {                            // stage(t+3) into buf (c+3)&3
        int j = (t + 3) * 32;
        gl_lds16(kg0 + (size_t)(j + krw) * LD3, &Kl[(c + 3) & 3][wv * 512]);
        gl_lds16(vg0 + j, &Vl[(c + 3) & 3][wv * 512]);
      }

      int j0 = t * 32;
      const __bf16* Kb = (const __bf16*)Kl[c];
      bf16x8 ka00 = *(const bf16x8*)(Kb + q16 * 64 + kx0);
      bf16x8 ka01 = *(const bf16x8*)(Kb + q16 * 64 + kx1);
      bf16x8 ka10 = *(const bf16x8*)(Kb + (16 + q16) * 64 + kx0);
      bf16x8 ka11 = *(const bf16x8*)(Kb + (16 + q16) * 64 + kx1);
      f32x4 st0 = {}, st1 = {};
      st0 = __builtin_amdgcn_mfma_f32_16x16x32_bf16(ka00, bq0, st0, 0, 0, 0);
      st0 = __builtin_amdgcn_mfma_f32_16x16x32_bf16(ka01, bq1, st0, 0, 0, 0);
      st1 = __builtin_amdgcn_mfma_f32_16x16x32_bf16(ka10, bq0, st1, 0, 0, 0);
      st1 = __builtin_amdgcn_mfma_f32_16x16x32_bf16(ka11, bq1, st1, 0, 0, 0);

      f32x4 pjl = *(const f32x4*)(&Pb[j0 + 4 * quad]);
      f32x4 pjh = *(const f32x4*)(&Pb[j0 + 16 + 4 * quad]);
      float sl[4], sh[4];
#pragma unroll
      for (int r = 0; r < 4; ++r) {
        sl[r] = st0[r] * scl2 - pjl[r];
        sh[r] = st1[r] * scl2 - pjh[r];
      }
      float lm = fmaxf(fmaxf(fmaxf(sl[0], sl[1]), fmaxf(sl[2], sl[3])),
                       fmaxf(fmaxf(sh[0], sh[1]), fmaxf(sh[2], sh[3])));
      lm = fmaxf(lm, __shfl_xor(lm, 16, 64));
      lm = fmaxf(lm, __shfl_xor(lm, 32, 64));
      float mn = fmaxf(mrun, lm);
      float alpha = exp2f(mrun - mn);
      mrun = mn;
      float pl[4], ph[4];
#pragma unroll
      for (int r = 0; r < 4; ++r) {
        pl[r] = exp2f(sl[r] - mn);
        ph[r] = exp2f(sh[r] - mn);
      }
      float ts = (pl[0] + pl[1]) + (pl[2] + pl[3]) +
                 (ph[0] + ph[1]) + (ph[2] + ph[3]);
      ts += __shfl_xor(ts, 16, 64);
      ts += __shfl_xor(ts, 32, 64);
      lsum = lsum * alpha + ts;

      bf16x4 w0 = {(__bf16)pl[0], (__bf16)pl[1], (__bf16)pl[2], (__bf16)pl[3]};
      bf16x4 w1 = {(__bf16)ph[0], (__bf16)ph[1], (__bf16)ph[2], (__bf16)ph[3]};
      *(bf16x4*)(&Pl[wv][q16][4 * quad]) = w0;
      *(bf16x4*)(&Pl[wv][q16][16 + 4 * quad]) = w1;
      bf16x8 ap = *(const bf16x8*)(&Pl[wv][q16][quad * 8]);  // wave-private

      const __bf16* Vb = (const __bf16*)Vl[c];
#pragma unroll
      for (int ds = 0; ds < 4; ++ds) {
        bf16x8 av = *(const bf16x8*)(Vb + (ds * 16 + q16) * 32 + vx);
        f32x4 cc = accO[ds];
#pragma unroll
        for (int r = 0; r < 4; ++r) cc[r] *= alpha;
        accO[ds] = __builtin_amdgcn_mfma_f32_16x16x32_bf16(av, ap, cc, 0, 0, 0);
      }
    }
  }

  float rl = 1.0f / lsum;
  size_t rowbase = ((size_t)(b * NTOK) + i0 + q16) * DMODEL + h * 64;
#pragma unroll
  for (int ds = 0; ds < 4; ++ds) {
    int d0 = ds * 16 + quad * 4;
    u16x4 xv = *(const u16x4*)(xp + rowbase + d0);
    f32x4 ov;
#pragma unroll
    for (int r = 0; r < 4; ++r) ov[r] = b2f(xv[r]) + accO[ds][r] * rl;
    *(f32x4*)(x1 + rowbase + d0) = ov;
  }
}

extern "C" void kernel_launch(void* const* d_in, const int* in_sizes, int n_in,
                              void* d_out, int out_size, void* d_ws, size_t ws_size,
                              hipStream_t stream) {
  // ---- host-side boundary tripwires (verified passing in R6) ----
  static const int esz[13] = {3145728, 12288, 768, 768, 1769472, 2304, 36,
                              768, 768, 3145728, 4096, 1572864, 768};
  float sig = -1.f;
  if (n_in != 13) {
    sig = 6000.f + 100.f * (float)n_in;
  } else {
    for (int i = 0; i < 13; ++i)
      if (in_sizes[i] != esz[i]) { sig = 1000.f + 100.f * (float)i; break; }
  }
  if (sig < 0.f && ws_size < 57258496ULL) sig = 3000.f;
  if (sig < 0.f && out_size != 3145728) sig = 3100.f;
  if (sig >= 0.f) {
    signal_kernel<<<(out_size + 255) / 256, 256, 0, stream>>>((float*)d_out, out_size, sig);
    return;
  }

  char* ws = (char*)d_ws;
  u16*  cx      = (u16*)(ws + 256);               // 6291456
  u16*  cqkvw   = (u16*)(ws + 6291712);           // 3538944
  u16*  cwinw   = (u16*)(ws + 9830656);           // 6291456
  u16*  cwoutw  = (u16*)(ws + 16122112);          // 3145728
  u16*  ccoords = (u16*)(ws + 19267840);          // 24576
  u16*  cln1g   = (u16*)(ws + 19292416);          // 1536
  u16*  cln1b   = (u16*)(ws + 19293952);          // 1536
  u16*  cqkvb   = (u16*)(ws + 19295488);          // 4608
  u16*  crelw   = (u16*)(ws + 19300096);          // 72 (padded)
  u16*  cln2g   = (u16*)(ws + 19300352);          // 1536
  u16*  cln2b   = (u16*)(ws + 19301888);          // 1536
  u16*  cwinb   = (u16*)(ws + 19303424);          // 8192
  u16*  cwoutb  = (u16*)(ws + 19311616);          // 1536
  u16*  h       = (u16*)(ws + 19313152);          // 6291456 (LN out; reused as Vt)
  u16*  qkv     = (u16*)(ws + 25604608);          // 18874368 (reused as act)
  float* pbuf   = (float*)(ws + 44478976);        // 196608
  float* x1     = (float*)(ws + 44675584);        // 12582912 -> end 57258496
  u16*  act     = qkv;
  u16*  vt      = h;       // Vt needs 6291456 B == sizeof(h)

  // 0. canonicalize all 13 inputs to bf16 (inline dtype-detect, vectorized x4)
  CanonJobs jobs;
  u16* dsts[13] = {cx, ccoords, cln1g, cln1b, cqkvw, cqkvb, crelw,
                   cln2g, cln2b, cwinw, cwinb, cwoutw, cwoutb};
  for (int i = 0; i < 13; ++i) {
    jobs.s[i] = d_in[i];
    jobs.d[i] = dsts[i];
    jobs.n[i] = in_sizes[i];
  }
  canon_kernel<<<dim3(768, 13), 256, 0, stream>>>(jobs);

  // 1. h = LN1(x)
  ln_bf16_kernel<<<4096, 256, 0, stream>>>(cx, cln1g, cln1b, h);
  // 2. qkv = h @ qkv_w^T + qkv_b   (M=4096, N=2304, K=768; 128x64 tiles)
  gemm_bt<<<dim3(36, 32), 256, 0, stream>>>(h, cqkvw, cqkvb, qkv, 2304, 768);
  // 3. Vt[b][h][d][n] = V  + fused p2 computation (h buffer dead here)
  vt_kernel<<<768, 256, 0, stream>>>(qkv, vt, ccoords, crelw, pbuf);
  // 4. x1 = x + attention(qkv, Vt, p2)   (768 blocks; XCD-local + deep pipeline)
  attn_kernel<<<768, 256, 0, stream>>>(qkv, vt, pbuf, cx, x1);
  // 5. h2 = LN2(x1)  (reuse h)
  ln_f32_kernel<<<4096, 256, 0, stream>>>(x1, cln2g, cln2b, h);
  // 6+7. act = silu(h2 @ Wu^T + bu) * (h2 @ Wg^T + bg)   (BK=64 double-buffer)
  ffn_in_kernel<<<dim3(64, 32), 256, 0, stream>>>(h, cwinw, cwinb, act);
  // 8. out(F32) = x1 + act @ wout_w^T + wout_b   (64x64 tiles, BK=64 dbuf)
  gemm_out_f32<<<dim3(12, 64), 256, 0, stream>>>(act, cwoutw, cwoutb, x1,
                                                 (float*)d_out);
}

// Round 14
// 265.425 us; speedup vs baseline: 1.1002x; 1.0128x over previous
//
#include <hip/hip_runtime.h>
#include <math.h>

typedef unsigned short u16;
typedef __bf16 bf16x8 __attribute__((ext_vector_type(8)));
typedef __bf16 bf16x4 __attribute__((ext_vector_type(4)));
typedef u16 u16x4 __attribute__((ext_vector_type(4)));
typedef float f32x4 __attribute__((ext_vector_type(4)));

// ---- constants ----
// B=4, N=1024, D=768, H=12, Dh=64, HID=2048, 3D=2304
#define NTOK 1024
#define DMODEL 768
#define NHEAD 12
#define LD3 2304
#define HIDDIM 2048

__device__ __forceinline__ float b2f(u16 u) {
  unsigned int t = ((unsigned int)u) << 16;
  float f;
  __builtin_memcpy(&f, &t, 4);
  return f;
}
__device__ __forceinline__ u16 f2b(float f) {
  unsigned int t;
  __builtin_memcpy(&t, &f, 4);
  t += 0x7fffu + ((t >> 16) & 1u);
  return (u16)(t >> 16);
}

// async global->LDS, 16B per lane; LDS dest is wave-uniform base + lane*16
__device__ __forceinline__ void gl_lds16(const u16* g, u16* l) {
  __builtin_amdgcn_global_load_lds(
      (__attribute__((address_space(1))) const unsigned int*)g,
      (__attribute__((address_space(3))) unsigned int*)l, 16, 0, 0);
}

// ---------------- host-assert signal (f32 output now) ------------------------
__global__ __launch_bounds__(256) void signal_kernel(float* __restrict__ out,
                                                     int n, float c) {
  int i = blockIdx.x * 256 + threadIdx.x;
  if (i < n) out[i] = c;
}

// ---------------- canonicalize all inputs to bf16 (inline dtype-detect) ------
struct CanonJobs {
  const void* s[13];
  u16* d[13];
  int n[13];
};

__global__ __launch_bounds__(256) void canon_kernel(CanonJobs jobs) {
  __shared__ int csh;
  u16 v = ((const u16*)jobs.s[0])[2 * threadIdx.x];
  int e = (v >> 7) & 0xFF;
  unsigned long long m = __ballot(e >= 0xC0);
  if (threadIdx.x == 0) csh = 0;
  __syncthreads();
  if ((threadIdx.x & 63) == 0) atomicAdd(&csh, __popcll(m));
  __syncthreads();
  bool isf32 = csh >= 8;       // 256 samples: f32 ~64 hits, bf16 ~0

  int j = blockIdx.y;
  int n4 = jobs.n[j] >> 2;     // all sizes divisible by 4
  const void* s = jobs.s[j];
  u16* d = jobs.d[j];
  for (int i = blockIdx.x * 256 + threadIdx.x; i < n4; i += gridDim.x * 256) {
    if (isf32) {
      f32x4 vv = *((const f32x4*)s + i);
      u16x4 o = {f2b(vv[0]), f2b(vv[1]), f2b(vv[2]), f2b(vv[3])};
      *((u16x4*)d + i) = o;
    } else {
      *((u16x4*)d + i) = *((const u16x4*)s + i);
    }
  }
}

// ---------------- LayerNorm (bf16 input) ----------------
__global__ __launch_bounds__(256) void ln_bf16_kernel(
    const u16* __restrict__ x, const u16* __restrict__ g,
    const u16* __restrict__ b, u16* __restrict__ out) {
  int row = blockIdx.x;
  int tid = threadIdx.x;
  const u16* xr = x + (size_t)row * DMODEL;
  float v0 = b2f(xr[tid]), v1 = b2f(xr[tid + 256]), v2 = b2f(xr[tid + 512]);
  float s = v0 + v1 + v2;
  float q = v0 * v0 + v1 * v1 + v2 * v2;
#pragma unroll
  for (int off = 32; off; off >>= 1) {
    s += __shfl_xor(s, off, 64);
    q += __shfl_xor(q, off, 64);
  }
  __shared__ float rs[4], rq[4];
  int wv = tid >> 6;
  if ((tid & 63) == 0) { rs[wv] = s; rq[wv] = q; }
  __syncthreads();
  s = rs[0] + rs[1] + rs[2] + rs[3];
  q = rq[0] + rq[1] + rq[2] + rq[3];
  float mean = s * (1.0f / 768.0f);
  float var = q * (1.0f / 768.0f) - mean * mean;
  float inv = rsqrtf(var + 1e-5f);
  u16* outr = out + (size_t)row * DMODEL;
  outr[tid]       = f2b((v0 - mean) * inv * b2f(g[tid])       + b2f(b[tid]));
  outr[tid + 256] = f2b((v1 - mean) * inv * b2f(g[tid + 256]) + b2f(b[tid + 256]));
  outr[tid + 512] = f2b((v2 - mean) * inv * b2f(g[tid + 512]) + b2f(b[tid + 512]));
}

// ---------------- LayerNorm (f32 input) ----------------
__global__ __launch_bounds__(256) void ln_f32_kernel(
    const float* __restrict__ x, const u16* __restrict__ g,
    const u16* __restrict__ b, u16* __restrict__ out) {
  int row = blockIdx.x;
  int tid = threadIdx.x;
  const float* xr = x + (size_t)row * DMODEL;
  float v0 = xr[tid], v1 = xr[tid + 256], v2 = xr[tid + 512];
  float s = v0 + v1 + v2;
  float q = v0 * v0 + v1 * v1 + v2 * v2;
#pragma unroll
  for (int off = 32; off; off >>= 1) {
    s += __shfl_xor(s, off, 64);
    q += __shfl_xor(q, off, 64);
  }
  __shared__ float rs[4], rq[4];
  int wv = tid >> 6;
  if ((tid & 63) == 0) { rs[wv] = s; rq[wv] = q; }
  __syncthreads();
  s = rs[0] + rs[1] + rs[2] + rs[3];
  q = rq[0] + rq[1] + rq[2] + rq[3];
  float mean = s * (1.0f / 768.0f);
  float var = q * (1.0f / 768.0f) - mean * mean;
  float inv = rsqrtf(var + 1e-5f);
  u16* outr = out + (size_t)row * DMODEL;
  outr[tid]       = f2b((v0 - mean) * inv * b2f(g[tid])       + b2f(b[tid]));
  outr[tid + 256] = f2b((v1 - mean) * inv * b2f(g[tid + 256]) + b2f(b[tid + 256]));
  outr[tid + 512] = f2b((v2 - mean) * inv * b2f(g[tid + 512]) + b2f(b[tid + 512]));
}

// ---------------- MFMA GEMM 128x64 tile, 3-ring pipelined, swizzled ----------
__global__ __launch_bounds__(256) void gemm_bt(
    const u16* __restrict__ Ap, const u16* __restrict__ Wp,
    const u16* __restrict__ bias, u16* __restrict__ Cp, int Nn, int K) {
  __shared__ __align__(16) u16 Al[3 * 128 * 32], Bl[3 * 64 * 32];
  int lane = threadIdx.x & 63;
  int wv = threadIdx.x >> 6;
  int q16 = lane & 15, quad = lane >> 4;
  int mB0 = blockIdx.y * 128;
  int nB0 = blockIdx.x * 64;
  int mW = (wv >> 1) * 64, nW = (wv & 1) * 32;
  int srow = lane >> 2;
  int scol = ((lane & 3) ^ ((lane >> 3) & 3)) * 8;   // inverse-swizzled source
  int sx8 = (quad ^ ((q16 >> 1) & 3)) * 8;           // swizzled read slot
  int r0 = wv * 32 + srow, r1 = r0 + 16;             // A rows this lane stages
  int rb = wv * 16 + srow;                           // B row 0..63
  const u16* Ag0 = Ap + (size_t)(mB0 + r0) * K + scol;
  const u16* Ag1 = Ap + (size_t)(mB0 + r1) * K + scol;
  const u16* Wg  = Wp + (size_t)(nB0 + rb) * K + scol;
  int ch0 = wv * 1024, ch1 = ch0 + 512, chb = wv * 512;
  int nsteps = K >> 5;                               // 24 (div by 3)
  f32x4 acc[4][2] = {};
#pragma unroll
  for (int tt = 0; tt < 2; ++tt) {
    int k0 = tt * 32;
    gl_lds16(Ag0 + k0, Al + tt * 4096 + ch0);
    gl_lds16(Ag1 + k0, Al + tt * 4096 + ch1);
    gl_lds16(Wg + k0, Bl + tt * 2048 + chb);
  }
  int n3 = nsteps / 3;
  for (int kb = 0; kb < n3; ++kb) {
#pragma unroll
    for (int c = 0; c < 3; ++c) {
      int t = kb * 3 + c;
      if (t < nsteps - 1) asm volatile("s_waitcnt vmcnt(3)" ::: "memory");
      else                asm volatile("s_waitcnt vmcnt(0)" ::: "memory");
      __builtin_amdgcn_sched_barrier(0);
      __builtin_amdgcn_s_barrier();
      __builtin_amdgcn_sched_barrier(0);
      if (t < nsteps - 2) {
        int k0 = (t + 2) * 32;
        int bs = (c + 2) % 3;
        gl_lds16(Ag0 + k0, Al + bs * 4096 + ch0);
        gl_lds16(Ag1 + k0, Al + bs * 4096 + ch1);
        gl_lds16(Wg + k0, Bl + bs * 2048 + chb);
      }
      const __bf16* Ab = (const __bf16*)(Al + c * 4096);
      const __bf16* Bb = (const __bf16*)(Bl + c * 2048);
      bf16x8 af[4], bfr[2];
#pragma unroll
      for (int si = 0; si < 4; ++si)
        af[si] = *(const bf16x8*)(Ab + (mW + si * 16 + q16) * 32 + sx8);
#pragma unroll
      for (int sj = 0; sj < 2; ++sj)
        bfr[sj] = *(const bf16x8*)(Bb + (nW + sj * 16 + q16) * 32 + sx8);
#pragma unroll
      for (int si = 0; si < 4; ++si)
#pragma unroll
        for (int sj = 0; sj < 2; ++sj)
          acc[si][sj] = __builtin_amdgcn_mfma_f32_16x16x32_bf16(af[si], bfr[sj], acc[si][sj], 0, 0, 0);
    }
  }
#pragma unroll
  for (int si = 0; si < 4; ++si)
#pragma unroll
    for (int sj = 0; sj < 2; ++sj) {
      int col = nB0 + nW + sj * 16 + q16;
      float bcol = b2f(bias[col]);
#pragma unroll
      for (int r = 0; r < 4; ++r) {
        int rowi = mB0 + mW + si * 16 + quad * 4 + r;
        Cp[(size_t)rowi * Nn + col] = f2b(acc[si][sj][r] + bcol);
      }
    }
}

// ---------------- final GEMM, 64x64 tiles, BK=64 double-buffer ---------------
__global__ __launch_bounds__(256) void gemm_out_f32(
    const u16* __restrict__ Ap, const u16* __restrict__ Wp,
    const u16* __restrict__ bias, const float* __restrict__ res,
    float* __restrict__ out) {
  __shared__ __align__(16) u16 Al[2 * 4096], Bl[2 * 4096];   // 16+16 KB
  int lane = threadIdx.x & 63;
  int wv = threadIdx.x >> 6;
  int q16 = lane & 15, quad = lane >> 4;
  int mB0 = blockIdx.y * 64;
  int nB0 = blockIdx.x * 64;
  int mW = (wv >> 1) * 32, nW = (wv & 1) * 32;
  int lr = lane >> 3, ls = lane & 7;
  int sg = (ls ^ lr) * 8;                       // inverse-swizzled source slot
  int sx0 = (quad ^ (q16 & 7)) * 8;             // read slot, k-half 0
  int sx1 = ((4 | quad) ^ (q16 & 7)) * 8;       // read slot, k-half 1
  const u16* Ag = Ap + (size_t)(mB0 + wv * 16 + lr) * 2048 + sg;
  const u16* Wg = Wp + (size_t)(nB0 + wv * 16 + lr) * 2048 + sg;
  int ch = wv * 1024;
  f32x4 acc[2][2] = {};
#pragma unroll
  for (int i = 0; i < 2; ++i) {
    gl_lds16(Ag + (size_t)i * 8 * 2048, Al + ch + i * 512);
    gl_lds16(Wg + (size_t)i * 8 * 2048, Bl + ch + i * 512);
  }
  for (int kb = 0; kb < 16; ++kb) {
#pragma unroll
    for (int c = 0; c < 2; ++c) {
      int t = kb * 2 + c;
      asm volatile("s_waitcnt vmcnt(0)" ::: "memory");
      __builtin_amdgcn_sched_barrier(0);
      __builtin_amdgcn_s_barrier();
      __builtin_amdgcn_sched_barrier(0);
      if (t < 31) {
        int k0 = (t + 1) * 64;
        int bs = c ^ 1;
#pragma unroll
        for (int i = 0; i < 2; ++i) {
          gl_lds16(Ag + (size_t)i * 8 * 2048 + k0, Al + bs * 4096 + ch + i * 512);
          gl_lds16(Wg + (size_t)i * 8 * 2048 + k0, Bl + bs * 4096 + ch + i * 512);
        }
      }
      const __bf16* Ab = (const __bf16*)(Al + c * 4096);
      const __bf16* Bb = (const __bf16*)(Bl + c * 4096);
      bf16x8 a0[2], a1[2], b0[2], b1[2];
#pragma unroll
      for (int si = 0; si < 2; ++si) {
        a0[si] = *(const bf16x8*)(Ab + (mW + si * 16 + q16) * 64 + sx0);
        a1[si] = *(const bf16x8*)(Ab + (mW + si * 16 + q16) * 64 + sx1);
      }
#pragma unroll
      for (int sj = 0; sj < 2; ++sj) {
        b0[sj] = *(const bf16x8*)(Bb + (nW + sj * 16 + q16) * 64 + sx0);
        b1[sj] = *(const bf16x8*)(Bb + (nW + sj * 16 + q16) * 64 + sx1);
      }
#pragma unroll
      for (int si = 0; si < 2; ++si)
#pragma unroll
        for (int sj = 0; sj < 2; ++sj) {
          acc[si][sj] = __builtin_amdgcn_mfma_f32_16x16x32_bf16(a0[si], b0[sj], acc[si][sj], 0, 0, 0);
          acc[si][sj] = __builtin_amdgcn_mfma_f32_16x16x32_bf16(a1[si], b1[sj], acc[si][sj], 0, 0, 0);
        }
    }
  }
#pragma unroll
  for (int si = 0; si < 2; ++si)
#pragma unroll
    for (int sj = 0; sj < 2; ++sj) {
      int col = nB0 + nW + sj * 16 + q16;
      float bcol = b2f(bias[col]);
#pragma unroll
      for (int r = 0; r < 4; ++r) {
        int rowi = mB0 + mW + si * 16 + quad * 4 + r;
        size_t idx = (size_t)rowi * 768 + col;
        out[idx] = acc[si][sj][r] + bcol + res[idx];
      }
    }
}

// ---------------- fused FFN-in, 128x32 tile, BK=64 double-buffer -------------
__global__ __launch_bounds__(256) void ffn_in_kernel(
    const u16* __restrict__ hp, const u16* __restrict__ Wp,
    const u16* __restrict__ bias, u16* __restrict__ actp) {
  __shared__ __align__(16) u16 Al[2 * 8192], Bl[2 * 4096];   // 32+16 KB
  int lane = threadIdx.x & 63;
  int wv = threadIdx.x >> 6;
  int q16 = lane & 15, quad = lane >> 4;
  int mB0 = blockIdx.y * 128;
  int cB0 = blockIdx.x * 32;
  int mW = (wv >> 1) * 64;
  int cW = (wv & 1) * 16;
  int lr = lane >> 3, ls = lane & 7;
  int sg = (ls ^ lr) * 8;
  int sx0 = (quad ^ (q16 & 7)) * 8;
  int sx1 = ((4 | quad) ^ (q16 & 7)) * 8;
  const u16* Ag = hp + (size_t)(mB0 + wv * 32 + lr) * DMODEL + sg;
  int rB0 = wv * 16 + lr, rB1 = rB0 + 8;
  int gb0 = (rB0 < 32) ? (cB0 + rB0) : (HIDDIM + cB0 + rB0 - 32);
  int gb1 = (rB1 < 32) ? (cB0 + rB1) : (HIDDIM + cB0 + rB1 - 32);
  const u16* Wg0 = Wp + (size_t)gb0 * DMODEL + sg;
  const u16* Wg1 = Wp + (size_t)gb1 * DMODEL + sg;
  int chA = wv * 2048, chB = wv * 1024;
  f32x4 au[4] = {}, ag[4] = {};
#pragma unroll
  for (int i = 0; i < 4; ++i)
    gl_lds16(Ag + (size_t)i * 8 * DMODEL, Al + chA + i * 512);
  gl_lds16(Wg0, Bl + chB);
  gl_lds16(Wg1, Bl + chB + 512);
  for (int kb = 0; kb < 6; ++kb) {
#pragma unroll
    for (int c = 0; c < 2; ++c) {
      int t = kb * 2 + c;
      asm volatile("s_waitcnt vmcnt(0)" ::: "memory");
      __builtin_amdgcn_sched_barrier(0);
      __builtin_amdgcn_s_barrier();
      __builtin_amdgcn_sched_barrier(0);
      if (t < 11) {
        int k0 = (t + 1) * 64;
        int bs = c ^ 1;
#pragma unroll
        for (int i = 0; i < 4; ++i)
          gl_lds16(Ag + (size_t)i * 8 * DMODEL + k0, Al + bs * 8192 + chA + i * 512);
        gl_lds16(Wg0 + k0, Bl + bs * 4096 + chB);
        gl_lds16(Wg1 + k0, Bl + bs * 4096 + chB + 512);
      }
      const __bf16* Ab = (const __bf16*)(Al + c * 8192);
      const __bf16* Bb = (const __bf16*)(Bl + c * 4096);
      bf16x8 a0[4], a1[4];
#pragma unroll
      for (int si = 0; si < 4; ++si) {
        a0[si] = *(const bf16x8*)(Ab + (mW + si * 16 + q16) * 64 + sx0);
        a1[si] = *(const bf16x8*)(Ab + (mW + si * 16 + q16) * 64 + sx1);
      }
      bf16x8 wu0 = *(const bf16x8*)(Bb + (cW + q16) * 64 + sx0);
      bf16x8 wu1 = *(const bf16x8*)(Bb + (cW + q16) * 64 + sx1);
      bf16x8 wg0 = *(const bf16x8*)(Bb + (32 + cW + q16) * 64 + sx0);
      bf16x8 wg1 = *(const bf16x8*)(Bb + (32 + cW + q16) * 64 + sx1);
#pragma unroll
      for (int si = 0; si < 4; ++si) {
        au[si] = __builtin_amdgcn_mfma_f32_16x16x32_bf16(a0[si], wu0, au[si], 0, 0, 0);
        ag[si] = __builtin_amdgcn_mfma_f32_16x16x32_bf16(a0[si], wg0, ag[si], 0, 0, 0);
      }
#pragma unroll
      for (int si = 0; si < 4; ++si) {
        au[si] = __builtin_amdgcn_mfma_f32_16x16x32_bf16(a1[si], wu1, au[si], 0, 0, 0);
        ag[si] = __builtin_amdgcn_mfma_f32_16x16x32_bf16(a1[si], wg1, ag[si], 0, 0, 0);
      }
    }
  }
  int col = cB0 + cW + q16;
  float bu = b2f(bias[col]);
  float bg = b2f(bias[HIDDIM + col]);
#pragma unroll
  for (int si = 0; si < 4; ++si) {
#pragma unroll
    for (int r = 0; r < 4; ++r) {
      int rowi = mB0 + mW + si * 16 + quad * 4 + r;
      float u = au[si][r] + bu;
      float g = ag[si][r] + bg;
      float s = u / (1.0f + __expf(-u));
      actp[(size_t)rowi * HIDDIM + col] = f2b(s * g);
    }
  }
}

// ---------------- V transpose + fused coord-bias p ---------------------------
__global__ __launch_bounds__(256) void vt_kernel(const u16* __restrict__ qkvp,
                                                 u16* __restrict__ vtp,
                                                 const u16* __restrict__ coords,
                                                 const u16* __restrict__ relw,
                                                 float* __restrict__ p) {
  int blk = blockIdx.x;            // b*192 + h*16 + nt
  int b = blk / 192;
  int rem = blk % 192;
  int h = rem >> 4;
  int nt = rem & 15;
  int wv = threadIdx.x >> 6;
  int d = threadIdx.x & 63;
  int n0 = nt * 64 + wv * 16;
  const u16* src = qkvp + ((size_t)(b * NTOK) + n0) * LD3 + 2 * DMODEL + h * 64 + d;
  u16* dst = vtp + ((size_t)((b * NHEAD + h) * 64 + d)) * NTOK + n0;
#pragma unroll
  for (int c = 0; c < 2; ++c) {
    u16 buf[8] __attribute__((aligned(16)));
#pragma unroll
    for (int i = 0; i < 8; ++i) buf[i] = src[(size_t)(c * 8 + i) * LD3];
    *(uint4*)(dst + c * 8) = *(const uint4*)buf;
  }
  if (nt == 0) {   // one block per (b,h): fused p-row
    const float LOG2E = 1.4426950408889634f;
    float w0 = b2f(relw[h * 3 + 0]), w1 = b2f(relw[h * 3 + 1]), w2 = b2f(relw[h * 3 + 2]);
    float* prow = p + (size_t)(b * NHEAD + h) * NTOK;
    for (int n = threadIdx.x; n < NTOK; n += 256) {
      int idx = b * NTOK + n;
      float c0 = b2f(coords[idx * 3 + 0]);
      float c1 = b2f(coords[idx * 3 + 1]);
      float c2 = b2f(coords[idx * 3 + 2]);
      prow[n] = (c0 * w0 + c1 * w1 + c2 * w2) * LOG2E;
    }
  }
}

// ---------------- flash attention: KVBLK=64, XCD-local heads, dbuf drain -----
// 16 iterations of 64 tokens (was 32x32): halves barriers, reduces, rescales,
// and stage-issue overhead. K/V/P tiles all use row-XOR 16B-slot swizzle;
// read-slot constants kx0/kx1 shared by K, V, and P reads.
__global__ __launch_bounds__(256) void attn_kernel(
    const u16* __restrict__ qkvp, const u16* __restrict__ vtp,
    const float* __restrict__ p2, const u16* __restrict__ xp,
    float* __restrict__ x1) {
  const __bf16* qb = (const __bf16*)qkvp;
  __shared__ __align__(16) u16 Kl[2][64 * 64];   // [j][d], slot swz by j&7 (16KB)
  __shared__ __align__(16) u16 Vl[2][64 * 64];   // [d][j], slot swz by d&7 (16KB)
  __shared__ __align__(16) u16 Pl[4][16][64];    // [q16][j], slot swz by q16&7 (8KB)
  __shared__ __align__(16) float Pb[1024];       // p-row (pre-scaled by LOG2E)
  int lane = threadIdx.x & 63;
  int wv = threadIdx.x >> 6;
  int hw = blockIdx.x;                     // 0..767
  int g = hw % 48;                         // (b,h): all its 16 tiles same XCD
  int nt = hw / 48;                        // query-tile group 0..15
  int b = g / 12, h = g % 12;
  int i0 = (nt * 4 + wv) * 16;             // wave's query tile
  int q16 = lane & 15, quad = lane >> 4;

  const float scl2 = 0.125f * 1.4426950408889634f;

  const __bf16* qrow = qb + ((size_t)(b * NTOK) + i0 + q16) * LD3 + h * 64;
  bf16x8 bq0 = *(const bf16x8*)(qrow + quad * 8);
  bf16x8 bq1 = *(const bf16x8*)(qrow + 32 + quad * 8);

  const float* prow = p2 + (size_t)(b * NHEAD + h) * NTOK;

  // staging: wave wv stages rows wv*16 + {0..7, 8..15}; lane covers (row, slot)
  int lr = lane >> 3, ls = lane & 7;
  int krw = wv * 16 + lr;                  // rows krw and krw+8
  int ksl = ls ^ (krw & 7);                // swizzled 16B slot (same for both: +8 keeps low3)
  const u16* kg0 = qkvp + (size_t)(b * NTOK) * LD3 + DMODEL + h * 64 + ksl * 8;
  const u16* vg0 = vtp + ((size_t)((b * NHEAD + h) * 64 + krw)) * NTOK + ksl * 8;

  // read-slot constants (shared by K rows, V rows, P rows)
  int kx0 = (quad ^ (q16 & 7)) << 3;
  int kx1 = ((4 | quad) ^ (q16 & 7)) << 3;

  float mrun = -1e30f, lsum = 0.f;
  f32x4 accO[4] = {};

  // prologue: p-row + tile 0
  gl_lds16((const u16*)(prow + wv * 256 + lane * 4), (u16*)&Pb[wv * 256]);
  gl_lds16(kg0 + (size_t)krw * LD3, &Kl[0][wv * 1024]);
  gl_lds16(kg0 + (size_t)(krw + 8) * LD3, &Kl[0][wv * 1024 + 512]);
  gl_lds16(vg0, &Vl[0][wv * 1024]);
  gl_lds16(vg0 + (size_t)8 * NTOK, &Vl[0][wv * 1024 + 512]);

  for (int t = 0; t < 16; ++t) {
    asm volatile("s_waitcnt vmcnt(0)" ::: "memory");
    __builtin_amdgcn_sched_barrier(0);
    __builtin_amdgcn_s_barrier();            // stage(t) landed for all waves
    __builtin_amdgcn_sched_barrier(0);
    int c = t & 1;
    if (t < 15) {                            // stage(t+1) into other buffer
      int j = (t + 1) * 64;
      int bs = c ^ 1;
      gl_lds16(kg0 + (size_t)(j + krw) * LD3, &Kl[bs][wv * 1024]);
      gl_lds16(kg0 + (size_t)(j + krw + 8) * LD3, &Kl[bs][wv * 1024 + 512]);
      gl_lds16(vg0 + j, &Vl[bs][wv * 1024]);
      gl_lds16(vg0 + (size_t)8 * NTOK + j, &Vl[bs][wv * 1024 + 512]);
    }

    int j0 = t * 64;
    const __bf16* Kb = (const __bf16*)Kl[c];
    const __bf16* Vb = (const __bf16*)Vl[c];

    // QK^T (swapped): st[tt] rows j = tt*16 + quad*4 + r, col q16
    f32x4 st[4];
#pragma unroll
    for (int tt = 0; tt < 4; ++tt) {
      bf16x8 ka0 = *(const bf16x8*)(Kb + (tt * 16 + q16) * 64 + kx0);
      bf16x8 ka1 = *(const bf16x8*)(Kb + (tt * 16 + q16) * 64 + kx1);
      f32x4 z = {};
      z = __builtin_amdgcn_mfma_f32_16x16x32_bf16(ka0, bq0, z, 0, 0, 0);
      z = __builtin_amdgcn_mfma_f32_16x16x32_bf16(ka1, bq1, z, 0, 0, 0);
      st[tt] = z;
    }

    float sv[4][4];
#pragma unroll
    for (int tt = 0; tt < 4; ++tt) {
      f32x4 pj = *(const f32x4*)(&Pb[j0 + tt * 16 + 4 * quad]);
#pragma unroll
      for (int r = 0; r < 4; ++r) sv[tt][r] = st[tt][r] * scl2 - pj[r];
    }
    float lm = sv[0][0];
#pragma unroll
    for (int tt = 0; tt < 4; ++tt)
#pragma unroll
      for (int r = 0; r < 4; ++r) lm = fmaxf(lm, sv[tt][r]);
    lm = fmaxf(lm, __shfl_xor(lm, 16, 64));
    lm = fmaxf(lm, __shfl_xor(lm, 32, 64));
    float mn = fmaxf(mrun, lm);
    float alpha = exp2f(mrun - mn);
    mrun = mn;
    float pp[4][4];
    float ts = 0.f;
#pragma unroll
    for (int tt = 0; tt < 4; ++tt) {
      float s0 = exp2f(sv[tt][0] - mn), s1 = exp2f(sv[tt][1] - mn);
      float s2 = exp2f(sv[tt][2] - mn), s3 = exp2f(sv[tt][3] - mn);
      pp[tt][0] = s0; pp[tt][1] = s1; pp[tt][2] = s2; pp[tt][3] = s3;
      ts += (s0 + s1) + (s2 + s3);
    }
    ts += __shfl_xor(ts, 16, 64);
    ts += __shfl_xor(ts, 32, 64);
    lsum = lsum * alpha + ts;

    // P writes: lane owns P[q16 col][j = tt*16 + quad*4 + r] -> row q16 of Pl,
    // logical byte tt*32 + quad*8 => slot 2*tt+(quad>>1), half (quad&1)
#pragma unroll
    for (int tt = 0; tt < 4; ++tt) {
      bf16x4 w = {(__bf16)pp[tt][0], (__bf16)pp[tt][1],
                  (__bf16)pp[tt][2], (__bf16)pp[tt][3]};
      int wslot = (2 * tt + (quad >> 1)) ^ (q16 & 7);
      *(bf16x4*)(&Pl[wv][q16][wslot * 8 + (quad & 1) * 4]) = w;
    }
    bf16x8 ap0 = *(const bf16x8*)(&Pl[wv][q16][kx0]);   // j 0..31 slice
    bf16x8 ap1 = *(const bf16x8*)(&Pl[wv][q16][kx1]);   // j 32..63 slice

    // PV (swapped): O^T += Vt * P
#pragma unroll
    for (int ds = 0; ds < 4; ++ds) {
      bf16x8 av0 = *(const bf16x8*)(Vb + (ds * 16 + q16) * 64 + kx0);
      bf16x8 av1 = *(const bf16x8*)(Vb + (ds * 16 + q16) * 64 + kx1);
      f32x4 cc = accO[ds];
#pragma unroll
      for (int r = 0; r < 4; ++r) cc[r] *= alpha;
      cc = __builtin_amdgcn_mfma_f32_16x16x32_bf16(av0, ap0, cc, 0, 0, 0);
      cc = __builtin_amdgcn_mfma_f32_16x16x32_bf16(av1, ap1, cc, 0, 0, 0);
      accO[ds] = cc;
    }
  }

  float rl = 1.0f / lsum;
  size_t rowbase = ((size_t)(b * NTOK) + i0 + q16) * DMODEL + h * 64;
#pragma unroll
  for (int ds = 0; ds < 4; ++ds) {
    int d0 = ds * 16 + quad * 4;
    u16x4 xv = *(const u16x4*)(xp + rowbase + d0);
    f32x4 ov;
#pragma unroll
    for (int r = 0; r < 4; ++r) ov[r] = b2f(xv[r]) + accO[ds][r] * rl;
    *(f32x4*)(x1 + rowbase + d0) = ov;
  }
}

extern "C" void kernel_launch(void* const* d_in, const int* in_sizes, int n_in,
                              void* d_out, int out_size, void* d_ws, size_t ws_size,
                              hipStream_t stream) {
  // ---- host-side boundary tripwires (verified passing in R6) ----
  static const int esz[13] = {3145728, 12288, 768, 768, 1769472, 2304, 36,
                              768, 768, 3145728, 4096, 1572864, 768};
  float sig = -1.f;
  if (n_in != 13) {
    sig = 6000.f + 100.f * (float)n_in;
  } else {
    for (int i = 0; i < 13; ++i)
      if (in_sizes[i] != esz[i]) { sig = 1000.f + 100.f * (float)i; break; }
  }
  if (sig < 0.f && ws_size < 57258496ULL) sig = 3000.f;
  if (sig < 0.f && out_size != 3145728) sig = 3100.f;
  if (sig >= 0.f) {
    signal_kernel<<<(out_size + 255) / 256, 256, 0, stream>>>((float*)d_out, out_size, sig);
    return;
  }

  char* ws = (char*)d_ws;
  u16*  cx      = (u16*)(ws + 256);               // 6291456
  u16*  cqkvw   = (u16*)(ws + 6291712);           // 3538944
  u16*  cwinw   = (u16*)(ws + 9830656);           // 6291456
  u16*  cwoutw  = (u16*)(ws + 16122112);          // 3145728
  u16*  ccoords = (u16*)(ws + 19267840);          // 24576
  u16*  cln1g   = (u16*)(ws + 19292416);          // 1536
  u16*  cln1b   = (u16*)(ws + 19293952);          // 1536
  u16*  cqkvb   = (u16*)(ws + 19295488);          // 4608
  u16*  crelw   = (u16*)(ws + 19300096);          // 72 (padded)
  u16*  cln2g   = (u16*)(ws + 19300352);          // 1536
  u16*  cln2b   = (u16*)(ws + 19301888);          // 1536
  u16*  cwinb   = (u16*)(ws + 19303424);          // 8192
  u16*  cwoutb  = (u16*)(ws + 19311616);          // 1536
  u16*  h       = (u16*)(ws + 19313152);          // 6291456 (LN out; reused as Vt)
  u16*  qkv     = (u16*)(ws + 25604608);          // 18874368 (reused as act)
  float* pbuf   = (float*)(ws + 44478976);        // 196608
  float* x1     = (float*)(ws + 44675584);        // 12582912 -> end 57258496
  u16*  act     = qkv;
  u16*  vt      = h;       // Vt needs 6291456 B == sizeof(h)

  // 0. canonicalize all 13 inputs to bf16 (inline dtype-detect, vectorized x4)
  CanonJobs jobs;
  u16* dsts[13] = {cx, ccoords, cln1g, cln1b, cqkvw, cqkvb, crelw,
                   cln2g, cln2b, cwinw, cwinb, cwoutw, cwoutb};
  for (int i = 0; i < 13; ++i) {
    jobs.s[i] = d_in[i];
    jobs.d[i] = dsts[i];
    jobs.n[i] = in_sizes[i];
  }
  canon_kernel<<<dim3(768, 13), 256, 0, stream>>>(jobs);

  // 1. h = LN1(x)
  ln_bf16_kernel<<<4096, 256, 0, stream>>>(cx, cln1g, cln1b, h);
  // 2. qkv = h @ qkv_w^T + qkv_b   (M=4096, N=2304, K=768; 128x64 tiles)
  gemm_bt<<<dim3(36, 32), 256, 0, stream>>>(h, cqkvw, cqkvb, qkv, 2304, 768);
  // 3. Vt[b][h][d][n] = V  + fused p2 computation (h buffer dead here)
  vt_kernel<<<768, 256, 0, stream>>>(qkv, vt, ccoords, crelw, pbuf);
  // 4. x1 = x + attention(qkv, Vt, p2)   (768 blocks; KVBLK=64 dbuf)
  attn_kernel<<<768, 256, 0, stream>>>(qkv, vt, pbuf, cx, x1);
  // 5. h2 = LN2(x1)  (reuse h)
  ln_f32_kernel<<<4096, 256, 0, stream>>>(x1, cln2g, cln2b, h);
  // 6+7. act = silu(h2 @ Wu^T + bu) * (h2 @ Wg^T + bg)   (BK=64 double-buffer)
  ffn_in_kernel<<<dim3(64, 32), 256, 0, stream>>>(h, cwinw, cwinb, act);
  // 8. out(F32) = x1 + act @ wout_w^T + wout_b   (64x64 tiles, BK=64 dbuf)
  gemm_out_f32<<<dim3(12, 64), 256, 0, stream>>>(act, cwoutw, cwoutb, x1,
                                                 (float*)d_out);
}

// Round 15
// 257.198 us; speedup vs baseline: 1.1353x; 1.0320x over previous
//
#include <hip/hip_runtime.h>
#include <math.h>

typedef unsigned short u16;
typedef __bf16 bf16x8 __attribute__((ext_vector_type(8)));
typedef __bf16 bf16x4 __attribute__((ext_vector_type(4)));
typedef u16 u16x4 __attribute__((ext_vector_type(4)));
typedef float f32x4 __attribute__((ext_vector_type(4)));

// ---- constants ----
// B=4, N=1024, D=768, H=12, Dh=64, HID=2048, 3D=2304
#define NTOK 1024
#define DMODEL 768
#define NHEAD 12
#define LD2 1536          // Q,K packed row stride (V split out to Vt)
#define HIDDIM 2048

__device__ __forceinline__ float b2f(u16 u) {
  unsigned int t = ((unsigned int)u) << 16;
  float f;
  __builtin_memcpy(&f, &t, 4);
  return f;
}
__device__ __forceinline__ u16 f2b(float f) {
  unsigned int t;
  __builtin_memcpy(&t, &f, 4);
  t += 0x7fffu + ((t >> 16) & 1u);
  return (u16)(t >> 16);
}

// async global->LDS, 16B per lane; LDS dest is wave-uniform base + lane*16
__device__ __forceinline__ void gl_lds16(const u16* g, u16* l) {
  __builtin_amdgcn_global_load_lds(
      (__attribute__((address_space(1))) const unsigned int*)g,
      (__attribute__((address_space(3))) unsigned int*)l, 16, 0, 0);
}

// ---------------- host-assert signal (f32 output now) ------------------------
__global__ __launch_bounds__(256) void signal_kernel(float* __restrict__ out,
                                                     int n, float c) {
  int i = blockIdx.x * 256 + threadIdx.x;
  if (i < n) out[i] = c;
}

// ---------------- canonicalize all inputs to bf16 (inline dtype-detect) ------
struct CanonJobs {
  const void* s[13];
  u16* d[13];
  int n[13];
};

__global__ __launch_bounds__(256) void canon_kernel(CanonJobs jobs) {
  __shared__ int csh;
  u16 v = ((const u16*)jobs.s[0])[2 * threadIdx.x];
  int e = (v >> 7) & 0xFF;
  unsigned long long m = __ballot(e >= 0xC0);
  if (threadIdx.x == 0) csh = 0;
  __syncthreads();
  if ((threadIdx.x & 63) == 0) atomicAdd(&csh, __popcll(m));
  __syncthreads();
  bool isf32 = csh >= 8;       // 256 samples: f32 ~64 hits, bf16 ~0

  int j = blockIdx.y;
  int n4 = jobs.n[j] >> 2;     // all sizes divisible by 4
  const void* s = jobs.s[j];
  u16* d = jobs.d[j];
  for (int i = blockIdx.x * 256 + threadIdx.x; i < n4; i += gridDim.x * 256) {
    if (isf32) {
      f32x4 vv = *((const f32x4*)s + i);
      u16x4 o = {f2b(vv[0]), f2b(vv[1]), f2b(vv[2]), f2b(vv[3])};
      *((u16x4*)d + i) = o;
    } else {
      *((u16x4*)d + i) = *((const u16x4*)s + i);
    }
  }
}

// ---------------- LayerNorm (bf16 input) + fused coord-bias p ----------------
// Blocks 0..47 additionally compute the p2-row for (b,h) = blockIdx/12,%12:
// p2 = (coords . relw) * LOG2E  (consumed by attn; coords canonicalized bf16).
__global__ __launch_bounds__(256) void ln_bf16_kernel(
    const u16* __restrict__ x, const u16* __restrict__ g,
    const u16* __restrict__ b, u16* __restrict__ out,
    const u16* __restrict__ coords, const u16* __restrict__ relw,
    float* __restrict__ p) {
  int row = blockIdx.x;
  int tid = threadIdx.x;
  const u16* xr = x + (size_t)row * DMODEL;
  float v0 = b2f(xr[tid]), v1 = b2f(xr[tid + 256]), v2 = b2f(xr[tid + 512]);
  float s = v0 + v1 + v2;
  float q = v0 * v0 + v1 * v1 + v2 * v2;
#pragma unroll
  for (int off = 32; off; off >>= 1) {
    s += __shfl_xor(s, off, 64);
    q += __shfl_xor(q, off, 64);
  }
  __shared__ float rs[4], rq[4];
  int wv = tid >> 6;
  if ((tid & 63) == 0) { rs[wv] = s; rq[wv] = q; }
  __syncthreads();
  s = rs[0] + rs[1] + rs[2] + rs[3];
  q = rq[0] + rq[1] + rq[2] + rq[3];
  float mean = s * (1.0f / 768.0f);
  float var = q * (1.0f / 768.0f) - mean * mean;
  float inv = rsqrtf(var + 1e-5f);
  u16* outr = out + (size_t)row * DMODEL;
  outr[tid]       = f2b((v0 - mean) * inv * b2f(g[tid])       + b2f(b[tid]));
  outr[tid + 256] = f2b((v1 - mean) * inv * b2f(g[tid + 256]) + b2f(b[tid + 256]));
  outr[tid + 512] = f2b((v2 - mean) * inv * b2f(g[tid + 512]) + b2f(b[tid + 512]));
  if (row < 48) {   // fused p-row for (b,h)
    const float LOG2E = 1.4426950408889634f;
    int bb = row / 12, hh = row % 12;
    float w0 = b2f(relw[hh * 3 + 0]), w1 = b2f(relw[hh * 3 + 1]), w2 = b2f(relw[hh * 3 + 2]);
    float* prow = p + (size_t)(bb * NHEAD + hh) * NTOK;
    for (int n = tid; n < NTOK; n += 256) {
      int idx = bb * NTOK + n;
      float c0 = b2f(coords[idx * 3 + 0]);
      float c1 = b2f(coords[idx * 3 + 1]);
      float c2 = b2f(coords[idx * 3 + 2]);
      prow[n] = (c0 * w0 + c1 * w1 + c2 * w2) * LOG2E;
    }
  }
}

// ---------------- LayerNorm (f32 input) ----------------
__global__ __launch_bounds__(256) void ln_f32_kernel(
    const float* __restrict__ x, const u16* __restrict__ g,
    const u16* __restrict__ b, u16* __restrict__ out) {
  int row = blockIdx.x;
  int tid = threadIdx.x;
  const float* xr = x + (size_t)row * DMODEL;
  float v0 = xr[tid], v1 = xr[tid + 256], v2 = xr[tid + 512];
  float s = v0 + v1 + v2;
  float q = v0 * v0 + v1 * v1 + v2 * v2;
#pragma unroll
  for (int off = 32; off; off >>= 1) {
    s += __shfl_xor(s, off, 64);
    q += __shfl_xor(q, off, 64);
  }
  __shared__ float rs[4], rq[4];
  int wv = tid >> 6;
  if ((tid & 63) == 0) { rs[wv] = s; rq[wv] = q; }
  __syncthreads();
  s = rs[0] + rs[1] + rs[2] + rs[3];
  q = rq[0] + rq[1] + rq[2] + rq[3];
  float mean = s * (1.0f / 768.0f);
  float var = q * (1.0f / 768.0f) - mean * mean;
  float inv = rsqrtf(var + 1e-5f);
  u16* outr = out + (size_t)row * DMODEL;
  outr[tid]       = f2b((v0 - mean) * inv * b2f(g[tid])       + b2f(b[tid]));
  outr[tid + 256] = f2b((v1 - mean) * inv * b2f(g[tid + 256]) + b2f(b[tid + 256]));
  outr[tid + 512] = f2b((v2 - mean) * inv * b2f(g[tid + 512]) + b2f(b[tid + 512]));
}

// ---------------- qkv GEMM 128x64 tile, 3-ring pipelined, swizzled -----------
// C layout split: cols 0..1535 (Q,K) -> qkv2[row*1536+col];
// cols 1536..2303 (V) -> DIRECT TRANSPOSED store Vt[((b*12+h)*64+d)*1024+n].
__global__ __launch_bounds__(256) void gemm_bt(
    const u16* __restrict__ Ap, const u16* __restrict__ Wp,
    const u16* __restrict__ bias, u16* __restrict__ Cp,
    u16* __restrict__ vtp, int K) {
  __shared__ __align__(16) u16 Al[3 * 128 * 32], Bl[3 * 64 * 32];
  int lane = threadIdx.x & 63;
  int wv = threadIdx.x >> 6;
  int q16 = lane & 15, quad = lane >> 4;
  int mB0 = blockIdx.y * 128;
  int nB0 = blockIdx.x * 64;
  int mW = (wv >> 1) * 64, nW = (wv & 1) * 32;
  int srow = lane >> 2;
  int scol = ((lane & 3) ^ ((lane >> 3) & 3)) * 8;   // inverse-swizzled source
  int sx8 = (quad ^ ((q16 >> 1) & 3)) * 8;           // swizzled read slot
  int r0 = wv * 32 + srow, r1 = r0 + 16;             // A rows this lane stages
  int rb = wv * 16 + srow;                           // B row 0..63
  const u16* Ag0 = Ap + (size_t)(mB0 + r0) * K + scol;
  const u16* Ag1 = Ap + (size_t)(mB0 + r1) * K + scol;
  const u16* Wg  = Wp + (size_t)(nB0 + rb) * K + scol;
  int ch0 = wv * 1024, ch1 = ch0 + 512, chb = wv * 512;
  int nsteps = K >> 5;                               // 24 (div by 3)
  f32x4 acc[4][2] = {};
#pragma unroll
  for (int tt = 0; tt < 2; ++tt) {
    int k0 = tt * 32;
    gl_lds16(Ag0 + k0, Al + tt * 4096 + ch0);
    gl_lds16(Ag1 + k0, Al + tt * 4096 + ch1);
    gl_lds16(Wg + k0, Bl + tt * 2048 + chb);
  }
  int n3 = nsteps / 3;
  for (int kb = 0; kb < n3; ++kb) {
#pragma unroll
    for (int c = 0; c < 3; ++c) {
      int t = kb * 3 + c;
      if (t < nsteps - 1) asm volatile("s_waitcnt vmcnt(3)" ::: "memory");
      else                asm volatile("s_waitcnt vmcnt(0)" ::: "memory");
      __builtin_amdgcn_sched_barrier(0);
      __builtin_amdgcn_s_barrier();
      __builtin_amdgcn_sched_barrier(0);
      if (t < nsteps - 2) {
        int k0 = (t + 2) * 32;
        int bs = (c + 2) % 3;
        gl_lds16(Ag0 + k0, Al + bs * 4096 + ch0);
        gl_lds16(Ag1 + k0, Al + bs * 4096 + ch1);
        gl_lds16(Wg + k0, Bl + bs * 2048 + chb);
      }
      const __bf16* Ab = (const __bf16*)(Al + c * 4096);
      const __bf16* Bb = (const __bf16*)(Bl + c * 2048);
      bf16x8 af[4], bfr[2];
#pragma unroll
      for (int si = 0; si < 4; ++si)
        af[si] = *(const bf16x8*)(Ab + (mW + si * 16 + q16) * 32 + sx8);
#pragma unroll
      for (int sj = 0; sj < 2; ++sj)
        bfr[sj] = *(const bf16x8*)(Bb + (nW + sj * 16 + q16) * 32 + sx8);
#pragma unroll
      for (int si = 0; si < 4; ++si)
#pragma unroll
        for (int sj = 0; sj < 2; ++sj)
          acc[si][sj] = __builtin_amdgcn_mfma_f32_16x16x32_bf16(af[si], bfr[sj], acc[si][sj], 0, 0, 0);
    }
  }
  if (nB0 < 1536) {
#pragma unroll
    for (int si = 0; si < 4; ++si)
#pragma unroll
      for (int sj = 0; sj < 2; ++sj) {
        int col = nB0 + nW + sj * 16 + q16;
        float bcol = b2f(bias[col]);
#pragma unroll
        for (int r = 0; r < 4; ++r) {
          int rowi = mB0 + mW + si * 16 + quad * 4 + r;
          Cp[(size_t)rowi * LD2 + col] = f2b(acc[si][sj][r] + bcol);
        }
      }
  } else {   // V tile -> direct transposed store
#pragma unroll
    for (int si = 0; si < 4; ++si)
#pragma unroll
      for (int sj = 0; sj < 2; ++sj) {
        int col = nB0 + nW + sj * 16 + q16;
        float bcol = b2f(bias[col]);
        int vd = col - 1536;
        int hh = vd >> 6, dd = vd & 63;
        int n0 = mB0 + mW + si * 16 + quad * 4;
        int bb = n0 >> 10, nn = n0 & 1023;
        u16x4 o = {f2b(acc[si][sj][0] + bcol), f2b(acc[si][sj][1] + bcol),
                   f2b(acc[si][sj][2] + bcol), f2b(acc[si][sj][3] + bcol)};
        *(u16x4*)(vtp + ((size_t)((bb * NHEAD + hh) * 64 + dd)) * NTOK + nn) = o;
      }
  }
}

// ---------------- final GEMM, 64x64 tiles, BK=64 double-buffer ---------------
__global__ __launch_bounds__(256) void gemm_out_f32(
    const u16* __restrict__ Ap, const u16* __restrict__ Wp,
    const u16* __restrict__ bias, const float* __restrict__ res,
    float* __restrict__ out) {
  __shared__ __align__(16) u16 Al[2 * 4096], Bl[2 * 4096];   // 16+16 KB
  int lane = threadIdx.x & 63;
  int wv = threadIdx.x >> 6;
  int q16 = lane & 15, quad = lane >> 4;
  int mB0 = blockIdx.y * 64;
  int nB0 = blockIdx.x * 64;
  int mW = (wv >> 1) * 32, nW = (wv & 1) * 32;
  int lr = lane >> 3, ls = lane & 7;
  int sg = (ls ^ lr) * 8;                       // inverse-swizzled source slot
  int sx0 = (quad ^ (q16 & 7)) * 8;             // read slot, k-half 0
  int sx1 = ((4 | quad) ^ (q16 & 7)) * 8;       // read slot, k-half 1
  const u16* Ag = Ap + (size_t)(mB0 + wv * 16 + lr) * 2048 + sg;
  const u16* Wg = Wp + (size_t)(nB0 + wv * 16 + lr) * 2048 + sg;
  int ch = wv * 1024;
  f32x4 acc[2][2] = {};
#pragma unroll
  for (int i = 0; i < 2; ++i) {
    gl_lds16(Ag + (size_t)i * 8 * 2048, Al + ch + i * 512);
    gl_lds16(Wg + (size_t)i * 8 * 2048, Bl + ch + i * 512);
  }
  for (int kb = 0; kb < 16; ++kb) {
#pragma unroll
    for (int c = 0; c < 2; ++c) {
      int t = kb * 2 + c;
      asm volatile("s_waitcnt vmcnt(0)" ::: "memory");
      __builtin_amdgcn_sched_barrier(0);
      __builtin_amdgcn_s_barrier();
      __builtin_amdgcn_sched_barrier(0);
      if (t < 31) {
        int k0 = (t + 1) * 64;
        int bs = c ^ 1;
#pragma unroll
        for (int i = 0; i < 2; ++i) {
          gl_lds16(Ag + (size_t)i * 8 * 2048 + k0, Al + bs * 4096 + ch + i * 512);
          gl_lds16(Wg + (size_t)i * 8 * 2048 + k0, Bl + bs * 4096 + ch + i * 512);
        }
      }
      const __bf16* Ab = (const __bf16*)(Al + c * 4096);
      const __bf16* Bb = (const __bf16*)(Bl + c * 4096);
      bf16x8 a0[2], a1[2], b0[2], b1[2];
#pragma unroll
      for (int si = 0; si < 2; ++si) {
        a0[si] = *(const bf16x8*)(Ab + (mW + si * 16 + q16) * 64 + sx0);
        a1[si] = *(const bf16x8*)(Ab + (mW + si * 16 + q16) * 64 + sx1);
      }
#pragma unroll
      for (int sj = 0; sj < 2; ++sj) {
        b0[sj] = *(const bf16x8*)(Bb + (nW + sj * 16 + q16) * 64 + sx0);
        b1[sj] = *(const bf16x8*)(Bb + (nW + sj * 16 + q16) * 64 + sx1);
      }
#pragma unroll
      for (int si = 0; si < 2; ++si)
#pragma unroll
        for (int sj = 0; sj < 2; ++sj) {
          acc[si][sj] = __builtin_amdgcn_mfma_f32_16x16x32_bf16(a0[si], b0[sj], acc[si][sj], 0, 0, 0);
          acc[si][sj] = __builtin_amdgcn_mfma_f32_16x16x32_bf16(a1[si], b1[sj], acc[si][sj], 0, 0, 0);
        }
    }
  }
#pragma unroll
  for (int si = 0; si < 2; ++si)
#pragma unroll
    for (int sj = 0; sj < 2; ++sj) {
      int col = nB0 + nW + sj * 16 + q16;
      float bcol = b2f(bias[col]);
#pragma unroll
      for (int r = 0; r < 4; ++r) {
        int rowi = mB0 + mW + si * 16 + quad * 4 + r;
        size_t idx = (size_t)rowi * 768 + col;
        out[idx] = acc[si][sj][r] + bcol + res[idx];
      }
    }
}

// ---------------- fused FFN-in, 128x64 tile, BK=64 double-buffer -------------
// grid (32, 32) = 1024 blocks. Per K-step/wave: 32 MFMA vs 16 b128 reads
// (2:1, was 1.33:1 at 128x32) and total barrier-iterations halved.
// LDS 64KB -> 2 blocks/CU.
__global__ __launch_bounds__(256) void ffn_in_kernel(
    const u16* __restrict__ hp, const u16* __restrict__ Wp,
    const u16* __restrict__ bias, u16* __restrict__ actp) {
  __shared__ __align__(16) u16 Al[2 * 8192], Bl[2 * 8192];   // 32+32 KB
  int lane = threadIdx.x & 63;
  int wv = threadIdx.x >> 6;
  int q16 = lane & 15, quad = lane >> 4;
  int mB0 = blockIdx.y * 128;
  int cB0 = blockIdx.x * 64;
  int mW = (wv >> 1) * 64;
  int cW = (wv & 1) * 32;
  int lr = lane >> 3, ls = lane & 7;
  int sg = (ls ^ lr) * 8;
  int sx0 = (quad ^ (q16 & 7)) * 8;
  int sx1 = ((4 | quad) ^ (q16 & 7)) * 8;
  // A: rows mB0 + wv*32 + i*8 + lr (i<4)
  const u16* Ag = hp + (size_t)(mB0 + wv * 32 + lr) * DMODEL + sg;
  // B tile rows 0..63 = Wu[cB0..+64), 64..127 = Wg[cB0..+64);
  // wave stages rows wv*32 + i*8 + lr (i<4)
  const u16* Wgp[4];
#pragma unroll
  for (int i = 0; i < 4; ++i) {
    int rbb = wv * 32 + i * 8 + lr;
    int gb = (rbb < 64) ? (cB0 + rbb) : (HIDDIM + cB0 + rbb - 64);
    Wgp[i] = Wp + (size_t)gb * DMODEL + sg;
  }
  int chA = wv * 2048, chB = wv * 2048;
  f32x4 au[4][2] = {}, ag[4][2] = {};
#pragma unroll
  for (int i = 0; i < 4; ++i) {
    gl_lds16(Ag + (size_t)i * 8 * DMODEL, Al + chA + i * 512);
    gl_lds16(Wgp[i], Bl + chB + i * 512);
  }
  for (int kb = 0; kb < 6; ++kb) {
#pragma unroll
    for (int c = 0; c < 2; ++c) {
      int t = kb * 2 + c;
      asm volatile("s_waitcnt vmcnt(0)" ::: "memory");
      __builtin_amdgcn_sched_barrier(0);
      __builtin_amdgcn_s_barrier();
      __builtin_amdgcn_sched_barrier(0);
      if (t < 11) {
        int k0 = (t + 1) * 64;
        int bs = c ^ 1;
#pragma unroll
        for (int i = 0; i < 4; ++i) {
          gl_lds16(Ag + (size_t)i * 8 * DMODEL + k0, Al + bs * 8192 + chA + i * 512);
          gl_lds16(Wgp[i] + k0, Bl + bs * 8192 + chB + i * 512);
        }
      }
      const __bf16* Ab = (const __bf16*)(Al + c * 8192);
      const __bf16* Bb = (const __bf16*)(Bl + c * 8192);
      bf16x8 a0[4], a1[4];
#pragma unroll
      for (int si = 0; si < 4; ++si) {
        a0[si] = *(const bf16x8*)(Ab + (mW + si * 16 + q16) * 64 + sx0);
        a1[si] = *(const bf16x8*)(Ab + (mW + si * 16 + q16) * 64 + sx1);
      }
      bf16x8 wu0[2], wu1[2], wg0[2], wg1[2];
#pragma unroll
      for (int sj = 0; sj < 2; ++sj) {
        wu0[sj] = *(const bf16x8*)(Bb + (cW + sj * 16 + q16) * 64 + sx0);
        wu1[sj] = *(const bf16x8*)(Bb + (cW + sj * 16 + q16) * 64 + sx1);
        wg0[sj] = *(const bf16x8*)(Bb + (64 + cW + sj * 16 + q16) * 64 + sx0);
        wg1[sj] = *(const bf16x8*)(Bb + (64 + cW + sj * 16 + q16) * 64 + sx1);
      }
#pragma unroll
      for (int si = 0; si < 4; ++si)
#pragma unroll
        for (int sj = 0; sj < 2; ++sj) {
          au[si][sj] = __builtin_amdgcn_mfma_f32_16x16x32_bf16(a0[si], wu0[sj], au[si][sj], 0, 0, 0);
          au[si][sj] = __builtin_amdgcn_mfma_f32_16x16x32_bf16(a1[si], wu1[sj], au[si][sj], 0, 0, 0);
          ag[si][sj] = __builtin_amdgcn_mfma_f32_16x16x32_bf16(a0[si], wg0[sj], ag[si][sj], 0, 0, 0);
          ag[si][sj] = __builtin_amdgcn_mfma_f32_16x16x32_bf16(a1[si], wg1[sj], ag[si][sj], 0, 0, 0);
        }
    }
  }
#pragma unroll
  for (int si = 0; si < 4; ++si)
#pragma unroll
    for (int sj = 0; sj < 2; ++sj) {
      int col = cB0 + cW + sj * 16 + q16;
      float bu = b2f(bias[col]);
      float bg = b2f(bias[HIDDIM + col]);
#pragma unroll
      for (int r = 0; r < 4; ++r) {
        int rowi = mB0 + mW + si * 16 + quad * 4 + r;
        float u = au[si][sj][r] + bu;
        float g = ag[si][sj][r] + bg;
        float s = u / (1.0f + __expf(-u));
        actp[(size_t)rowi * HIDDIM + col] = f2b(s * g);
      }
    }
}

// ---------------- flash attention: KVBLK=64, XCD-local heads, dbuf drain -----
// Q,K read from qkv2 (row stride 1536); V from Vt (written by gemm_bt).
__global__ __launch_bounds__(256) void attn_kernel(
    const u16* __restrict__ qkvp, const u16* __restrict__ vtp,
    const float* __restrict__ p2, const u16* __restrict__ xp,
    float* __restrict__ x1) {
  const __bf16* qb = (const __bf16*)qkvp;
  __shared__ __align__(16) u16 Kl[2][64 * 64];   // [j][d], slot swz by j&7 (16KB)
  __shared__ __align__(16) u16 Vl[2][64 * 64];   // [d][j], slot swz by d&7 (16KB)
  __shared__ __align__(16) u16 Pl[4][16][64];    // [q16][j], slot swz by q16&7 (8KB)
  __shared__ __align__(16) float Pb[1024];       // p-row (pre-scaled by LOG2E)
  int lane = threadIdx.x & 63;
  int wv = threadIdx.x >> 6;
  int hw = blockIdx.x;                     // 0..767
  int g = hw % 48;                         // (b,h): all its 16 tiles same XCD
  int nt = hw / 48;                        // query-tile group 0..15
  int b = g / 12, h = g % 12;
  int i0 = (nt * 4 + wv) * 16;             // wave's query tile
  int q16 = lane & 15, quad = lane >> 4;

  const float scl2 = 0.125f * 1.4426950408889634f;

  const __bf16* qrow = qb + ((size_t)(b * NTOK) + i0 + q16) * LD2 + h * 64;
  bf16x8 bq0 = *(const bf16x8*)(qrow + quad * 8);
  bf16x8 bq1 = *(const bf16x8*)(qrow + 32 + quad * 8);

  const float* prow = p2 + (size_t)(b * NHEAD + h) * NTOK;

  // staging: wave wv stages rows wv*16 + {0..7, 8..15}; lane covers (row, slot)
  int lr = lane >> 3, ls = lane & 7;
  int krw = wv * 16 + lr;                  // rows krw and krw+8
  int ksl = ls ^ (krw & 7);                // swizzled 16B slot (same for both: +8 keeps low3)
  const u16* kg0 = qkvp + (size_t)(b * NTOK) * LD2 + DMODEL + h * 64 + ksl * 8;
  const u16* vg0 = vtp + ((size_t)((b * NHEAD + h) * 64 + krw)) * NTOK + ksl * 8;

  // read-slot constants (shared by K rows, V rows, P rows)
  int kx0 = (quad ^ (q16 & 7)) << 3;
  int kx1 = ((4 | quad) ^ (q16 & 7)) << 3;

  float mrun = -1e30f, lsum = 0.f;
  f32x4 accO[4] = {};

  // prologue: p-row + tile 0
  gl_lds16((const u16*)(prow + wv * 256 + lane * 4), (u16*)&Pb[wv * 256]);
  gl_lds16(kg0 + (size_t)krw * LD2, &Kl[0][wv * 1024]);
  gl_lds16(kg0 + (size_t)(krw + 8) * LD2, &Kl[0][wv * 1024 + 512]);
  gl_lds16(vg0, &Vl[0][wv * 1024]);
  gl_lds16(vg0 + (size_t)8 * NTOK, &Vl[0][wv * 1024 + 512]);

  for (int t = 0; t < 16; ++t) {
    asm volatile("s_waitcnt vmcnt(0)" ::: "memory");
    __builtin_amdgcn_sched_barrier(0);
    __builtin_amdgcn_s_barrier();            // stage(t) landed for all waves
    __builtin_amdgcn_sched_barrier(0);
    int c = t & 1;
    if (t < 15) {                            // stage(t+1) into other buffer
      int j = (t + 1) * 64;
      int bs = c ^ 1;
      gl_lds16(kg0 + (size_t)(j + krw) * LD2, &Kl[bs][wv * 1024]);
      gl_lds16(kg0 + (size_t)(j + krw + 8) * LD2, &Kl[bs][wv * 1024 + 512]);
      gl_lds16(vg0 + j, &Vl[bs][wv * 1024]);
      gl_lds16(vg0 + (size_t)8 * NTOK + j, &Vl[bs][wv * 1024 + 512]);
    }

    int j0 = t * 64;
    const __bf16* Kb = (const __bf16*)Kl[c];
    const __bf16* Vb = (const __bf16*)Vl[c];

    // QK^T (swapped): st[tt] rows j = tt*16 + quad*4 + r, col q16
    f32x4 st[4];
#pragma unroll
    for (int tt = 0; tt < 4; ++tt) {
      bf16x8 ka0 = *(const bf16x8*)(Kb + (tt * 16 + q16) * 64 + kx0);
      bf16x8 ka1 = *(const bf16x8*)(Kb + (tt * 16 + q16) * 64 + kx1);
      f32x4 z = {};
      z = __builtin_amdgcn_mfma_f32_16x16x32_bf16(ka0, bq0, z, 0, 0, 0);
      z = __builtin_amdgcn_mfma_f32_16x16x32_bf16(ka1, bq1, z, 0, 0, 0);
      st[tt] = z;
    }

    float sv[4][4];
#pragma unroll
    for (int tt = 0; tt < 4; ++tt) {
      f32x4 pj = *(const f32x4*)(&Pb[j0 + tt * 16 + 4 * quad]);
#pragma unroll
      for (int r = 0; r < 4; ++r) sv[tt][r] = st[tt][r] * scl2 - pj[r];
    }
    float lm = sv[0][0];
#pragma unroll
    for (int tt = 0; tt < 4; ++tt)
#pragma unroll
      for (int r = 0; r < 4; ++r) lm = fmaxf(lm, sv[tt][r]);
    lm = fmaxf(lm, __shfl_xor(lm, 16, 64));
    lm = fmaxf(lm, __shfl_xor(lm, 32, 64));
    float mn = fmaxf(mrun, lm);
    float alpha = exp2f(mrun - mn);
    mrun = mn;
    float pp[4][4];
    float ts = 0.f;
#pragma unroll
    for (int tt = 0; tt < 4; ++tt) {
      float s0 = exp2f(sv[tt][0] - mn), s1 = exp2f(sv[tt][1] - mn);
      float s2 = exp2f(sv[tt][2] - mn), s3 = exp2f(sv[tt][3] - mn);
      pp[tt][0] = s0; pp[tt][1] = s1; pp[tt][2] = s2; pp[tt][3] = s3;
      ts += (s0 + s1) + (s2 + s3);
    }
    ts += __shfl_xor(ts, 16, 64);
    ts += __shfl_xor(ts, 32, 64);
    lsum = lsum * alpha + ts;

    // P writes: lane owns P[q16 col][j = tt*16 + quad*4 + r] -> row q16 of Pl
#pragma unroll
    for (int tt = 0; tt < 4; ++tt) {
      bf16x4 w = {(__bf16)pp[tt][0], (__bf16)pp[tt][1],
                  (__bf16)pp[tt][2], (__bf16)pp[tt][3]};
      int wslot = (2 * tt + (quad >> 1)) ^ (q16 & 7);
      *(bf16x4*)(&Pl[wv][q16][wslot * 8 + (quad & 1) * 4]) = w;
    }
    bf16x8 ap0 = *(const bf16x8*)(&Pl[wv][q16][kx0]);   // j 0..31 slice
    bf16x8 ap1 = *(const bf16x8*)(&Pl[wv][q16][kx1]);   // j 32..63 slice

    // PV (swapped): O^T += Vt * P
#pragma unroll
    for (int ds = 0; ds < 4; ++ds) {
      bf16x8 av0 = *(const bf16x8*)(Vb + (ds * 16 + q16) * 64 + kx0);
      bf16x8 av1 = *(const bf16x8*)(Vb + (ds * 16 + q16) * 64 + kx1);
      f32x4 cc = accO[ds];
#pragma unroll
      for (int r = 0; r < 4; ++r) cc[r] *= alpha;
      cc = __builtin_amdgcn_mfma_f32_16x16x32_bf16(av0, ap0, cc, 0, 0, 0);
      cc = __builtin_amdgcn_mfma_f32_16x16x32_bf16(av1, ap1, cc, 0, 0, 0);
      accO[ds] = cc;
    }
  }

  float rl = 1.0f / lsum;
  size_t rowbase = ((size_t)(b * NTOK) + i0 + q16) * DMODEL + h * 64;
#pragma unroll
  for (int ds = 0; ds < 4; ++ds) {
    int d0 = ds * 16 + quad * 4;
    u16x4 xv = *(const u16x4*)(xp + rowbase + d0);
    f32x4 ov;
#pragma unroll
    for (int r = 0; r < 4; ++r) ov[r] = b2f(xv[r]) + accO[ds][r] * rl;
    *(f32x4*)(x1 + rowbase + d0) = ov;
  }
}

extern "C" void kernel_launch(void* const* d_in, const int* in_sizes, int n_in,
                              void* d_out, int out_size, void* d_ws, size_t ws_size,
                              hipStream_t stream) {
  // ---- host-side boundary tripwires (verified passing in R6) ----
  static const int esz[13] = {3145728, 12288, 768, 768, 1769472, 2304, 36,
                              768, 768, 3145728, 4096, 1572864, 768};
  float sig = -1.f;
  if (n_in != 13) {
    sig = 6000.f + 100.f * (float)n_in;
  } else {
    for (int i = 0; i < 13; ++i)
      if (in_sizes[i] != esz[i]) { sig = 1000.f + 100.f * (float)i; break; }
  }
  if (sig < 0.f && ws_size < 57258496ULL) sig = 3000.f;
  if (sig < 0.f && out_size != 3145728) sig = 3100.f;
  if (sig >= 0.f) {
    signal_kernel<<<(out_size + 255) / 256, 256, 0, stream>>>((float*)d_out, out_size, sig);
    return;
  }

  char* ws = (char*)d_ws;
  u16*  cx      = (u16*)(ws + 256);               // 6291456
  u16*  cqkvw   = (u16*)(ws + 6291712);           // 3538944
  u16*  cwinw   = (u16*)(ws + 9830656);           // 6291456
  u16*  cwoutw  = (u16*)(ws + 16122112);          // 3145728
  u16*  ccoords = (u16*)(ws + 19267840);          // 24576
  u16*  cln1g   = (u16*)(ws + 19292416);          // 1536
  u16*  cln1b   = (u16*)(ws + 19293952);          // 1536
  u16*  cqkvb   = (u16*)(ws + 19295488);          // 4608
  u16*  crelw   = (u16*)(ws + 19300096);          // 72 (padded)
  u16*  cln2g   = (u16*)(ws + 19300352);          // 1536
  u16*  cln2b   = (u16*)(ws + 19301888);          // 1536
  u16*  cwinb   = (u16*)(ws + 19303424);          // 8192
  u16*  cwoutb  = (u16*)(ws + 19311616);          // 1536
  u16*  h       = (u16*)(ws + 19313152);          // 6291456 (LN out)
  u16*  qkv2    = (u16*)(ws + 25604608);          // 12582912 (Q,K @ stride 1536)
  u16*  vt      = (u16*)(ws + 38187520);          // 6291456 (Vt, from gemm_bt)
  float* pbuf   = (float*)(ws + 44478976);        // 196608
  float* x1     = (float*)(ws + 44675584);        // 12582912 -> end 57258496
  u16*  act     = qkv2;    // act needs 16.8MB: spans qkv2+vt (both dead post-attn)

  // 0. canonicalize all 13 inputs to bf16 (inline dtype-detect, vectorized x4)
  CanonJobs jobs;
  u16* dsts[13] = {cx, ccoords, cln1g, cln1b, cqkvw, cqkvb, crelw,
                   cln2g, cln2b, cwinw, cwinb, cwoutw, cwoutb};
  for (int i = 0; i < 13; ++i) {
    jobs.s[i] = d_in[i];
    jobs.d[i] = dsts[i];
    jobs.n[i] = in_sizes[i];
  }
  canon_kernel<<<dim3(768, 13), 256, 0, stream>>>(jobs);

  // 1. h = LN1(x)  (+ fused p2 rows in blocks 0..47)
  ln_bf16_kernel<<<4096, 256, 0, stream>>>(cx, cln1g, cln1b, h,
                                           ccoords, crelw, pbuf);
  // 2. qkv: Q,K -> qkv2 (stride 1536); V -> Vt (transposed epilogue store)
  gemm_bt<<<dim3(36, 32), 256, 0, stream>>>(h, cqkvw, cqkvb, qkv2, vt, 768);
  // 3. x1 = x + attention(qkv2, Vt, p2)   (768 blocks; KVBLK=64 dbuf)
  attn_kernel<<<768, 256, 0, stream>>>(qkv2, vt, pbuf, cx, x1);
  // 4. h2 = LN2(x1)  (reuse h)
  ln_f32_kernel<<<4096, 256, 0, stream>>>(x1, cln2g, cln2b, h);
  // 5+6. act = silu(h2 @ Wu^T + bu) * (h2 @ Wg^T + bg)   (128x64, BK=64 dbuf)
  ffn_in_kernel<<<dim3(32, 32), 256, 0, stream>>>(h, cwinw, cwinb, act);
  // 7. out(F32) = x1 + act @ wout_w^T + wout_b   (64x64 tiles, BK=64 dbuf)
  gemm_out_f32<<<dim3(12, 64), 256, 0, stream>>>(act, cwoutw, cwoutb, x1,
                                                 (float*)d_out);
}